// Round 11
// baseline (244.676 us; speedup 1.0000x reference)
//
#include <hip/hip_runtime.h>
#include <hip/hip_bf16.h>
#include <stdint.h>

typedef __attribute__((ext_vector_type(4))) float f32x4;
typedef __attribute__((ext_vector_type(8))) __bf16 bf16x8;
typedef __attribute__((ext_vector_type(8))) unsigned short u16x8;
typedef long long ll64;
typedef __attribute__((ext_vector_type(2))) long long ll64x2;

__device__ __forceinline__ unsigned short f2bf(float f){
  uint32_t u = __builtin_bit_cast(uint32_t, f);
  u += 0x7FFFu + ((u >> 16) & 1u);
  return (unsigned short)(u >> 16);
}
__device__ __forceinline__ float bf2f(unsigned short h){
  return __builtin_bit_cast(float, ((uint32_t)h) << 16);
}
__device__ __forceinline__ float fast_exp2(float x){
#if __has_builtin(__builtin_amdgcn_exp2f)
  return __builtin_amdgcn_exp2f(x);
#else
  return exp2f(x);
#endif
}
__device__ __forceinline__ unsigned char f2fp8(float f){
#if __has_builtin(__builtin_amdgcn_cvt_pk_fp8_f32)
  int r = __builtin_amdgcn_cvt_pk_fp8_f32(f, f, 0, false);
  return (unsigned char)(r & 0xff);
#else
  uint32_t u = __builtin_bit_cast(uint32_t, f);
  uint32_t s = (u >> 24) & 0x80u;
  uint32_t a = u & 0x7fffffffu;
  float af = __builtin_bit_cast(float, a);
  if (af >= 448.f) return (unsigned char)(s | 0x7e);
  a += 0x000fffffu + ((a >> 20) & 1u);
  int e = (int)(a >> 23) - 127;
  if (e < -6) return (unsigned char)s;
  return (unsigned char)(s | (uint32_t)((e + 7) << 3) | ((a >> 20) & 7u));
#endif
}
// k-interleave permutation: lane lk's two 8B chunks (true k lk*8, 32+lk*8) contiguous
__device__ __forceinline__ int perm64(int c){
  return (c & ~63) | (((c >> 3) & 3) << 4) | (((c >> 5) & 1) << 3) | (c & 7);
}
__device__ __forceinline__ void gl_lds16(const unsigned short* g, unsigned short* l){
  __builtin_amdgcn_global_load_lds(
      (const __attribute__((address_space(1))) uint32_t*)g,
      (__attribute__((address_space(3))) uint32_t*)l, 16, 0, 0);
}
__device__ __forceinline__ void gl_lds16b(const unsigned char* g, unsigned char* l){
  __builtin_amdgcn_global_load_lds(
      (const __attribute__((address_space(1))) uint32_t*)g,
      (__attribute__((address_space(3))) uint32_t*)l, 16, 0, 0);
}

// ---------------- fp32 -> bf16 convert: Wq|Wk concat, Wv, Wo ----------------
__global__ __launch_bounds__(256) void conv4(const float* __restrict__ a, const float* __restrict__ b,
                                             const float* __restrict__ c, const float* __restrict__ d,
                                             unsigned short* __restrict__ oqk,
                                             unsigned short* __restrict__ ov,
                                             unsigned short* __restrict__ oo){
  const int bid = blockIdx.x;
  const int sel = bid >> 7;
  const float* in = sel == 0 ? a : sel == 1 ? b : sel == 2 ? c : d;
  unsigned short* out = sel == 0 ? oqk : sel == 1 ? (oqk + 262144) : sel == 2 ? ov : oo;
  const int i = ((bid & 127) * 256 + threadIdx.x) * 8;
  float4 v0 = *(const float4*)&in[i];
  float4 v1 = *(const float4*)&in[i + 4];
  u16x8 o;
  o[0]=f2bf(v0.x); o[1]=f2bf(v0.y); o[2]=f2bf(v0.z); o[3]=f2bf(v0.w);
  o[4]=f2bf(v1.x); o[5]=f2bf(v1.y); o[6]=f2bf(v1.z); o[7]=f2bf(v1.w);
  *(u16x8*)&out[i] = o;
}

// ---------------- GroupNorm stats, 2-stage ----------------
__global__ __launch_bounds__(256) void gn_stats1(const float* __restrict__ x,
                                                 float* __restrict__ part){
  const int bid = blockIdx.x;
  const float* p = x + (size_t)bid * 8192;
  float s = 0.f, ss = 0.f;
  for (int i = threadIdx.x; i < 2048; i += 256) {
    float4 v = *(const float4*)(p + (size_t)i * 4);
    s  += v.x + v.y + v.z + v.w;
    ss += v.x*v.x + v.y*v.y + v.z*v.z + v.w*v.w;
  }
  for (int off = 32; off; off >>= 1) { s += __shfl_down(s, off); ss += __shfl_down(ss, off); }
  __shared__ float red[8];
  int w = threadIdx.x >> 6;
  if ((threadIdx.x & 63) == 0) { red[w] = s; red[w + 4] = ss; }
  __syncthreads();
  if (threadIdx.x == 0) {
    part[bid * 2]     = red[0] + red[1] + red[2] + red[3];
    part[bid * 2 + 1] = red[4] + red[5] + red[6] + red[7];
  }
}
__global__ __launch_bounds__(128) void gn_stats2(const float* __restrict__ part,
                                                 float* __restrict__ stats){
  const int g = threadIdx.x;
  float s = 0.f, ss = 0.f;
#pragma unroll
  for (int i = 0; i < 8; i++) { s += part[(g * 8 + i) * 2]; ss += part[(g * 8 + i) * 2 + 1]; }
  float mean = s * (1.f / 65536.f);
  float var  = ss * (1.f / 65536.f) - mean * mean;
  stats[g * 2]     = mean;
  stats[g * 2 + 1] = rsqrtf(var + 1e-6f);
}

// ---------------- GN apply + transpose ----------------
__global__ __launch_bounds__(256) void gn_apply(const float* __restrict__ x,
                                                const float* __restrict__ stats,
                                                const float* __restrict__ gamma,
                                                const float* __restrict__ beta,
                                                unsigned short* __restrict__ hn_t){
  __shared__ float tile[64][33];
  const int b  = blockIdx.z;
  const int c0 = blockIdx.y * 64;
  const int p0 = blockIdx.x * 32;
  const int t  = threadIdx.x;
  const float* xb = x + (size_t)b * 512 * 4096;
  const int lpx = t & 31, lcc = t >> 5;
#pragma unroll
  for (int i = 0; i < 8; i++)
    tile[lcc + i * 8][lpx] = xb[(size_t)(c0 + lcc + i * 8) * 4096 + p0 + lpx];
  __syncthreads();
  unsigned short* hb = hn_t + (size_t)b * 4096 * 512;
  const int c   = c0 + (t & 31) * 2;
  const int pxi = t >> 5;
  const int g2  = (b * 32 + (c >> 4)) * 2;
  const float mean = stats[g2], rstd = stats[g2 + 1];
  const float ga0 = gamma[c], be0 = beta[c];
  const float ga1 = gamma[c + 1], be1 = beta[c + 1];
#pragma unroll
  for (int i = 0; i < 4; i++) {
    const int px = pxi + i * 8;
    float v0 = tile[(t & 31) * 2][px];
    float v1 = tile[(t & 31) * 2 + 1][px];
    uint32_t h0 = f2bf((v0 - mean) * rstd * ga0 + be0);
    uint32_t h1 = f2bf((v1 - mean) * rstd * ga1 + be1);
    *(uint32_t*)&hb[(size_t)(p0 + px) * 512 + c] = h0 | (h1 << 16);
  }
}

// ---------------- R5-structure bf16 GEMM (projections): BM=256, BN=128, BK=64 ----------------
// MODE 1: +bias(qk split) -> FP8 to qt8/kt8 (k-interleaved cols)
// MODE 2: +bias[row] -> FP8 to vcm8 (k-interleaved cols)
// MODE 5: acc+resid+bias[col] -> fp32 transposed out
template<int MODE>
__device__ __forceinline__ void gemm_body5(
    const unsigned short* __restrict__ A, const unsigned short* __restrict__ B,
    unsigned char* __restrict__ C8, float* __restrict__ OUTF,
    const float* __restrict__ auxA, const float* __restrict__ auxB,
    int M, int N, int K, size_t sA, size_t sB, size_t sC, int gx, int gy)
{
  constexpr int NF = 2;
  __shared__ __align__(16) unsigned short As[4 * 8192];
  __shared__ __align__(16) unsigned short Bs[2 * 8192];

  const int lin = blockIdx.x;
  const int nwg = gridDim.x;
  const int wg = ((lin & 7) * (nwg >> 3)) + (lin >> 3);
  const int bx = wg % gx;
  const int t2 = wg / gx;
  const int by = t2 % gy;
  const int bz = t2 / gy;

  const unsigned short* Ab = A + (size_t)bz * sA;
  const unsigned short* Bb = B + (size_t)bz * sB;
  const int brow = bx * 256;
  const int bcol = by * 128;
  const int t = threadIdx.x;
  const int lane = t & 63;
  const int wid = t >> 6;
  const int wr = wid >> 2;
  const int wc = wid & 3;
  const int la = lane & 15;
  const int lk = lane >> 4;
  const int axr = la >> 1;

  const f32x4 zero = {0.f, 0.f, 0.f, 0.f};
  f32x4 acc[8][NF];
#pragma unroll
  for (int m = 0; m < 8; m++)
#pragma unroll
    for (int n = 0; n < NF; n++) acc[m][n] = zero;

  const int ru0 = t >> 3, s0 = t & 7;
  const int gx0 = s0 ^ ((ru0 >> 1) & 7);

  auto stageA = [&](int kt, int h) {
    unsigned short* base = As + ((kt & 1) * 2 + h) * 8192;
    const size_t ko = (size_t)kt * 64;
    gl_lds16(Ab + (size_t)(brow + h * 64 + ru0) * K + ko + gx0 * 8, base + t * 8);
    gl_lds16(Ab + (size_t)(brow + 128 + h * 64 + ru0) * K + ko + gx0 * 8, base + 4096 + t * 8);
  };
  auto stageBf = [&](int kt) {
    unsigned short* base = Bs + (kt & 1) * 8192;
    const size_t ko = (size_t)kt * 64;
    gl_lds16(Bb + (size_t)(bcol + ru0) * K + ko + gx0 * 8, base + t * 8);
    gl_lds16(Bb + (size_t)(bcol + 64 + ru0) * K + ko + gx0 * 8, base + 4096 + t * 8);
  };
  auto LDA = [&](int db, int mh, int i, int kst) -> bf16x8 {
    const int ru = wr * 64 + i * 16 + la;
    const int slot = ((kst << 2) | lk) ^ axr;
    return __builtin_bit_cast(bf16x8, *(const u16x8*)&As[(db * 2 + mh) * 8192 + ru * 64 + slot * 8]);
  };
  auto LDB = [&](int db, int n2, int kst) -> bf16x8 {
    const int ru = wc * 32 + n2 * 16 + la;
    const int slot = ((kst << 2) | lk) ^ axr;
    return __builtin_bit_cast(bf16x8, *(const u16x8*)&Bs[db * 8192 + ru * 64 + slot * 8]);
  };

#define DSR5(mh) \
  bf16x8 aq[4][2], bq[2][2]; \
  _Pragma("unroll") for (int i = 0; i < 4; ++i) { aq[i][0] = LDA(db, mh, i, 0); aq[i][1] = LDA(db, mh, i, 1); } \
  _Pragma("unroll") for (int n2 = 0; n2 < 2; ++n2) { bq[n2][0] = LDB(db, n2, 0); bq[n2][1] = LDB(db, n2, 1); }

#define MM5(mh) \
  asm volatile("s_waitcnt lgkmcnt(0)" ::: "memory"); \
  __builtin_amdgcn_sched_barrier(0); \
  __builtin_amdgcn_s_setprio(1); \
  _Pragma("unroll") for (int i = 0; i < 4; ++i) \
    _Pragma("unroll") for (int n2 = 0; n2 < 2; ++n2) { \
      acc[(mh)*4+i][n2] = __builtin_amdgcn_mfma_f32_16x16x32_bf16(aq[i][0], bq[n2][0], acc[(mh)*4+i][n2], 0, 0, 0); \
      acc[(mh)*4+i][n2] = __builtin_amdgcn_mfma_f32_16x16x32_bf16(aq[i][1], bq[n2][1], acc[(mh)*4+i][n2], 0, 0, 0); } \
  __builtin_amdgcn_s_setprio(0); \
  __builtin_amdgcn_sched_barrier(0);

#define PHASE5(VMS, mh, STG) do { \
  asm volatile("s_waitcnt vmcnt(" VMS ")" ::: "memory"); \
  __builtin_amdgcn_s_barrier(); \
  DSR5(mh); \
  STG; \
  MM5(mh); \
} while (0)

  const int nk = K >> 6;
  stageA(0, 0); stageBf(0); stageA(0, 1);
  for (int j = 0; j < nk - 1; ++j) {
    const int db = j & 1;
    PHASE5("2", 0, { stageA(j + 1, 0); stageBf(j + 1); });
    PHASE5("4", 1, { stageA(j + 1, 1); });
  }
  {
    const int db = (nk - 1) & 1;
    asm volatile("s_waitcnt vmcnt(0)" ::: "memory");
    __builtin_amdgcn_s_barrier();
    { DSR5(0); MM5(0); }
    { DSR5(1); MM5(1); }
  }
#undef PHASE5
#undef MM5
#undef DSR5

  const int cl = la;
  const int rg = lk * 4;
  const int rowbase = brow + wr * 128;
  const int colbase = bcol + wc * 32;

  if (MODE == 1) {
    // C8: qt8 (16384x512) then kt8 at +8388608; store k-interleaved
#pragma unroll
    for (int m = 0; m < 8; m++) {
#pragma unroll
      for (int n = 0; n < NF; n++) {
        const int col = colbase + n * 16 + cl;
        const float bcv = (col < 512 ? auxA[col] : auxB[col - 512]);
        unsigned char* dst = C8 + (col < 512 ? 0 : (size_t)8388608);
        const int c9 = perm64(col & 511);
#pragma unroll
        for (int j = 0; j < 4; j++) {
          const int row = rowbase + m * 16 + rg + j;
          dst[(size_t)row * 512 + c9] = f2fp8(acc[m][n][j] + bcv);
        }
      }
    }
  } else if (MODE == 2) {
    unsigned char* Cb = C8 + (size_t)bz * sC;
#pragma unroll
    for (int m = 0; m < 8; m++) {
#pragma unroll
      for (int n = 0; n < NF; n++) {
        const int col = colbase + n * 16 + cl;
        const int cp = perm64(col);
#pragma unroll
        for (int j = 0; j < 4; j++) {
          const int row = rowbase + m * 16 + rg + j;
          Cb[(size_t)row * N + cp] = f2fp8(acc[m][n][j] + auxA[row]);
        }
      }
    }
  } else { // MODE 5
#pragma unroll
    for (int m = 0; m < 8; m++) {
      const int row = rowbase + m * 16 + rg;
      const int bb = row >> 12;
      const int p  = row & 4095;
#pragma unroll
      for (int n = 0; n < NF; n++) {
        const int col = colbase + n * 16 + cl;
        const size_t idx = ((size_t)bb * 512 + col) * 4096 + p;
        const float4 xv = *(const float4*)&auxA[idx];
        const float bv = auxB[col];
        float4 ov;
        ov.x = acc[m][n][0] + xv.x + bv;
        ov.y = acc[m][n][1] + xv.y + bv;
        ov.z = acc[m][n][2] + xv.z + bv;
        ov.w = acc[m][n][3] + xv.w + bv;
        *(float4*)&OUTF[idx] = ov;
      }
    }
  }
}

#define GEMM_ARGS const unsigned short* A, const unsigned short* B, unsigned char* C8, \
                  float* OUTF, const float* auxA, const float* auxB, \
                  int M, int N, int K, size_t sA, size_t sB, size_t sC, int gx, int gy
#define GEMM_PASS A, B, C8, OUTF, auxA, auxB, M, N, K, sA, sB, sC, gx, gy

__global__ __launch_bounds__(512, 2) void k_qkproj(GEMM_ARGS){ gemm_body5<1>(GEMM_PASS); }
__global__ __launch_bounds__(512, 2) void k_vproj (GEMM_ARGS){ gemm_body5<2>(GEMM_PASS); }

__global__ __launch_bounds__(512, 2) void k_oproj(const unsigned short* A, const unsigned short* B,
                                                  float* OUTF, const float* resid, const float* bias,
                                                  int gx, int gy){
  gemm_body5<5>(A, B, nullptr, OUTF, resid, bias, 16384, 512, 512, 0, 0, 0, gx, gy);
}

// ---------------- fp8 scores GEMM: BM=BN=256, BK=64, NBUF=2 (64 KB -> 2 blocks/CU) ----------------
// Per tile: {vmcnt(0); barrier; STAGE(j+1) [other buf, proven consumed]; ds_read b128; lgkm; MFMA}
__global__ __launch_bounds__(512, 2)
void k_scores(const unsigned char* __restrict__ A, const unsigned char* __restrict__ B,
              unsigned char* __restrict__ C, const float* __restrict__ mask,
              float* __restrict__ partial,
              int M, int N, int K, int ldA, int ldB, float scale,
              size_t sA, size_t sB, size_t sC, int gx, int gy)
{
  __shared__ __align__(16) unsigned char As[2 * 16384];   // 32 KB
  __shared__ __align__(16) unsigned char Bs[2 * 16384];   // 32 KB

  const int lin = blockIdx.x;
  const int nwg = gridDim.x;
  const int wg = ((lin & 7) * (nwg >> 3)) + (lin >> 3);
  const int bx = wg % gx;
  const int t2 = wg / gx;
  const int by = t2 % gy;
  const int bz = t2 / gy;

  const unsigned char* Ab = A + (size_t)bz * sA;
  const unsigned char* Bb = B + (size_t)bz * sB;
  const int brow = bx * 256;
  const int bcol = by * 256;
  const int t = threadIdx.x;
  const int lane = t & 63;
  const int wid = t >> 6;
  const int wr = wid >> 2;
  const int wc = wid & 3;
  const int la = lane & 15;
  const int lk = lane >> 4;

  const f32x4 zero = {0.f, 0.f, 0.f, 0.f};
  f32x4 acc[8][4];
#pragma unroll
  for (int m = 0; m < 8; m++)
#pragma unroll
    for (int n = 0; n < 4; n++) acc[m][n] = zero;

  const unsigned char* srcA[2];
  const unsigned char* srcB[2];
#pragma unroll
  for (int c = 0; c < 2; ++c) {
    const int q = c * 512 + t, r = q >> 2, s = (q & 3) ^ ((r >> 1) & 3);
    srcA[c] = Ab + (size_t)(brow + r) * ldA + s * 16;
    srcB[c] = Bb + (size_t)(bcol + r) * ldB + s * 16;
  }
  auto STAGE = [&](int kt, int buf) {
    const int ko = kt * 64;
#pragma unroll
    for (int c = 0; c < 2; ++c) {
      gl_lds16b(srcA[c] + ko, &As[buf * 16384 + (c * 512 + t) * 16]);
      gl_lds16b(srcB[c] + ko, &Bs[buf * 16384 + (c * 512 + t) * 16]);
    }
  };
  auto LDA8 = [&](int buf, int m) -> ll64x2 {
    const int ru = wr * 128 + m * 16 + la;
    const int slot = lk ^ ((ru >> 1) & 3);
    return *(const ll64x2*)&As[buf * 16384 + ru * 64 + slot * 16];
  };
  auto LDB8 = [&](int buf, int n) -> ll64x2 {
    const int ru = wc * 64 + n * 16 + la;
    const int slot = lk ^ ((ru >> 1) & 3);
    return *(const ll64x2*)&Bs[buf * 16384 + ru * 64 + slot * 16];
  };

  const int nk = K >> 6;    // 8
  STAGE(0, 0);
  for (int j = 0; j < nk; ++j) {
    const int bi = j & 1;
    asm volatile("s_waitcnt vmcnt(0)" ::: "memory");
    __builtin_amdgcn_s_barrier();
    __builtin_amdgcn_sched_barrier(0);
    if (j + 1 < nk) STAGE(j + 1, bi ^ 1);
    ll64x2 aq[8], bq[4];
#pragma unroll
    for (int n = 0; n < 4; n++) bq[n] = LDB8(bi, n);
#pragma unroll
    for (int m = 0; m < 8; m++) aq[m] = LDA8(bi, m);
    asm volatile("s_waitcnt lgkmcnt(0)" ::: "memory");
    __builtin_amdgcn_sched_barrier(0);
    __builtin_amdgcn_s_setprio(1);
#pragma unroll
    for (int m = 0; m < 8; m++)
#pragma unroll
      for (int n = 0; n < 4; n++) {
        acc[m][n] = __builtin_amdgcn_mfma_f32_16x16x32_fp8_fp8(aq[m][0], bq[n][0], acc[m][n], 0, 0, 0);
        acc[m][n] = __builtin_amdgcn_mfma_f32_16x16x32_fp8_fp8(aq[m][1], bq[n][1], acc[m][n], 0, 0, 0);
      }
    __builtin_amdgcn_s_setprio(0);
    __builtin_amdgcn_sched_barrier(0);
  }

  // epilogue
  const int cl = la;
  const int rg = lk * 4;
  const int rowbase = brow + wr * 128;
  const int colbase = bcol + wc * 64;
  unsigned char* Cb = C + (size_t)bz * sC;
  const float* maskb = mask + (size_t)bz * 4096;
  float* partb = partial + ((size_t)bz * 64 + (size_t)(by * 4 + wc)) * M;
  const float sc2 = scale * 1.4426950408889634f;
  f32x4 rs[8];
#pragma unroll
  for (int m = 0; m < 8; m++) rs[m] = zero;
#pragma unroll
  for (int m = 0; m < 8; m++) {
#pragma unroll
    for (int n = 0; n < 4; n++) {
      const int col = colbase + n * 16 + cl;
      const float mk = maskb[col];
      const int cp = perm64(col);
#pragma unroll
      for (int j = 0; j < 4; j++) {
        const int row = rowbase + m * 16 + rg + j;
        float v = mk * fast_exp2(acc[m][n][j] * sc2);
        rs[m][j] += v;
        Cb[(size_t)row * N + cp] = f2fp8(v);
      }
    }
  }
#pragma unroll
  for (int off = 1; off < 16; off <<= 1)
#pragma unroll
    for (int m = 0; m < 8; m++) {
#pragma unroll
      for (int j = 0; j < 4; j++) rs[m][j] += __shfl_xor(rs[m][j], off);
    }
  if (cl == 0) {
#pragma unroll
    for (int m = 0; m < 8; m++) {
      float4 v = make_float4(rs[m][0], rs[m][1], rs[m][2], rs[m][3]);
      *(float4*)&partb[rowbase + m * 16 + rg] = v;
    }
  }
}

// ---------------- fp8 PV GEMM: BM=128, BN=128, BK=64, NBUF=2 (32 KB) ----------------
// 8 waves 2Mx4N, wave tile 64x32; grid 512 -> 2 blocks/CU.
__global__ __launch_bounds__(512, 2)
void k_pv(const unsigned char* __restrict__ A, const unsigned char* __restrict__ B,
          unsigned short* __restrict__ C, const float* __restrict__ rinv,
          int M, int N, int K, int ldA, int ldB,
          size_t sA, size_t sB, size_t sC, int gx, int gy)
{
  __shared__ __align__(16) unsigned char As[2 * 8192];   // 16 KB
  __shared__ __align__(16) unsigned char Bs[2 * 8192];   // 16 KB

  const int lin = blockIdx.x;
  const int nwg = gridDim.x;
  const int wg = ((lin & 7) * (nwg >> 3)) + (lin >> 3);
  const int bx = wg % gx;
  const int t2 = wg / gx;
  const int by = t2 % gy;
  const int bz = t2 / gy;

  const unsigned char* Ab = A + (size_t)bz * sA;
  const unsigned char* Bb = B + (size_t)bz * sB;
  const int brow = bx * 128;
  const int bcol = by * 128;
  const int t = threadIdx.x;
  const int lane = t & 63;
  const int wid = t >> 6;
  const int wr = wid >> 2;        // 0..1 (64 rows each)
  const int wc = wid & 3;         // 0..3 (32 cols each)
  const int la = lane & 15;
  const int lk = lane >> 4;

  const f32x4 zero = {0.f, 0.f, 0.f, 0.f};
  f32x4 acc[4][2];
#pragma unroll
  for (int m = 0; m < 4; m++)
#pragma unroll
    for (int n = 0; n < 2; n++) acc[m][n] = zero;

  const unsigned char* srcA1;
  const unsigned char* srcB1;
  {
    const int r = t >> 2, s = (t & 3) ^ ((r >> 1) & 3);
    srcA1 = Ab + (size_t)(brow + r) * ldA + s * 16;
    srcB1 = Bb + (size_t)(bcol + r) * ldB + s * 16;
  }
  auto STAGE = [&](int kt, int buf) {
    const int ko = kt * 64;
    gl_lds16b(srcA1 + ko, &As[buf * 8192 + t * 16]);
    gl_lds16b(srcB1 + ko, &Bs[buf * 8192 + t * 16]);
  };
  auto LDA8 = [&](int buf, int m) -> ll64x2 {
    const int ru = wr * 64 + m * 16 + la;
    const int slot = lk ^ ((ru >> 1) & 3);
    return *(const ll64x2*)&As[buf * 8192 + ru * 64 + slot * 16];
  };
  auto LDB8 = [&](int buf, int n) -> ll64x2 {
    const int ru = wc * 32 + n * 16 + la;
    const int slot = lk ^ ((ru >> 1) & 3);
    return *(const ll64x2*)&Bs[buf * 8192 + ru * 64 + slot * 16];
  };

  const int nk = K >> 6;    // 64
  STAGE(0, 0);
  for (int j = 0; j < nk; ++j) {
    const int bi = j & 1;
    asm volatile("s_waitcnt vmcnt(0)" ::: "memory");
    __builtin_amdgcn_s_barrier();
    __builtin_amdgcn_sched_barrier(0);
    if (j + 1 < nk) STAGE(j + 1, bi ^ 1);
    ll64x2 aq[4], bq[2];
#pragma unroll
    for (int n = 0; n < 2; n++) bq[n] = LDB8(bi, n);
#pragma unroll
    for (int m = 0; m < 4; m++) aq[m] = LDA8(bi, m);
    asm volatile("s_waitcnt lgkmcnt(0)" ::: "memory");
    __builtin_amdgcn_sched_barrier(0);
    __builtin_amdgcn_s_setprio(1);
#pragma unroll
    for (int m = 0; m < 4; m++)
#pragma unroll
      for (int n = 0; n < 2; n++) {
        acc[m][n] = __builtin_amdgcn_mfma_f32_16x16x32_fp8_fp8(aq[m][0], bq[n][0], acc[m][n], 0, 0, 0);
        acc[m][n] = __builtin_amdgcn_mfma_f32_16x16x32_fp8_fp8(aq[m][1], bq[n][1], acc[m][n], 0, 0, 0);
      }
    __builtin_amdgcn_s_setprio(0);
    __builtin_amdgcn_sched_barrier(0);
  }

  const int cl = la;
  const int rg = lk * 4;
  const int rowbase = brow + wr * 64;
  const int colbase = bcol + wc * 32;
  unsigned short* Cb = C + (size_t)bz * sC;
  const float* rb = rinv + (size_t)bz * 4096;
#pragma unroll
  for (int m = 0; m < 4; m++) {
    const float4 ri = *(const float4*)&rb[rowbase + m * 16 + rg];
    const float riv[4] = {ri.x, ri.y, ri.z, ri.w};
#pragma unroll
    for (int n = 0; n < 2; n++) {
      const int col = colbase + n * 16 + cl;
#pragma unroll
      for (int j = 0; j < 4; j++) {
        const int row = rowbase + m * 16 + rg + j;
        Cb[(size_t)row * N + col] = f2bf(acc[m][n][j] * riv[j]);
      }
    }
  }
}

// ---------------- rowsum reduce ----------------
__global__ __launch_bounds__(256) void rowsum_inv(const float* __restrict__ partial,
                                                  float* __restrict__ rinv){
  const int idx = blockIdx.x * 256 + threadIdx.x;
  const int b = idx >> 12, q = idx & 4095;
  const float* p = partial + ((size_t)b * 64) * 4096 + q;
  float s = 0.f;
#pragma unroll
  for (int i = 0; i < 64; i++) s += p[(size_t)i * 4096];
  rinv[idx] = 1.f / s;
}

extern "C" void kernel_launch(void* const* d_in, const int* in_sizes, int n_in,
                              void* d_out, int out_size, void* d_ws, size_t ws_size,
                              hipStream_t stream) {
  const float* x     = (const float*)d_in[0];
  const float* mask  = (const float*)d_in[1];
  const float* gamma = (const float*)d_in[2];
  const float* beta  = (const float*)d_in[3];
  const float* Wq    = (const float*)d_in[4];
  const float* bq    = (const float*)d_in[5];
  const float* Wk    = (const float*)d_in[6];
  const float* bk    = (const float*)d_in[7];
  const float* Wv    = (const float*)d_in[8];
  const float* bv    = (const float*)d_in[9];
  const float* Wo    = (const float*)d_in[10];
  const float* bo    = (const float*)d_in[11];
  float* out = (float*)d_out;

  size_t off = 0;
  auto nxt = [&](size_t bytes) -> void* {
    void* p = (char*)d_ws + off;
    off += (bytes + 255) & ~(size_t)255;
    return p;
  };
  float* stats          = (float*)nxt(256 * sizeof(float));
  float* spart          = (float*)nxt(2048 * sizeof(float));
  float* partial        = (float*)nxt((size_t)4 * 64 * 4096 * 4);
  float* rinv           = (float*)nxt((size_t)16384 * 4);
  unsigned short* Wqkb  = (unsigned short*)nxt((size_t)1024 * 512 * 2);
  unsigned short* Wvb   = (unsigned short*)nxt((size_t)512 * 512 * 2);
  unsigned short* Wob   = (unsigned short*)nxt((size_t)512 * 512 * 2);
  unsigned short* hnt   = (unsigned short*)nxt((size_t)16384 * 512 * 2);   // [b*4096+p][c] bf16
  unsigned char*  qk8   = (unsigned char*)nxt((size_t)2 * 16384 * 512);    // qt8 | kt8 fp8 k-ilv
  unsigned char*  vcm8  = (unsigned char*)nxt((size_t)4 * 512 * 4096);     // [b][c][p] fp8 k-ilv
  unsigned short* ot    = (unsigned short*)nxt((size_t)16384 * 512 * 2);   // bf16
  unsigned char*  P8    = (unsigned char*)nxt((size_t)4 * 4096 * 4096);    // fp8 k-ilv cols

  conv4<<<512, 256, 0, stream>>>(Wq, Wk, Wv, Wo, Wqkb, Wvb, Wob);

  gn_stats1<<<1024, 256, 0, stream>>>(x, spart);
  gn_stats2<<<1, 128, 0, stream>>>(spart, stats);
  gn_apply<<<dim3(128, 8, 4), 256, 0, stream>>>(x, stats, gamma, beta, hnt);

  // fused QK proj -> fp8 qt8/kt8 (k-interleaved); gx=64, gy=8 -> 512
  k_qkproj<<<512, 512, 0, stream>>>(hnt, Wqkb, qk8, nullptr, bq, bk,
                                    16384, 1024, 512, 0, 0, 0, 64, 8);
  // V proj -> fp8 vcm8[b][c][p] (p k-interleaved); gx=2, gy=32, gz=4 -> 256
  k_vproj<<<256, 512, 0, stream>>>(Wvb, hnt, vcm8, nullptr, bv, nullptr,
                                   512, 4096, 512,
                                   0, (size_t)4096 * 512, (size_t)512 * 4096, 2, 32);
  // scores (fp8 in, fp8 P out + f32 partials); gx=16, gy=16, gz=4 -> 1024
  k_scores<<<1024, 512, 0, stream>>>(qk8, qk8 + (size_t)8388608, P8, mask, partial,
                                     4096, 4096, 512, 512, 512, 0.044194173824159216f,
                                     (size_t)4096 * 512, (size_t)4096 * 512,
                                     (size_t)4096 * 4096, 16, 16);
  rowsum_inv<<<64, 256, 0, stream>>>(partial, rinv);
  // PV (fp8 in, bf16 ot out, *rinv); gx=32, gy=4, gz=4 -> 512
  k_pv<<<512, 512, 0, stream>>>(P8, vcm8, ot, rinv,
                                4096, 512, 4096, 4096, 4096,
                                (size_t)4096 * 4096, (size_t)512 * 4096,
                                (size_t)4096 * 512, 32, 4);
  // O-projection + residual + bias -> fp32 out; gx=64, gy=4 -> 256
  k_oproj<<<256, 512, 0, stream>>>(ot, Wob, out, x, bo, 64, 4);
}

// Round 12
// 237.837 us; speedup vs baseline: 1.0288x; 1.0288x over previous
//
#include <hip/hip_runtime.h>
#include <hip/hip_bf16.h>
#include <stdint.h>

typedef __attribute__((ext_vector_type(4))) float f32x4;
typedef __attribute__((ext_vector_type(16))) float f32x16;
typedef __attribute__((ext_vector_type(8))) __bf16 bf16x8;
typedef __attribute__((ext_vector_type(8))) unsigned short u16x8;
typedef __attribute__((ext_vector_type(4))) int i32x4;
typedef __attribute__((ext_vector_type(8))) int i32x8;
typedef long long ll64;
typedef __attribute__((ext_vector_type(2))) long long ll64x2;

__device__ __forceinline__ unsigned short f2bf(float f){
  uint32_t u = __builtin_bit_cast(uint32_t, f);
  u += 0x7FFFu + ((u >> 16) & 1u);
  return (unsigned short)(u >> 16);
}
__device__ __forceinline__ float bf2f(unsigned short h){
  return __builtin_bit_cast(float, ((uint32_t)h) << 16);
}
__device__ __forceinline__ float fast_exp2(float x){
#if __has_builtin(__builtin_amdgcn_exp2f)
  return __builtin_amdgcn_exp2f(x);
#else
  return exp2f(x);
#endif
}
__device__ __forceinline__ unsigned char f2fp8(float f){
#if __has_builtin(__builtin_amdgcn_cvt_pk_fp8_f32)
  int r = __builtin_amdgcn_cvt_pk_fp8_f32(f, f, 0, false);
  return (unsigned char)(r & 0xff);
#else
  uint32_t u = __builtin_bit_cast(uint32_t, f);
  uint32_t s = (u >> 24) & 0x80u;
  uint32_t a = u & 0x7fffffffu;
  float af = __builtin_bit_cast(float, a);
  if (af >= 448.f) return (unsigned char)(s | 0x7e);
  a += 0x000fffffu + ((a >> 20) & 1u);
  int e = (int)(a >> 23) - 127;
  if (e < -6) return (unsigned char)s;
  return (unsigned char)(s | (uint32_t)((e + 7) << 3) | ((a >> 20) & 7u));
#endif
}
// k-interleave permutation: lane lk's two 8B chunks (true k lk*8, 32+lk*8) contiguous
__device__ __forceinline__ int perm64(int c){
  return (c & ~63) | (((c >> 3) & 3) << 4) | (((c >> 5) & 1) << 3) | (c & 7);
}
__device__ __forceinline__ void gl_lds16(const unsigned short* g, unsigned short* l){
  __builtin_amdgcn_global_load_lds(
      (const __attribute__((address_space(1))) uint32_t*)g,
      (__attribute__((address_space(3))) uint32_t*)l, 16, 0, 0);
}
__device__ __forceinline__ void gl_lds16b(const unsigned char* g, unsigned char* l){
  __builtin_amdgcn_global_load_lds(
      (const __attribute__((address_space(1))) uint32_t*)g,
      (__attribute__((address_space(3))) uint32_t*)l, 16, 0, 0);
}

// 32x32 K=64 fp8 MFMA: scaled-MX with unit scales (2.3x rate) or 4x non-scaled fallback
__device__ __forceinline__ f32x16 mfma8_32x32x64(i32x8 a, i32x8 b, f32x16 c){
#if __has_builtin(__builtin_amdgcn_mfma_scale_f32_32x32x64_f8f6f4)
  return __builtin_amdgcn_mfma_scale_f32_32x32x64_f8f6f4(a, b, c, 0, 0,
                                                         0, 0x7f7f7f7f, 0, 0x7f7f7f7f);
#else
  ll64x2 al = __builtin_bit_cast(ll64x2, *(i32x4*)&a);
  ll64x2 ah; ah[0] = ((ll64*)&a)[2]; ah[1] = ((ll64*)&a)[3];
  ll64x2 bl = __builtin_bit_cast(ll64x2, *(i32x4*)&b);
  ll64x2 bh; bh[0] = ((ll64*)&b)[2]; bh[1] = ((ll64*)&b)[3];
  c = __builtin_amdgcn_mfma_f32_32x32x16_fp8_fp8(al[0], bl[0], c, 0, 0, 0);
  c = __builtin_amdgcn_mfma_f32_32x32x16_fp8_fp8(al[1], bl[1], c, 0, 0, 0);
  c = __builtin_amdgcn_mfma_f32_32x32x16_fp8_fp8(ah[0], bh[0], c, 0, 0, 0);
  c = __builtin_amdgcn_mfma_f32_32x32x16_fp8_fp8(ah[1], bh[1], c, 0, 0, 0);
  return c;
#endif
}

// ---------------- fp32 -> bf16 convert: Wq|Wk concat, Wv, Wo ----------------
__global__ __launch_bounds__(256) void conv4(const float* __restrict__ a, const float* __restrict__ b,
                                             const float* __restrict__ c, const float* __restrict__ d,
                                             unsigned short* __restrict__ oqk,
                                             unsigned short* __restrict__ ov,
                                             unsigned short* __restrict__ oo){
  const int bid = blockIdx.x;
  const int sel = bid >> 7;
  const float* in = sel == 0 ? a : sel == 1 ? b : sel == 2 ? c : d;
  unsigned short* out = sel == 0 ? oqk : sel == 1 ? (oqk + 262144) : sel == 2 ? ov : oo;
  const int i = ((bid & 127) * 256 + threadIdx.x) * 8;
  float4 v0 = *(const float4*)&in[i];
  float4 v1 = *(const float4*)&in[i + 4];
  u16x8 o;
  o[0]=f2bf(v0.x); o[1]=f2bf(v0.y); o[2]=f2bf(v0.z); o[3]=f2bf(v0.w);
  o[4]=f2bf(v1.x); o[5]=f2bf(v1.y); o[6]=f2bf(v1.z); o[7]=f2bf(v1.w);
  *(u16x8*)&out[i] = o;
}

// ---------------- GroupNorm stats, 2-stage ----------------
__global__ __launch_bounds__(256) void gn_stats1(const float* __restrict__ x,
                                                 float* __restrict__ part){
  const int bid = blockIdx.x;
  const float* p = x + (size_t)bid * 8192;
  float s = 0.f, ss = 0.f;
  for (int i = threadIdx.x; i < 2048; i += 256) {
    float4 v = *(const float4*)(p + (size_t)i * 4);
    s  += v.x + v.y + v.z + v.w;
    ss += v.x*v.x + v.y*v.y + v.z*v.z + v.w*v.w;
  }
  for (int off = 32; off; off >>= 1) { s += __shfl_down(s, off); ss += __shfl_down(ss, off); }
  __shared__ float red[8];
  int w = threadIdx.x >> 6;
  if ((threadIdx.x & 63) == 0) { red[w] = s; red[w + 4] = ss; }
  __syncthreads();
  if (threadIdx.x == 0) {
    part[bid * 2]     = red[0] + red[1] + red[2] + red[3];
    part[bid * 2 + 1] = red[4] + red[5] + red[6] + red[7];
  }
}
__global__ __launch_bounds__(128) void gn_stats2(const float* __restrict__ part,
                                                 float* __restrict__ stats){
  const int g = threadIdx.x;
  float s = 0.f, ss = 0.f;
#pragma unroll
  for (int i = 0; i < 8; i++) { s += part[(g * 8 + i) * 2]; ss += part[(g * 8 + i) * 2 + 1]; }
  float mean = s * (1.f / 65536.f);
  float var  = ss * (1.f / 65536.f) - mean * mean;
  stats[g * 2]     = mean;
  stats[g * 2 + 1] = rsqrtf(var + 1e-6f);
}

// ---------------- GN apply + transpose ----------------
__global__ __launch_bounds__(256) void gn_apply(const float* __restrict__ x,
                                                const float* __restrict__ stats,
                                                const float* __restrict__ gamma,
                                                const float* __restrict__ beta,
                                                unsigned short* __restrict__ hn_t){
  __shared__ float tile[64][33];
  const int b  = blockIdx.z;
  const int c0 = blockIdx.y * 64;
  const int p0 = blockIdx.x * 32;
  const int t  = threadIdx.x;
  const float* xb = x + (size_t)b * 512 * 4096;
  const int lpx = t & 31, lcc = t >> 5;
#pragma unroll
  for (int i = 0; i < 8; i++)
    tile[lcc + i * 8][lpx] = xb[(size_t)(c0 + lcc + i * 8) * 4096 + p0 + lpx];
  __syncthreads();
  unsigned short* hb = hn_t + (size_t)b * 4096 * 512;
  const int c   = c0 + (t & 31) * 2;
  const int pxi = t >> 5;
  const int g2  = (b * 32 + (c >> 4)) * 2;
  const float mean = stats[g2], rstd = stats[g2 + 1];
  const float ga0 = gamma[c], be0 = beta[c];
  const float ga1 = gamma[c + 1], be1 = beta[c + 1];
#pragma unroll
  for (int i = 0; i < 4; i++) {
    const int px = pxi + i * 8;
    float v0 = tile[(t & 31) * 2][px];
    float v1 = tile[(t & 31) * 2 + 1][px];
    uint32_t h0 = f2bf((v0 - mean) * rstd * ga0 + be0);
    uint32_t h1 = f2bf((v1 - mean) * rstd * ga1 + be1);
    *(uint32_t*)&hb[(size_t)(p0 + px) * 512 + c] = h0 | (h1 << 16);
  }
}

// ---------------- R5-structure bf16 GEMM (projections): BM=256, BN=128, BK=64 ----------------
template<int MODE>
__device__ __forceinline__ void gemm_body5(
    const unsigned short* __restrict__ A, const unsigned short* __restrict__ B,
    unsigned char* __restrict__ C8, float* __restrict__ OUTF,
    const float* __restrict__ auxA, const float* __restrict__ auxB,
    int M, int N, int K, size_t sA, size_t sB, size_t sC, int gx, int gy)
{
  constexpr int NF = 2;
  __shared__ __align__(16) unsigned short As[4 * 8192];
  __shared__ __align__(16) unsigned short Bs[2 * 8192];

  const int lin = blockIdx.x;
  const int nwg = gridDim.x;
  const int wg = ((lin & 7) * (nwg >> 3)) + (lin >> 3);
  const int bx = wg % gx;
  const int t2 = wg / gx;
  const int by = t2 % gy;
  const int bz = t2 / gy;

  const unsigned short* Ab = A + (size_t)bz * sA;
  const unsigned short* Bb = B + (size_t)bz * sB;
  const int brow = bx * 256;
  const int bcol = by * 128;
  const int t = threadIdx.x;
  const int lane = t & 63;
  const int wid = t >> 6;
  const int wr = wid >> 2;
  const int wc = wid & 3;
  const int la = lane & 15;
  const int lk = lane >> 4;
  const int axr = la >> 1;

  const f32x4 zero = {0.f, 0.f, 0.f, 0.f};
  f32x4 acc[8][NF];
#pragma unroll
  for (int m = 0; m < 8; m++)
#pragma unroll
    for (int n = 0; n < NF; n++) acc[m][n] = zero;

  const int ru0 = t >> 3, s0 = t & 7;
  const int gx0 = s0 ^ ((ru0 >> 1) & 7);

  auto stageA = [&](int kt, int h) {
    unsigned short* base = As + ((kt & 1) * 2 + h) * 8192;
    const size_t ko = (size_t)kt * 64;
    gl_lds16(Ab + (size_t)(brow + h * 64 + ru0) * K + ko + gx0 * 8, base + t * 8);
    gl_lds16(Ab + (size_t)(brow + 128 + h * 64 + ru0) * K + ko + gx0 * 8, base + 4096 + t * 8);
  };
  auto stageBf = [&](int kt) {
    unsigned short* base = Bs + (kt & 1) * 8192;
    const size_t ko = (size_t)kt * 64;
    gl_lds16(Bb + (size_t)(bcol + ru0) * K + ko + gx0 * 8, base + t * 8);
    gl_lds16(Bb + (size_t)(bcol + 64 + ru0) * K + ko + gx0 * 8, base + 4096 + t * 8);
  };
  auto LDA = [&](int db, int mh, int i, int kst) -> bf16x8 {
    const int ru = wr * 64 + i * 16 + la;
    const int slot = ((kst << 2) | lk) ^ axr;
    return __builtin_bit_cast(bf16x8, *(const u16x8*)&As[(db * 2 + mh) * 8192 + ru * 64 + slot * 8]);
  };
  auto LDB = [&](int db, int n2, int kst) -> bf16x8 {
    const int ru = wc * 32 + n2 * 16 + la;
    const int slot = ((kst << 2) | lk) ^ axr;
    return __builtin_bit_cast(bf16x8, *(const u16x8*)&Bs[db * 8192 + ru * 64 + slot * 8]);
  };

#define DSR5(mh) \
  bf16x8 aq[4][2], bq[2][2]; \
  _Pragma("unroll") for (int i = 0; i < 4; ++i) { aq[i][0] = LDA(db, mh, i, 0); aq[i][1] = LDA(db, mh, i, 1); } \
  _Pragma("unroll") for (int n2 = 0; n2 < 2; ++n2) { bq[n2][0] = LDB(db, n2, 0); bq[n2][1] = LDB(db, n2, 1); }

#define MM5(mh) \
  asm volatile("s_waitcnt lgkmcnt(0)" ::: "memory"); \
  __builtin_amdgcn_sched_barrier(0); \
  __builtin_amdgcn_s_setprio(1); \
  _Pragma("unroll") for (int i = 0; i < 4; ++i) \
    _Pragma("unroll") for (int n2 = 0; n2 < 2; ++n2) { \
      acc[(mh)*4+i][n2] = __builtin_amdgcn_mfma_f32_16x16x32_bf16(aq[i][0], bq[n2][0], acc[(mh)*4+i][n2], 0, 0, 0); \
      acc[(mh)*4+i][n2] = __builtin_amdgcn_mfma_f32_16x16x32_bf16(aq[i][1], bq[n2][1], acc[(mh)*4+i][n2], 0, 0, 0); } \
  __builtin_amdgcn_s_setprio(0); \
  __builtin_amdgcn_sched_barrier(0);

#define PHASE5(VMS, mh, STG) do { \
  asm volatile("s_waitcnt vmcnt(" VMS ")" ::: "memory"); \
  __builtin_amdgcn_s_barrier(); \
  DSR5(mh); \
  STG; \
  MM5(mh); \
} while (0)

  const int nk = K >> 6;
  stageA(0, 0); stageBf(0); stageA(0, 1);
  for (int j = 0; j < nk - 1; ++j) {
    const int db = j & 1;
    PHASE5("2", 0, { stageA(j + 1, 0); stageBf(j + 1); });
    PHASE5("4", 1, { stageA(j + 1, 1); });
  }
  {
    const int db = (nk - 1) & 1;
    asm volatile("s_waitcnt vmcnt(0)" ::: "memory");
    __builtin_amdgcn_s_barrier();
    { DSR5(0); MM5(0); }
    { DSR5(1); MM5(1); }
  }
#undef PHASE5
#undef MM5
#undef DSR5

  const int cl = la;
  const int rg = lk * 4;
  const int rowbase = brow + wr * 128;
  const int colbase = bcol + wc * 32;

  if (MODE == 1) {
#pragma unroll
    for (int m = 0; m < 8; m++) {
#pragma unroll
      for (int n = 0; n < NF; n++) {
        const int col = colbase + n * 16 + cl;
        const float bcv = (col < 512 ? auxA[col] : auxB[col - 512]);
        unsigned char* dst = C8 + (col < 512 ? 0 : (size_t)8388608);
        const int c9 = perm64(col & 511);
#pragma unroll
        for (int j = 0; j < 4; j++) {
          const int row = rowbase + m * 16 + rg + j;
          dst[(size_t)row * 512 + c9] = f2fp8(acc[m][n][j] + bcv);
        }
      }
    }
  } else if (MODE == 2) {
    unsigned char* Cb = C8 + (size_t)bz * sC;
#pragma unroll
    for (int m = 0; m < 8; m++) {
#pragma unroll
      for (int n = 0; n < NF; n++) {
        const int col = colbase + n * 16 + cl;
        const int cp = perm64(col);
#pragma unroll
        for (int j = 0; j < 4; j++) {
          const int row = rowbase + m * 16 + rg + j;
          Cb[(size_t)row * N + cp] = f2fp8(acc[m][n][j] + auxA[row]);
        }
      }
    }
  } else { // MODE 5
#pragma unroll
    for (int m = 0; m < 8; m++) {
      const int row = rowbase + m * 16 + rg;
      const int bb = row >> 12;
      const int p  = row & 4095;
#pragma unroll
      for (int n = 0; n < NF; n++) {
        const int col = colbase + n * 16 + cl;
        const size_t idx = ((size_t)bb * 512 + col) * 4096 + p;
        const float4 xv = *(const float4*)&auxA[idx];
        const float bv = auxB[col];
        float4 ov;
        ov.x = acc[m][n][0] + xv.x + bv;
        ov.y = acc[m][n][1] + xv.y + bv;
        ov.z = acc[m][n][2] + xv.z + bv;
        ov.w = acc[m][n][3] + xv.w + bv;
        *(float4*)&OUTF[idx] = ov;
      }
    }
  }
}

#define GEMM_ARGS const unsigned short* A, const unsigned short* B, unsigned char* C8, \
                  float* OUTF, const float* auxA, const float* auxB, \
                  int M, int N, int K, size_t sA, size_t sB, size_t sC, int gx, int gy
#define GEMM_PASS A, B, C8, OUTF, auxA, auxB, M, N, K, sA, sB, sC, gx, gy

__global__ __launch_bounds__(512, 2) void k_qkproj(GEMM_ARGS){ gemm_body5<1>(GEMM_PASS); }
__global__ __launch_bounds__(512, 2) void k_vproj (GEMM_ARGS){ gemm_body5<2>(GEMM_PASS); }

__global__ __launch_bounds__(512, 2) void k_oproj(const unsigned short* A, const unsigned short* B,
                                                  float* OUTF, const float* resid, const float* bias,
                                                  int gx, int gy){
  gemm_body5<5>(A, B, nullptr, OUTF, resid, bias, 16384, 512, 512, 0, 0, 0, gx, gy);
}

// ---------------- scaled-fp8 scores: BM=BN=256, BK=64, NBUF=2, 32x32x64 MFMA ----------------
__global__ __launch_bounds__(512, 2)
void k_scores(const unsigned char* __restrict__ A, const unsigned char* __restrict__ B,
              unsigned char* __restrict__ C, const float* __restrict__ mask,
              float* __restrict__ partial,
              int M, int N, int K, int ldA, int ldB, float scale,
              size_t sA, size_t sB, size_t sC, int gx, int gy)
{
  __shared__ __align__(16) unsigned char As[2 * 16384];   // 32 KB
  __shared__ __align__(16) unsigned char Bs[2 * 16384];   // 32 KB

  const int lin = blockIdx.x;
  const int nwg = gridDim.x;
  const int wg = ((lin & 7) * (nwg >> 3)) + (lin >> 3);
  const int bx = wg % gx;
  const int t2 = wg / gx;
  const int by = t2 % gy;
  const int bz = t2 / gy;

  const unsigned char* Ab = A + (size_t)bz * sA;
  const unsigned char* Bb = B + (size_t)bz * sB;
  const int brow = bx * 256;
  const int bcol = by * 256;
  const int t = threadIdx.x;
  const int lane = t & 63;
  const int wid = t >> 6;
  const int wr = wid >> 2;        // 0..1 (128 rows)
  const int wc = wid & 3;         // 0..3 (64 cols)
  const int l31 = lane & 31;
  const int lh  = lane >> 5;      // k-half

  f32x16 acc[4][2];
#pragma unroll
  for (int m = 0; m < 4; m++)
#pragma unroll
    for (int n = 0; n < 2; n++)
#pragma unroll
      for (int e = 0; e < 16; e++) acc[m][n][e] = 0.f;

  const unsigned char* srcA[2];
  const unsigned char* srcB[2];
#pragma unroll
  for (int c = 0; c < 2; ++c) {
    const int q = c * 512 + t, r = q >> 2, s = (q & 3) ^ ((r >> 1) & 3);
    srcA[c] = Ab + (size_t)(brow + r) * ldA + s * 16;
    srcB[c] = Bb + (size_t)(bcol + r) * ldB + s * 16;
  }
  auto STAGE = [&](int kt, int buf) {
    const int ko = kt * 64;
#pragma unroll
    for (int c = 0; c < 2; ++c) {
      gl_lds16b(srcA[c] + ko, &As[buf * 16384 + (c * 512 + t) * 16]);
      gl_lds16b(srcB[c] + ko, &Bs[buf * 16384 + (c * 512 + t) * 16]);
    }
  };
  // 32B operand read: global chunks {2h, 2h+1} live at LDS chunks {(2h)^x, (2h+1)^x}
  auto LDA32 = [&](int buf, int mb) -> i32x8 {
    const int ru = wr * 128 + mb * 32 + l31;
    const int x = (ru >> 1) & 3;
    const unsigned char* base = &As[buf * 16384 + ru * 64];
    i32x4 lo = *(const i32x4*)&base[((2 * lh) ^ x) * 16];
    i32x4 hi = *(const i32x4*)&base[((2 * lh + 1) ^ x) * 16];
    i32x8 r;
    r[0]=lo[0]; r[1]=lo[1]; r[2]=lo[2]; r[3]=lo[3];
    r[4]=hi[0]; r[5]=hi[1]; r[6]=hi[2]; r[7]=hi[3];
    return r;
  };
  auto LDB32 = [&](int buf, int nb) -> i32x8 {
    const int ru = wc * 64 + nb * 32 + l31;
    const int x = (ru >> 1) & 3;
    const unsigned char* base = &Bs[buf * 16384 + ru * 64];
    i32x4 lo = *(const i32x4*)&base[((2 * lh) ^ x) * 16];
    i32x4 hi = *(const i32x4*)&base[((2 * lh + 1) ^ x) * 16];
    i32x8 r;
    r[0]=lo[0]; r[1]=lo[1]; r[2]=lo[2]; r[3]=lo[3];
    r[4]=hi[0]; r[5]=hi[1]; r[6]=hi[2]; r[7]=hi[3];
    return r;
  };

  const int nk = K >> 6;    // 8
  STAGE(0, 0);
  for (int j = 0; j < nk; ++j) {
    const int bi = j & 1;
    asm volatile("s_waitcnt vmcnt(0)" ::: "memory");
    __builtin_amdgcn_s_barrier();
    __builtin_amdgcn_sched_barrier(0);
    if (j + 1 < nk) STAGE(j + 1, bi ^ 1);
    i32x8 aq[4], bq[2];
#pragma unroll
    for (int n = 0; n < 2; n++) bq[n] = LDB32(bi, n);
#pragma unroll
    for (int m = 0; m < 4; m++) aq[m] = LDA32(bi, m);
    asm volatile("s_waitcnt lgkmcnt(0)" ::: "memory");
    __builtin_amdgcn_sched_barrier(0);
    __builtin_amdgcn_s_setprio(1);
#pragma unroll
    for (int m = 0; m < 4; m++)
#pragma unroll
      for (int n = 0; n < 2; n++)
        acc[m][n] = mfma8_32x32x64(aq[m], bq[n], acc[m][n]);
    __builtin_amdgcn_s_setprio(0);
    __builtin_amdgcn_sched_barrier(0);
  }

  // epilogue: 32x32 C/D layout col=lane&31, row=(reg&3)+8*(reg>>2)+4*(lane>>5)
  const int rowbase = brow + wr * 128;
  const int colbase = bcol + wc * 64;
  unsigned char* Cb = C + (size_t)bz * sC;
  const float* maskb = mask + (size_t)bz * 4096;
  float* partb = partial + ((size_t)bz * 64 + (size_t)(by * 4 + wc)) * M;
  const float sc2 = scale * 1.4426950408889634f;
#pragma unroll
  for (int mi = 0; mi < 4; mi++) {
    float rsm[16];
#pragma unroll
    for (int e = 0; e < 16; e++) rsm[e] = 0.f;
#pragma unroll
    for (int ni = 0; ni < 2; ni++) {
      const int col = colbase + ni * 32 + l31;
      const float mk = maskb[col];
      const int cp = perm64(col);
#pragma unroll
      for (int g = 0; g < 4; g++) {
#pragma unroll
        for (int q = 0; q < 4; q++) {
          const int reg = g * 4 + q;
          const int row = rowbase + mi * 32 + g * 8 + 4 * lh + q;
          float v = mk * fast_exp2(acc[mi][ni][reg] * sc2);
          rsm[reg] += v;
          Cb[(size_t)row * N + cp] = f2fp8(v);
        }
      }
    }
#pragma unroll
    for (int off = 1; off < 32; off <<= 1)
#pragma unroll
      for (int e = 0; e < 16; e++) rsm[e] += __shfl_xor(rsm[e], off);
    if (l31 == 0) {
#pragma unroll
      for (int g = 0; g < 4; g++) {
        float4 v = make_float4(rsm[g*4], rsm[g*4+1], rsm[g*4+2], rsm[g*4+3]);
        *(float4*)&partb[rowbase + mi * 32 + g * 8 + 4 * lh] = v;
      }
    }
  }
}

// ---------------- scaled-fp8 PV: BM=128, BN=128, BK=64, NBUF=2, 32x32x64 MFMA ----------------
__global__ __launch_bounds__(512, 2)
void k_pv(const unsigned char* __restrict__ A, const unsigned char* __restrict__ B,
          unsigned short* __restrict__ C, const float* __restrict__ rinv,
          int M, int N, int K, int ldA, int ldB,
          size_t sA, size_t sB, size_t sC, int gx, int gy)
{
  __shared__ __align__(16) unsigned char As[2 * 8192];   // 16 KB
  __shared__ __align__(16) unsigned char Bs[2 * 8192];   // 16 KB

  const int lin = blockIdx.x;
  const int nwg = gridDim.x;
  const int wg = ((lin & 7) * (nwg >> 3)) + (lin >> 3);
  const int bx = wg % gx;
  const int t2 = wg / gx;
  const int by = t2 % gy;
  const int bz = t2 / gy;

  const unsigned char* Ab = A + (size_t)bz * sA;
  const unsigned char* Bb = B + (size_t)bz * sB;
  const int brow = bx * 128;
  const int bcol = by * 128;
  const int t = threadIdx.x;
  const int lane = t & 63;
  const int wid = t >> 6;
  const int wr = wid >> 2;        // 0..1 (64 rows)
  const int wc = wid & 3;         // 0..3 (32 cols)
  const int l31 = lane & 31;
  const int lh  = lane >> 5;

  f32x16 acc[2];
#pragma unroll
  for (int m = 0; m < 2; m++)
#pragma unroll
    for (int e = 0; e < 16; e++) acc[m][e] = 0.f;

  const unsigned char* srcA1;
  const unsigned char* srcB1;
  {
    const int r = t >> 2, s = (t & 3) ^ ((r >> 1) & 3);
    srcA1 = Ab + (size_t)(brow + r) * ldA + s * 16;
    srcB1 = Bb + (size_t)(bcol + r) * ldB + s * 16;
  }
  auto STAGE = [&](int kt, int buf) {
    const int ko = kt * 64;
    gl_lds16b(srcA1 + ko, &As[buf * 8192 + t * 16]);
    gl_lds16b(srcB1 + ko, &Bs[buf * 8192 + t * 16]);
  };
  auto LDA32 = [&](int buf, int mb) -> i32x8 {
    const int ru = wr * 64 + mb * 32 + l31;
    const int x = (ru >> 1) & 3;
    const unsigned char* base = &As[buf * 8192 + ru * 64];
    i32x4 lo = *(const i32x4*)&base[((2 * lh) ^ x) * 16];
    i32x4 hi = *(const i32x4*)&base[((2 * lh + 1) ^ x) * 16];
    i32x8 r;
    r[0]=lo[0]; r[1]=lo[1]; r[2]=lo[2]; r[3]=lo[3];
    r[4]=hi[0]; r[5]=hi[1]; r[6]=hi[2]; r[7]=hi[3];
    return r;
  };
  auto LDB32 = [&](int buf) -> i32x8 {
    const int ru = wc * 32 + l31;
    const int x = (ru >> 1) & 3;
    const unsigned char* base = &Bs[buf * 8192 + ru * 64];
    i32x4 lo = *(const i32x4*)&base[((2 * lh) ^ x) * 16];
    i32x4 hi = *(const i32x4*)&base[((2 * lh + 1) ^ x) * 16];
    i32x8 r;
    r[0]=lo[0]; r[1]=lo[1]; r[2]=lo[2]; r[3]=lo[3];
    r[4]=hi[0]; r[5]=hi[1]; r[6]=hi[2]; r[7]=hi[3];
    return r;
  };

  const int nk = K >> 6;    // 64
  STAGE(0, 0);
  for (int j = 0; j < nk; ++j) {
    const int bi = j & 1;
    asm volatile("s_waitcnt vmcnt(0)" ::: "memory");
    __builtin_amdgcn_s_barrier();
    __builtin_amdgcn_sched_barrier(0);
    if (j + 1 < nk) STAGE(j + 1, bi ^ 1);
    i32x8 aq[2], bq;
    bq = LDB32(bi);
#pragma unroll
    for (int m = 0; m < 2; m++) aq[m] = LDA32(bi, m);
    asm volatile("s_waitcnt lgkmcnt(0)" ::: "memory");
    __builtin_amdgcn_sched_barrier(0);
    __builtin_amdgcn_s_setprio(1);
#pragma unroll
    for (int m = 0; m < 2; m++)
      acc[m] = mfma8_32x32x64(aq[m], bq, acc[m]);
    __builtin_amdgcn_s_setprio(0);
    __builtin_amdgcn_sched_barrier(0);
  }

  // epilogue: 32x32 C/D layout; *rinv[row] -> bf16
  const int rowbase = brow + wr * 64;
  const int colbase = bcol + wc * 32;
  unsigned short* Cb = C + (size_t)bz * sC;
  const float* rb = rinv + (size_t)bz * 4096;
#pragma unroll
  for (int mb = 0; mb < 2; mb++) {
#pragma unroll
    for (int g = 0; g < 4; g++) {
      const int r0 = rowbase + mb * 32 + g * 8 + 4 * lh;
      const float4 ri = *(const float4*)&rb[r0];
      const float riv[4] = {ri.x, ri.y, ri.z, ri.w};
      const int col = colbase + l31;
#pragma unroll
      for (int q = 0; q < 4; q++) {
        const int reg = g * 4 + q;
        Cb[(size_t)(r0 + q) * N + col] = f2bf(acc[mb][reg] * riv[q]);
      }
    }
  }
}

// ---------------- rowsum reduce ----------------
__global__ __launch_bounds__(256) void rowsum_inv(const float* __restrict__ partial,
                                                  float* __restrict__ rinv){
  const int idx = blockIdx.x * 256 + threadIdx.x;
  const int b = idx >> 12, q = idx & 4095;
  const float* p = partial + ((size_t)b * 64) * 4096 + q;
  float s = 0.f;
#pragma unroll
  for (int i = 0; i < 64; i++) s += p[(size_t)i * 4096];
  rinv[idx] = 1.f / s;
}

extern "C" void kernel_launch(void* const* d_in, const int* in_sizes, int n_in,
                              void* d_out, int out_size, void* d_ws, size_t ws_size,
                              hipStream_t stream) {
  const float* x     = (const float*)d_in[0];
  const float* mask  = (const float*)d_in[1];
  const float* gamma = (const float*)d_in[2];
  const float* beta  = (const float*)d_in[3];
  const float* Wq    = (const float*)d_in[4];
  const float* bq    = (const float*)d_in[5];
  const float* Wk    = (const float*)d_in[6];
  const float* bk    = (const float*)d_in[7];
  const float* Wv    = (const float*)d_in[8];
  const float* bv    = (const float*)d_in[9];
  const float* Wo    = (const float*)d_in[10];
  const float* bo    = (const float*)d_in[11];
  float* out = (float*)d_out;

  size_t off = 0;
  auto nxt = [&](size_t bytes) -> void* {
    void* p = (char*)d_ws + off;
    off += (bytes + 255) & ~(size_t)255;
    return p;
  };
  float* stats          = (float*)nxt(256 * sizeof(float));
  float* spart          = (float*)nxt(2048 * sizeof(float));
  float* partial        = (float*)nxt((size_t)4 * 64 * 4096 * 4);
  float* rinv           = (float*)nxt((size_t)16384 * 4);
  unsigned short* Wqkb  = (unsigned short*)nxt((size_t)1024 * 512 * 2);
  unsigned short* Wvb   = (unsigned short*)nxt((size_t)512 * 512 * 2);
  unsigned short* Wob   = (unsigned short*)nxt((size_t)512 * 512 * 2);
  unsigned short* hnt   = (unsigned short*)nxt((size_t)16384 * 512 * 2);   // [b*4096+p][c] bf16
  unsigned char*  qk8   = (unsigned char*)nxt((size_t)2 * 16384 * 512);    // qt8 | kt8 fp8 k-ilv
  unsigned char*  vcm8  = (unsigned char*)nxt((size_t)4 * 512 * 4096);     // [b][c][p] fp8 k-ilv
  unsigned short* ot    = (unsigned short*)nxt((size_t)16384 * 512 * 2);   // bf16
  unsigned char*  P8    = (unsigned char*)nxt((size_t)4 * 4096 * 4096);    // fp8 k-ilv cols

  conv4<<<512, 256, 0, stream>>>(Wq, Wk, Wv, Wo, Wqkb, Wvb, Wob);

  gn_stats1<<<1024, 256, 0, stream>>>(x, spart);
  gn_stats2<<<1, 128, 0, stream>>>(spart, stats);
  gn_apply<<<dim3(128, 8, 4), 256, 0, stream>>>(x, stats, gamma, beta, hnt);

  // fused QK proj -> fp8 qt8/kt8 (k-interleaved); gx=64, gy=8 -> 512
  k_qkproj<<<512, 512, 0, stream>>>(hnt, Wqkb, qk8, nullptr, bq, bk,
                                    16384, 1024, 512, 0, 0, 0, 64, 8);
  // V proj -> fp8 vcm8[b][c][p] (p k-interleaved); gx=2, gy=32, gz=4 -> 256
  k_vproj<<<256, 512, 0, stream>>>(Wvb, hnt, vcm8, nullptr, bv, nullptr,
                                   512, 4096, 512,
                                   0, (size_t)4096 * 512, (size_t)512 * 4096, 2, 32);
  // scores (scaled fp8, fp8 P out + f32 partials); gx=16, gy=16, gz=4 -> 1024
  k_scores<<<1024, 512, 0, stream>>>(qk8, qk8 + (size_t)8388608, P8, mask, partial,
                                     4096, 4096, 512, 512, 512, 0.044194173824159216f,
                                     (size_t)4096 * 512, (size_t)4096 * 512,
                                     (size_t)4096 * 4096, 16, 16);
  rowsum_inv<<<64, 256, 0, stream>>>(partial, rinv);
  // PV (scaled fp8 in, bf16 ot out, *rinv); gx=32, gy=4, gz=4 -> 512
  k_pv<<<512, 512, 0, stream>>>(P8, vcm8, ot, rinv,
                                4096, 512, 4096, 4096, 4096,
                                (size_t)4096 * 4096, (size_t)512 * 4096,
                                (size_t)4096 * 512, 32, 4);
  // O-projection + residual + bias -> fp32 out; gx=64, gy=4 -> 256
  k_oproj<<<256, 512, 0, stream>>>(ot, Wob, out, x, bo, 64, 4);
}

// Round 13
// 236.720 us; speedup vs baseline: 1.0336x; 1.0047x over previous
//
#include <hip/hip_runtime.h>
#include <hip/hip_bf16.h>
#include <stdint.h>

typedef __attribute__((ext_vector_type(4))) float f32x4;
typedef __attribute__((ext_vector_type(16))) float f32x16;
typedef __attribute__((ext_vector_type(8))) __bf16 bf16x8;
typedef __attribute__((ext_vector_type(8))) unsigned short u16x8;
typedef __attribute__((ext_vector_type(4))) int i32x4;
typedef __attribute__((ext_vector_type(8))) int i32x8;
typedef long long ll64;
typedef __attribute__((ext_vector_type(2))) long long ll64x2;

__device__ __forceinline__ unsigned short f2bf(float f){
  uint32_t u = __builtin_bit_cast(uint32_t, f);
  u += 0x7FFFu + ((u >> 16) & 1u);
  return (unsigned short)(u >> 16);
}
__device__ __forceinline__ float bf2f(unsigned short h){
  return __builtin_bit_cast(float, ((uint32_t)h) << 16);
}
__device__ __forceinline__ float fast_exp2(float x){
#if __has_builtin(__builtin_amdgcn_exp2f)
  return __builtin_amdgcn_exp2f(x);
#else
  return exp2f(x);
#endif
}
__device__ __forceinline__ unsigned char f2fp8(float f){
#if __has_builtin(__builtin_amdgcn_cvt_pk_fp8_f32)
  int r = __builtin_amdgcn_cvt_pk_fp8_f32(f, f, 0, false);
  return (unsigned char)(r & 0xff);
#else
  uint32_t u = __builtin_bit_cast(uint32_t, f);
  uint32_t s = (u >> 24) & 0x80u;
  uint32_t a = u & 0x7fffffffu;
  float af = __builtin_bit_cast(float, a);
  if (af >= 448.f) return (unsigned char)(s | 0x7e);
  a += 0x000fffffu + ((a >> 20) & 1u);
  int e = (int)(a >> 23) - 127;
  if (e < -6) return (unsigned char)s;
  return (unsigned char)(s | (uint32_t)((e + 7) << 3) | ((a >> 20) & 7u));
#endif
}
// k-interleave permutation: lane lk's two 8B chunks (true k lk*8, 32+lk*8) contiguous
__device__ __forceinline__ int perm64(int c){
  return (c & ~63) | (((c >> 3) & 3) << 4) | (((c >> 5) & 1) << 3) | (c & 7);
}
__device__ __forceinline__ void gl_lds16(const unsigned short* g, unsigned short* l){
  __builtin_amdgcn_global_load_lds(
      (const __attribute__((address_space(1))) uint32_t*)g,
      (__attribute__((address_space(3))) uint32_t*)l, 16, 0, 0);
}
__device__ __forceinline__ void gl_lds16b(const unsigned char* g, unsigned char* l){
  __builtin_amdgcn_global_load_lds(
      (const __attribute__((address_space(1))) uint32_t*)g,
      (__attribute__((address_space(3))) uint32_t*)l, 16, 0, 0);
}

// 32x32 K=64 fp8 MFMA: scaled-MX with unit scales (2.3x rate) or 4x non-scaled fallback
__device__ __forceinline__ f32x16 mfma8_32x32x64(i32x8 a, i32x8 b, f32x16 c){
#if __has_builtin(__builtin_amdgcn_mfma_scale_f32_32x32x64_f8f6f4)
  return __builtin_amdgcn_mfma_scale_f32_32x32x64_f8f6f4(a, b, c, 0, 0,
                                                         0, 0x7f7f7f7f, 0, 0x7f7f7f7f);
#else
  ll64x2 al = __builtin_bit_cast(ll64x2, *(i32x4*)&a);
  ll64x2 ah; ah[0] = ((ll64*)&a)[2]; ah[1] = ((ll64*)&a)[3];
  ll64x2 bl = __builtin_bit_cast(ll64x2, *(i32x4*)&b);
  ll64x2 bh; bh[0] = ((ll64*)&b)[2]; bh[1] = ((ll64*)&b)[3];
  c = __builtin_amdgcn_mfma_f32_32x32x16_fp8_fp8(al[0], bl[0], c, 0, 0, 0);
  c = __builtin_amdgcn_mfma_f32_32x32x16_fp8_fp8(al[1], bl[1], c, 0, 0, 0);
  c = __builtin_amdgcn_mfma_f32_32x32x16_fp8_fp8(ah[0], bh[0], c, 0, 0, 0);
  c = __builtin_amdgcn_mfma_f32_32x32x16_fp8_fp8(ah[1], bh[1], c, 0, 0, 0);
  return c;
#endif
}

// ---------------- fp32 -> bf16 convert: Wq|Wk concat, Wv, Wo ----------------
__global__ __launch_bounds__(256) void conv4(const float* __restrict__ a, const float* __restrict__ b,
                                             const float* __restrict__ c, const float* __restrict__ d,
                                             unsigned short* __restrict__ oqk,
                                             unsigned short* __restrict__ ov,
                                             unsigned short* __restrict__ oo){
  const int bid = blockIdx.x;
  const int sel = bid >> 7;
  const float* in = sel == 0 ? a : sel == 1 ? b : sel == 2 ? c : d;
  unsigned short* out = sel == 0 ? oqk : sel == 1 ? (oqk + 262144) : sel == 2 ? ov : oo;
  const int i = ((bid & 127) * 256 + threadIdx.x) * 8;
  float4 v0 = *(const float4*)&in[i];
  float4 v1 = *(const float4*)&in[i + 4];
  u16x8 o;
  o[0]=f2bf(v0.x); o[1]=f2bf(v0.y); o[2]=f2bf(v0.z); o[3]=f2bf(v0.w);
  o[4]=f2bf(v1.x); o[5]=f2bf(v1.y); o[6]=f2bf(v1.z); o[7]=f2bf(v1.w);
  *(u16x8*)&out[i] = o;
}

// ---------------- GroupNorm stats, 2-stage ----------------
__global__ __launch_bounds__(256) void gn_stats1(const float* __restrict__ x,
                                                 float* __restrict__ part){
  const int bid = blockIdx.x;
  const float* p = x + (size_t)bid * 8192;
  float s = 0.f, ss = 0.f;
  for (int i = threadIdx.x; i < 2048; i += 256) {
    float4 v = *(const float4*)(p + (size_t)i * 4);
    s  += v.x + v.y + v.z + v.w;
    ss += v.x*v.x + v.y*v.y + v.z*v.z + v.w*v.w;
  }
  for (int off = 32; off; off >>= 1) { s += __shfl_down(s, off); ss += __shfl_down(ss, off); }
  __shared__ float red[8];
  int w = threadIdx.x >> 6;
  if ((threadIdx.x & 63) == 0) { red[w] = s; red[w + 4] = ss; }
  __syncthreads();
  if (threadIdx.x == 0) {
    part[bid * 2]     = red[0] + red[1] + red[2] + red[3];
    part[bid * 2 + 1] = red[4] + red[5] + red[6] + red[7];
  }
}
__global__ __launch_bounds__(128) void gn_stats2(const float* __restrict__ part,
                                                 float* __restrict__ stats){
  const int g = threadIdx.x;
  float s = 0.f, ss = 0.f;
#pragma unroll
  for (int i = 0; i < 8; i++) { s += part[(g * 8 + i) * 2]; ss += part[(g * 8 + i) * 2 + 1]; }
  float mean = s * (1.f / 65536.f);
  float var  = ss * (1.f / 65536.f) - mean * mean;
  stats[g * 2]     = mean;
  stats[g * 2 + 1] = rsqrtf(var + 1e-6f);
}

// ---------------- GN apply + transpose ----------------
__global__ __launch_bounds__(256) void gn_apply(const float* __restrict__ x,
                                                const float* __restrict__ stats,
                                                const float* __restrict__ gamma,
                                                const float* __restrict__ beta,
                                                unsigned short* __restrict__ hn_t){
  __shared__ float tile[64][33];
  const int b  = blockIdx.z;
  const int c0 = blockIdx.y * 64;
  const int p0 = blockIdx.x * 32;
  const int t  = threadIdx.x;
  const float* xb = x + (size_t)b * 512 * 4096;
  const int lpx = t & 31, lcc = t >> 5;
#pragma unroll
  for (int i = 0; i < 8; i++)
    tile[lcc + i * 8][lpx] = xb[(size_t)(c0 + lcc + i * 8) * 4096 + p0 + lpx];
  __syncthreads();
  unsigned short* hb = hn_t + (size_t)b * 4096 * 512;
  const int c   = c0 + (t & 31) * 2;
  const int pxi = t >> 5;
  const int g2  = (b * 32 + (c >> 4)) * 2;
  const float mean = stats[g2], rstd = stats[g2 + 1];
  const float ga0 = gamma[c], be0 = beta[c];
  const float ga1 = gamma[c + 1], be1 = beta[c + 1];
#pragma unroll
  for (int i = 0; i < 4; i++) {
    const int px = pxi + i * 8;
    float v0 = tile[(t & 31) * 2][px];
    float v1 = tile[(t & 31) * 2 + 1][px];
    uint32_t h0 = f2bf((v0 - mean) * rstd * ga0 + be0);
    uint32_t h1 = f2bf((v1 - mean) * rstd * ga1 + be1);
    *(uint32_t*)&hb[(size_t)(p0 + px) * 512 + c] = h0 | (h1 << 16);
  }
}

// ---------------- R5-structure bf16 GEMM (projections): BM=256, BN=128, BK=64 ----------------
template<int MODE>
__device__ __forceinline__ void gemm_body5(
    const unsigned short* __restrict__ A, const unsigned short* __restrict__ B,
    unsigned char* __restrict__ C8, float* __restrict__ OUTF,
    const float* __restrict__ auxA, const float* __restrict__ auxB,
    int M, int N, int K, size_t sA, size_t sB, size_t sC, int gx, int gy)
{
  constexpr int NF = 2;
  __shared__ __align__(16) unsigned short As[4 * 8192];
  __shared__ __align__(16) unsigned short Bs[2 * 8192];

  const int lin = blockIdx.x;
  const int nwg = gridDim.x;
  const int wg = ((lin & 7) * (nwg >> 3)) + (lin >> 3);
  const int bx = wg % gx;
  const int t2 = wg / gx;
  const int by = t2 % gy;
  const int bz = t2 / gy;

  const unsigned short* Ab = A + (size_t)bz * sA;
  const unsigned short* Bb = B + (size_t)bz * sB;
  const int brow = bx * 256;
  const int bcol = by * 128;
  const int t = threadIdx.x;
  const int lane = t & 63;
  const int wid = t >> 6;
  const int wr = wid >> 2;
  const int wc = wid & 3;
  const int la = lane & 15;
  const int lk = lane >> 4;
  const int axr = la >> 1;

  const f32x4 zero = {0.f, 0.f, 0.f, 0.f};
  f32x4 acc[8][NF];
#pragma unroll
  for (int m = 0; m < 8; m++)
#pragma unroll
    for (int n = 0; n < NF; n++) acc[m][n] = zero;

  const int ru0 = t >> 3, s0 = t & 7;
  const int gx0 = s0 ^ ((ru0 >> 1) & 7);

  auto stageA = [&](int kt, int h) {
    unsigned short* base = As + ((kt & 1) * 2 + h) * 8192;
    const size_t ko = (size_t)kt * 64;
    gl_lds16(Ab + (size_t)(brow + h * 64 + ru0) * K + ko + gx0 * 8, base + t * 8);
    gl_lds16(Ab + (size_t)(brow + 128 + h * 64 + ru0) * K + ko + gx0 * 8, base + 4096 + t * 8);
  };
  auto stageBf = [&](int kt) {
    unsigned short* base = Bs + (kt & 1) * 8192;
    const size_t ko = (size_t)kt * 64;
    gl_lds16(Bb + (size_t)(bcol + ru0) * K + ko + gx0 * 8, base + t * 8);
    gl_lds16(Bb + (size_t)(bcol + 64 + ru0) * K + ko + gx0 * 8, base + 4096 + t * 8);
  };
  auto LDA = [&](int db, int mh, int i, int kst) -> bf16x8 {
    const int ru = wr * 64 + i * 16 + la;
    const int slot = ((kst << 2) | lk) ^ axr;
    return __builtin_bit_cast(bf16x8, *(const u16x8*)&As[(db * 2 + mh) * 8192 + ru * 64 + slot * 8]);
  };
  auto LDB = [&](int db, int n2, int kst) -> bf16x8 {
    const int ru = wc * 32 + n2 * 16 + la;
    const int slot = ((kst << 2) | lk) ^ axr;
    return __builtin_bit_cast(bf16x8, *(const u16x8*)&Bs[db * 8192 + ru * 64 + slot * 8]);
  };

#define DSR5(mh) \
  bf16x8 aq[4][2], bq[2][2]; \
  _Pragma("unroll") for (int i = 0; i < 4; ++i) { aq[i][0] = LDA(db, mh, i, 0); aq[i][1] = LDA(db, mh, i, 1); } \
  _Pragma("unroll") for (int n2 = 0; n2 < 2; ++n2) { bq[n2][0] = LDB(db, n2, 0); bq[n2][1] = LDB(db, n2, 1); }

#define MM5(mh) \
  asm volatile("s_waitcnt lgkmcnt(0)" ::: "memory"); \
  __builtin_amdgcn_sched_barrier(0); \
  __builtin_amdgcn_s_setprio(1); \
  _Pragma("unroll") for (int i = 0; i < 4; ++i) \
    _Pragma("unroll") for (int n2 = 0; n2 < 2; ++n2) { \
      acc[(mh)*4+i][n2] = __builtin_amdgcn_mfma_f32_16x16x32_bf16(aq[i][0], bq[n2][0], acc[(mh)*4+i][n2], 0, 0, 0); \
      acc[(mh)*4+i][n2] = __builtin_amdgcn_mfma_f32_16x16x32_bf16(aq[i][1], bq[n2][1], acc[(mh)*4+i][n2], 0, 0, 0); } \
  __builtin_amdgcn_s_setprio(0); \
  __builtin_amdgcn_sched_barrier(0);

#define PHASE5(VMS, mh, STG) do { \
  asm volatile("s_waitcnt vmcnt(" VMS ")" ::: "memory"); \
  __builtin_amdgcn_s_barrier(); \
  DSR5(mh); \
  STG; \
  MM5(mh); \
} while (0)

  const int nk = K >> 6;
  stageA(0, 0); stageBf(0); stageA(0, 1);
  for (int j = 0; j < nk - 1; ++j) {
    const int db = j & 1;
    PHASE5("2", 0, { stageA(j + 1, 0); stageBf(j + 1); });
    PHASE5("4", 1, { stageA(j + 1, 1); });
  }
  {
    const int db = (nk - 1) & 1;
    asm volatile("s_waitcnt vmcnt(0)" ::: "memory");
    __builtin_amdgcn_s_barrier();
    { DSR5(0); MM5(0); }
    { DSR5(1); MM5(1); }
  }
#undef PHASE5
#undef MM5
#undef DSR5

  const int cl = la;
  const int rg = lk * 4;
  const int rowbase = brow + wr * 128;
  const int colbase = bcol + wc * 32;

  if (MODE == 1) {
#pragma unroll
    for (int m = 0; m < 8; m++) {
#pragma unroll
      for (int n = 0; n < NF; n++) {
        const int col = colbase + n * 16 + cl;
        const float bcv = (col < 512 ? auxA[col] : auxB[col - 512]);
        unsigned char* dst = C8 + (col < 512 ? 0 : (size_t)8388608);
        const int c9 = perm64(col & 511);
#pragma unroll
        for (int j = 0; j < 4; j++) {
          const int row = rowbase + m * 16 + rg + j;
          dst[(size_t)row * 512 + c9] = f2fp8(acc[m][n][j] + bcv);
        }
      }
    }
  } else if (MODE == 2) {
    unsigned char* Cb = C8 + (size_t)bz * sC;
#pragma unroll
    for (int m = 0; m < 8; m++) {
#pragma unroll
      for (int n = 0; n < NF; n++) {
        const int col = colbase + n * 16 + cl;
        const int cp = perm64(col);
#pragma unroll
        for (int j = 0; j < 4; j++) {
          const int row = rowbase + m * 16 + rg + j;
          Cb[(size_t)row * N + cp] = f2fp8(acc[m][n][j] + auxA[row]);
        }
      }
    }
  } else { // MODE 5
#pragma unroll
    for (int m = 0; m < 8; m++) {
      const int row = rowbase + m * 16 + rg;
      const int bb = row >> 12;
      const int p  = row & 4095;
#pragma unroll
      for (int n = 0; n < NF; n++) {
        const int col = colbase + n * 16 + cl;
        const size_t idx = ((size_t)bb * 512 + col) * 4096 + p;
        const float4 xv = *(const float4*)&auxA[idx];
        const float bv = auxB[col];
        float4 ov;
        ov.x = acc[m][n][0] + xv.x + bv;
        ov.y = acc[m][n][1] + xv.y + bv;
        ov.z = acc[m][n][2] + xv.z + bv;
        ov.w = acc[m][n][3] + xv.w + bv;
        *(float4*)&OUTF[idx] = ov;
      }
    }
  }
}

#define GEMM_ARGS const unsigned short* A, const unsigned short* B, unsigned char* C8, \
                  float* OUTF, const float* auxA, const float* auxB, \
                  int M, int N, int K, size_t sA, size_t sB, size_t sC, int gx, int gy
#define GEMM_PASS A, B, C8, OUTF, auxA, auxB, M, N, K, sA, sB, sC, gx, gy

__global__ __launch_bounds__(512, 2) void k_qkproj(GEMM_ARGS){ gemm_body5<1>(GEMM_PASS); }
__global__ __launch_bounds__(512, 2) void k_vproj (GEMM_ARGS){ gemm_body5<2>(GEMM_PASS); }

__global__ __launch_bounds__(512, 2) void k_oproj(const unsigned short* A, const unsigned short* B,
                                                  float* OUTF, const float* resid, const float* bias,
                                                  int gx, int gy){
  gemm_body5<5>(A, B, nullptr, OUTF, resid, bias, 16384, 512, 512, 0, 0, 0, gx, gy);
}

// ---------------- scaled-fp8 scores: BM=BN=256, BK=64, NBUF=2, 32x32x64 MFMA ----------------
// Epilogue routes P through LDS (reusing staging buffers) -> coalesced b128 stores.
__global__ __launch_bounds__(512, 2)
void k_scores(const unsigned char* __restrict__ A, const unsigned char* __restrict__ B,
              unsigned char* __restrict__ C, const float* __restrict__ mask,
              float* __restrict__ partial,
              int M, int N, int K, int ldA, int ldB, float scale,
              size_t sA, size_t sB, size_t sC, int gx, int gy)
{
  __shared__ __align__(16) unsigned char LDSBUF[65536];   // staging (2x32KB) then P tile 256x256
  unsigned char* As = LDSBUF;
  unsigned char* Bs = LDSBUF + 32768;

  const int lin = blockIdx.x;
  const int nwg = gridDim.x;
  const int wg = ((lin & 7) * (nwg >> 3)) + (lin >> 3);
  const int bx = wg % gx;
  const int t2 = wg / gx;
  const int by = t2 % gy;
  const int bz = t2 / gy;

  const unsigned char* Ab = A + (size_t)bz * sA;
  const unsigned char* Bb = B + (size_t)bz * sB;
  const int brow = bx * 256;
  const int bcol = by * 256;
  const int t = threadIdx.x;
  const int lane = t & 63;
  const int wid = t >> 6;
  const int wr = wid >> 2;        // 0..1 (128 rows)
  const int wc = wid & 3;         // 0..3 (64 cols)
  const int l31 = lane & 31;
  const int lh  = lane >> 5;      // k-half

  f32x16 acc[4][2];
#pragma unroll
  for (int m = 0; m < 4; m++)
#pragma unroll
    for (int n = 0; n < 2; n++)
#pragma unroll
      for (int e = 0; e < 16; e++) acc[m][n][e] = 0.f;

  const unsigned char* srcA[2];
  const unsigned char* srcB[2];
#pragma unroll
  for (int c = 0; c < 2; ++c) {
    const int q = c * 512 + t, r = q >> 2, s = (q & 3) ^ ((r >> 1) & 3);
    srcA[c] = Ab + (size_t)(brow + r) * ldA + s * 16;
    srcB[c] = Bb + (size_t)(bcol + r) * ldB + s * 16;
  }
  auto STAGE = [&](int kt, int buf) {
    const int ko = kt * 64;
#pragma unroll
    for (int c = 0; c < 2; ++c) {
      gl_lds16b(srcA[c] + ko, &As[buf * 16384 + (c * 512 + t) * 16]);
      gl_lds16b(srcB[c] + ko, &Bs[buf * 16384 + (c * 512 + t) * 16]);
    }
  };
  auto LDA32 = [&](int buf, int mb) -> i32x8 {
    const int ru = wr * 128 + mb * 32 + l31;
    const int x = (ru >> 1) & 3;
    const unsigned char* base = &As[buf * 16384 + ru * 64];
    i32x4 lo = *(const i32x4*)&base[((2 * lh) ^ x) * 16];
    i32x4 hi = *(const i32x4*)&base[((2 * lh + 1) ^ x) * 16];
    i32x8 r;
    r[0]=lo[0]; r[1]=lo[1]; r[2]=lo[2]; r[3]=lo[3];
    r[4]=hi[0]; r[5]=hi[1]; r[6]=hi[2]; r[7]=hi[3];
    return r;
  };
  auto LDB32 = [&](int buf, int nb) -> i32x8 {
    const int ru = wc * 64 + nb * 32 + l31;
    const int x = (ru >> 1) & 3;
    const unsigned char* base = &Bs[buf * 16384 + ru * 64];
    i32x4 lo = *(const i32x4*)&base[((2 * lh) ^ x) * 16];
    i32x4 hi = *(const i32x4*)&base[((2 * lh + 1) ^ x) * 16];
    i32x8 r;
    r[0]=lo[0]; r[1]=lo[1]; r[2]=lo[2]; r[3]=lo[3];
    r[4]=hi[0]; r[5]=hi[1]; r[6]=hi[2]; r[7]=hi[3];
    return r;
  };

  const int nk = K >> 6;    // 8
  STAGE(0, 0);
  for (int j = 0; j < nk; ++j) {
    const int bi = j & 1;
    asm volatile("s_waitcnt vmcnt(0)" ::: "memory");
    __builtin_amdgcn_s_barrier();
    __builtin_amdgcn_sched_barrier(0);
    if (j + 1 < nk) STAGE(j + 1, bi ^ 1);
    i32x8 aq[4], bq[2];
#pragma unroll
    for (int n = 0; n < 2; n++) bq[n] = LDB32(bi, n);
#pragma unroll
    for (int m = 0; m < 4; m++) aq[m] = LDA32(bi, m);
    asm volatile("s_waitcnt lgkmcnt(0)" ::: "memory");
    __builtin_amdgcn_sched_barrier(0);
    __builtin_amdgcn_s_setprio(1);
#pragma unroll
    for (int m = 0; m < 4; m++)
#pragma unroll
      for (int n = 0; n < 2; n++)
        acc[m][n] = mfma8_32x32x64(aq[m], bq[n], acc[m][n]);
    __builtin_amdgcn_s_setprio(0);
    __builtin_amdgcn_sched_barrier(0);
  }

  // epilogue: 32x32 C/D layout col=lane&31, row=(reg&3)+8*(reg>>2)+4*(lane>>5)
  const int rowbase = brow + wr * 128;
  const int colbase = bcol + wc * 64;
  const float* maskb = mask + (size_t)bz * 4096;
  float* partb = partial + ((size_t)bz * 64 + (size_t)(by * 4 + wc)) * M;
  const float sc2 = scale * 1.4426950408889634f;

  // wait for all waves' last-tile LDS reads, then reuse LDSBUF as P tile [256][256]
  asm volatile("s_waitcnt lgkmcnt(0)" ::: "memory");
  __builtin_amdgcn_s_barrier();

#pragma unroll
  for (int mi = 0; mi < 4; mi++) {
    float rsm[16];
#pragma unroll
    for (int e = 0; e < 16; e++) rsm[e] = 0.f;
#pragma unroll
    for (int ni = 0; ni < 2; ni++) {
      const int col = colbase + ni * 32 + l31;
      const float mk = maskb[col];
      const int ccl = wc * 64 + perm64(ni * 32 + l31);   // block-local perm'd col
#pragma unroll
      for (int g = 0; g < 4; g++) {
#pragma unroll
        for (int q = 0; q < 4; q++) {
          const int reg = g * 4 + q;
          const int rl = wr * 128 + mi * 32 + g * 8 + 4 * lh + q;  // block-local row
          float v = mk * fast_exp2(acc[mi][ni][reg] * sc2);
          rsm[reg] += v;
          LDSBUF[rl * 256 + (ccl ^ (((rl >> 2) & 1) << 5))] = f2fp8(v);
        }
      }
    }
#pragma unroll
    for (int off = 1; off < 32; off <<= 1)
#pragma unroll
      for (int e = 0; e < 16; e++) rsm[e] += __shfl_xor(rsm[e], off);
    if (l31 == 0) {
#pragma unroll
      for (int g = 0; g < 4; g++) {
        float4 v = make_float4(rsm[g*4], rsm[g*4+1], rsm[g*4+2], rsm[g*4+3]);
        *(float4*)&partb[rowbase + mi * 32 + g * 8 + 4 * lh] = v;
      }
    }
  }
  __builtin_amdgcn_s_barrier();
  // coalesced copy: 4096 16B chunks, 8 per thread
  unsigned char* Cb = C + (size_t)bz * sC;
#pragma unroll
  for (int i = 0; i < 8; i++) {
    const int ch = i * 512 + t;
    const int rl = ch >> 4;              // 16 chunks per 256B row
    const int c16 = (ch & 15) * 16;
    i32x4 v = *(const i32x4*)&LDSBUF[rl * 256 + (c16 ^ (((rl >> 2) & 1) << 5))];
    *(i32x4*)&Cb[(size_t)(brow + rl) * N + bcol + c16] = v;
  }
}

// ---------------- scaled-fp8 PV: BM=128, BN=128, BK=64, NBUF=2, 32x32x64 MFMA ----------------
// Epilogue routes O (bf16 128x128) through LDS -> coalesced b128 stores.
__global__ __launch_bounds__(512, 2)
void k_pv(const unsigned char* __restrict__ A, const unsigned char* __restrict__ B,
          unsigned short* __restrict__ C, const float* __restrict__ rinv,
          int M, int N, int K, int ldA, int ldB,
          size_t sA, size_t sB, size_t sC, int gx, int gy)
{
  __shared__ __align__(16) unsigned char LDSBUF[32768];  // staging then O tile 128x128 bf16
  unsigned char* As = LDSBUF;
  unsigned char* Bs = LDSBUF + 16384;

  const int lin = blockIdx.x;
  const int nwg = gridDim.x;
  const int wg = ((lin & 7) * (nwg >> 3)) + (lin >> 3);
  const int bx = wg % gx;
  const int t2 = wg / gx;
  const int by = t2 % gy;
  const int bz = t2 / gy;

  const unsigned char* Ab = A + (size_t)bz * sA;
  const unsigned char* Bb = B + (size_t)bz * sB;
  const int brow = bx * 128;
  const int bcol = by * 128;
  const int t = threadIdx.x;
  const int lane = t & 63;
  const int wid = t >> 6;
  const int wr = wid >> 2;        // 0..1 (64 rows)
  const int wc = wid & 3;         // 0..3 (32 cols)
  const int l31 = lane & 31;
  const int lh  = lane >> 5;

  f32x16 acc[2];
#pragma unroll
  for (int m = 0; m < 2; m++)
#pragma unroll
    for (int e = 0; e < 16; e++) acc[m][e] = 0.f;

  const unsigned char* srcA1;
  const unsigned char* srcB1;
  {
    const int r = t >> 2, s = (t & 3) ^ ((r >> 1) & 3);
    srcA1 = Ab + (size_t)(brow + r) * ldA + s * 16;
    srcB1 = Bb + (size_t)(bcol + r) * ldB + s * 16;
  }
  auto STAGE = [&](int kt, int buf) {
    const int ko = kt * 64;
    gl_lds16b(srcA1 + ko, &As[buf * 8192 + t * 16]);
    gl_lds16b(srcB1 + ko, &Bs[buf * 8192 + t * 16]);
  };
  auto LDA32 = [&](int buf, int mb) -> i32x8 {
    const int ru = wr * 64 + mb * 32 + l31;
    const int x = (ru >> 1) & 3;
    const unsigned char* base = &As[buf * 8192 + ru * 64];
    i32x4 lo = *(const i32x4*)&base[((2 * lh) ^ x) * 16];
    i32x4 hi = *(const i32x4*)&base[((2 * lh + 1) ^ x) * 16];
    i32x8 r;
    r[0]=lo[0]; r[1]=lo[1]; r[2]=lo[2]; r[3]=lo[3];
    r[4]=hi[0]; r[5]=hi[1]; r[6]=hi[2]; r[7]=hi[3];
    return r;
  };
  auto LDB32 = [&](int buf) -> i32x8 {
    const int ru = wc * 32 + l31;
    const int x = (ru >> 1) & 3;
    const unsigned char* base = &Bs[buf * 8192 + ru * 64];
    i32x4 lo = *(const i32x4*)&base[((2 * lh) ^ x) * 16];
    i32x4 hi = *(const i32x4*)&base[((2 * lh + 1) ^ x) * 16];
    i32x8 r;
    r[0]=lo[0]; r[1]=lo[1]; r[2]=lo[2]; r[3]=lo[3];
    r[4]=hi[0]; r[5]=hi[1]; r[6]=hi[2]; r[7]=hi[3];
    return r;
  };

  const int nk = K >> 6;    // 64
  STAGE(0, 0);
  for (int j = 0; j < nk; ++j) {
    const int bi = j & 1;
    asm volatile("s_waitcnt vmcnt(0)" ::: "memory");
    __builtin_amdgcn_s_barrier();
    __builtin_amdgcn_sched_barrier(0);
    if (j + 1 < nk) STAGE(j + 1, bi ^ 1);
    i32x8 aq[2], bq;
    bq = LDB32(bi);
#pragma unroll
    for (int m = 0; m < 2; m++) aq[m] = LDA32(bi, m);
    asm volatile("s_waitcnt lgkmcnt(0)" ::: "memory");
    __builtin_amdgcn_sched_barrier(0);
    __builtin_amdgcn_s_setprio(1);
#pragma unroll
    for (int m = 0; m < 2; m++)
      acc[m] = mfma8_32x32x64(aq[m], bq, acc[m]);
    __builtin_amdgcn_s_setprio(0);
    __builtin_amdgcn_sched_barrier(0);
  }

  // epilogue: *rinv[row] -> bf16 via LDS tile [128][128] (row stride 256 B)
  const int rowbase = brow + wr * 64;
  const float* rb = rinv + (size_t)bz * 4096;
  asm volatile("s_waitcnt lgkmcnt(0)" ::: "memory");
  __builtin_amdgcn_s_barrier();
#pragma unroll
  for (int mb = 0; mb < 2; mb++) {
#pragma unroll
    for (int g = 0; g < 4; g++) {
      const int rl = wr * 64 + mb * 32 + g * 8 + 4 * lh;   // block-local row
      const float4 ri = *(const float4*)&rb[brow + rl];
      const float riv[4] = {ri.x, ri.y, ri.z, ri.w};
      const int cb = (wc * 32 + l31) * 2;                  // byte offset of col
#pragma unroll
      for (int q = 0; q < 4; q++) {
        const int reg = g * 4 + q;
        const int r2 = rl + q;
        *(unsigned short*)&LDSBUF[r2 * 256 + (cb ^ (((r2 >> 2) & 1) << 5))] =
            f2bf(acc[mb][reg] * riv[q]);
      }
    }
  }
  __builtin_amdgcn_s_barrier();
  // coalesced copy: 2048 16B chunks, 4 per thread
  unsigned short* Cb = C + (size_t)bz * sC;
#pragma unroll
  for (int i = 0; i < 4; i++) {
    const int ch = i * 512 + t;
    const int rl = ch >> 4;
    const int c16 = (ch & 15) * 16;
    i32x4 v = *(const i32x4*)&LDSBUF[rl * 256 + (c16 ^ (((rl >> 2) & 1) << 5))];
    *(i32x4*)&Cb[(size_t)(brow + rl) * N + bcol + (c16 >> 1)] = v;
  }
}

// ---------------- rowsum reduce ----------------
__global__ __launch_bounds__(256) void rowsum_inv(const float* __restrict__ partial,
                                                  float* __restrict__ rinv){
  const int idx = blockIdx.x * 256 + threadIdx.x;
  const int b = idx >> 12, q = idx & 4095;
  const float* p = partial + ((size_t)b * 64) * 4096 + q;
  float s = 0.f;
#pragma unroll
  for (int i = 0; i < 64; i++) s += p[(size_t)i * 4096];
  rinv[idx] = 1.f / s;
}

extern "C" void kernel_launch(void* const* d_in, const int* in_sizes, int n_in,
                              void* d_out, int out_size, void* d_ws, size_t ws_size,
                              hipStream_t stream) {
  const float* x     = (const float*)d_in[0];
  const float* mask  = (const float*)d_in[1];
  const float* gamma = (const float*)d_in[2];
  const float* beta  = (const float*)d_in[3];
  const float* Wq    = (const float*)d_in[4];
  const float* bq    = (const float*)d_in[5];
  const float* Wk    = (const float*)d_in[6];
  const float* bk    = (const float*)d_in[7];
  const float* Wv    = (const float*)d_in[8];
  const float* bv    = (const float*)d_in[9];
  const float* Wo    = (const float*)d_in[10];
  const float* bo    = (const float*)d_in[11];
  float* out = (float*)d_out;

  size_t off = 0;
  auto nxt = [&](size_t bytes) -> void* {
    void* p = (char*)d_ws + off;
    off += (bytes + 255) & ~(size_t)255;
    return p;
  };
  float* stats          = (float*)nxt(256 * sizeof(float));
  float* spart          = (float*)nxt(2048 * sizeof(float));
  float* partial        = (float*)nxt((size_t)4 * 64 * 4096 * 4);
  float* rinv           = (float*)nxt((size_t)16384 * 4);
  unsigned short* Wqkb  = (unsigned short*)nxt((size_t)1024 * 512 * 2);
  unsigned short* Wvb   = (unsigned short*)nxt((size_t)512 * 512 * 2);
  unsigned short* Wob   = (unsigned short*)nxt((size_t)512 * 512 * 2);
  unsigned short* hnt   = (unsigned short*)nxt((size_t)16384 * 512 * 2);   // [b*4096+p][c] bf16
  unsigned char*  qk8   = (unsigned char*)nxt((size_t)2 * 16384 * 512);    // qt8 | kt8 fp8 k-ilv
  unsigned char*  vcm8  = (unsigned char*)nxt((size_t)4 * 512 * 4096);     // [b][c][p] fp8 k-ilv
  unsigned short* ot    = (unsigned short*)nxt((size_t)16384 * 512 * 2);   // bf16
  unsigned char*  P8    = (unsigned char*)nxt((size_t)4 * 4096 * 4096);    // fp8 k-ilv cols

  conv4<<<512, 256, 0, stream>>>(Wq, Wk, Wv, Wo, Wqkb, Wvb, Wob);

  gn_stats1<<<1024, 256, 0, stream>>>(x, spart);
  gn_stats2<<<1, 128, 0, stream>>>(spart, stats);
  gn_apply<<<dim3(128, 8, 4), 256, 0, stream>>>(x, stats, gamma, beta, hnt);

  // fused QK proj -> fp8 qt8/kt8 (k-interleaved); gx=64, gy=8 -> 512
  k_qkproj<<<512, 512, 0, stream>>>(hnt, Wqkb, qk8, nullptr, bq, bk,
                                    16384, 1024, 512, 0, 0, 0, 64, 8);
  // V proj -> fp8 vcm8[b][c][p] (p k-interleaved); gx=2, gy=32, gz=4 -> 256
  k_vproj<<<256, 512, 0, stream>>>(Wvb, hnt, vcm8, nullptr, bv, nullptr,
                                   512, 4096, 512,
                                   0, (size_t)4096 * 512, (size_t)512 * 4096, 2, 32);
  // scores (scaled fp8, fp8 P out + f32 partials); gx=16, gy=16, gz=4 -> 1024
  k_scores<<<1024, 512, 0, stream>>>(qk8, qk8 + (size_t)8388608, P8, mask, partial,
                                     4096, 4096, 512, 512, 512, 0.044194173824159216f,
                                     (size_t)4096 * 512, (size_t)4096 * 512,
                                     (size_t)4096 * 4096, 16, 16);
  rowsum_inv<<<64, 256, 0, stream>>>(partial, rinv);
  // PV (scaled fp8 in, bf16 ot out, *rinv); gx=32, gy=4, gz=4 -> 512
  k_pv<<<512, 512, 0, stream>>>(P8, vcm8, ot, rinv,
                                4096, 512, 4096, 4096, 4096,
                                (size_t)4096 * 4096, (size_t)512 * 4096,
                                (size_t)4096 * 512, 32, 4);
  // O-projection + residual + bias -> fp32 out; gx=64, gy=4 -> 256
  k_oproj<<<256, 512, 0, stream>>>(ot, Wob, out, x, bo, 64, 4);
}

// Round 14
// 222.205 us; speedup vs baseline: 1.1011x; 1.0653x over previous
//
#include <hip/hip_runtime.h>
#include <hip/hip_bf16.h>
#include <stdint.h>

typedef __attribute__((ext_vector_type(4))) float f32x4;
typedef __attribute__((ext_vector_type(16))) float f32x16;
typedef __attribute__((ext_vector_type(8))) unsigned short u16x8;
typedef __attribute__((ext_vector_type(4))) int i32x4;
typedef __attribute__((ext_vector_type(8))) int i32x8;
typedef long long ll64;
typedef __attribute__((ext_vector_type(2))) long long ll64x2;

__device__ __forceinline__ unsigned short f2bf(float f){
  uint32_t u = __builtin_bit_cast(uint32_t, f);
  u += 0x7FFFu + ((u >> 16) & 1u);
  return (unsigned short)(u >> 16);
}
__device__ __forceinline__ float fast_exp2(float x){
#if __has_builtin(__builtin_amdgcn_exp2f)
  return __builtin_amdgcn_exp2f(x);
#else
  return exp2f(x);
#endif
}
__device__ __forceinline__ unsigned char f2fp8(float f){
#if __has_builtin(__builtin_amdgcn_cvt_pk_fp8_f32)
  int r = __builtin_amdgcn_cvt_pk_fp8_f32(f, f, 0, false);
  return (unsigned char)(r & 0xff);
#else
  uint32_t u = __builtin_bit_cast(uint32_t, f);
  uint32_t s = (u >> 24) & 0x80u;
  uint32_t a = u & 0x7fffffffu;
  float af = __builtin_bit_cast(float, a);
  if (af >= 448.f) return (unsigned char)(s | 0x7e);
  a += 0x000fffffu + ((a >> 20) & 1u);
  int e = (int)(a >> 23) - 127;
  if (e < -6) return (unsigned char)s;
  return (unsigned char)(s | (uint32_t)((e + 7) << 3) | ((a >> 20) & 7u));
#endif
}
// k-interleave permutation: lane lk's two 8B chunks (true k lk*8, 32+lk*8) contiguous
__device__ __forceinline__ int perm64(int c){
  return (c & ~63) | (((c >> 3) & 3) << 4) | (((c >> 5) & 1) << 3) | (c & 7);
}
__device__ __forceinline__ void gl_lds16b(const unsigned char* g, unsigned char* l){
  __builtin_amdgcn_global_load_lds(
      (const __attribute__((address_space(1))) uint32_t*)g,
      (__attribute__((address_space(3))) uint32_t*)l, 16, 0, 0);
}

// 32x32 K=64 fp8 MFMA: scaled-MX with unit scales (2.3x rate) or 4x non-scaled fallback
__device__ __forceinline__ f32x16 mfma8_32x32x64(i32x8 a, i32x8 b, f32x16 c){
#if __has_builtin(__builtin_amdgcn_mfma_scale_f32_32x32x64_f8f6f4)
  return __builtin_amdgcn_mfma_scale_f32_32x32x64_f8f6f4(a, b, c, 0, 0,
                                                         0, 0x7f7f7f7f, 0, 0x7f7f7f7f);
#else
  ll64x2 al = __builtin_bit_cast(ll64x2, *(i32x4*)&a);
  ll64x2 ah; ah[0] = ((ll64*)&a)[2]; ah[1] = ((ll64*)&a)[3];
  ll64x2 bl = __builtin_bit_cast(ll64x2, *(i32x4*)&b);
  ll64x2 bh; bh[0] = ((ll64*)&b)[2]; bh[1] = ((ll64*)&b)[3];
  c = __builtin_amdgcn_mfma_f32_32x32x16_fp8_fp8(al[0], bl[0], c, 0, 0, 0);
  c = __builtin_amdgcn_mfma_f32_32x32x16_fp8_fp8(al[1], bl[1], c, 0, 0, 0);
  c = __builtin_amdgcn_mfma_f32_32x32x16_fp8_fp8(ah[0], bh[0], c, 0, 0, 0);
  c = __builtin_amdgcn_mfma_f32_32x32x16_fp8_fp8(ah[1], bh[1], c, 0, 0, 0);
  return c;
#endif
}

// ---------------- fp32 -> fp8 (k-interleaved) weight convert: Wq|Wk concat, Wv, Wo ----------------
__global__ __launch_bounds__(256) void conv4(const float* __restrict__ a, const float* __restrict__ b,
                                             const float* __restrict__ c, const float* __restrict__ d,
                                             unsigned char* __restrict__ oqk,
                                             unsigned char* __restrict__ ov,
                                             unsigned char* __restrict__ oo){
  const int bid = blockIdx.x;
  const int sel = bid >> 7;
  const float* in = sel == 0 ? a : sel == 1 ? b : sel == 2 ? c : d;
  unsigned char* out = sel == 0 ? oqk : sel == 1 ? (oqk + 262144) : sel == 2 ? ov : oo;
  const int i = ((bid & 127) * 256 + threadIdx.x) * 8;   // elem idx within 262144
  const int row = i >> 9;
  const int c0  = i & 511;                               // 8-aligned
  float4 v0 = *(const float4*)&in[i];
  float4 v1 = *(const float4*)&in[i + 4];
  unsigned char o[8];
  o[0]=f2fp8(v0.x); o[1]=f2fp8(v0.y); o[2]=f2fp8(v0.z); o[3]=f2fp8(v0.w);
  o[4]=f2fp8(v1.x); o[5]=f2fp8(v1.y); o[6]=f2fp8(v1.z); o[7]=f2fp8(v1.w);
  *(ll64*)&out[row * 512 + perm64(c0)] = *(ll64*)o;
}

// ---------------- GroupNorm stats, 2-stage ----------------
__global__ __launch_bounds__(256) void gn_stats1(const float* __restrict__ x,
                                                 float* __restrict__ part){
  const int bid = blockIdx.x;
  const float* p = x + (size_t)bid * 8192;
  float s = 0.f, ss = 0.f;
  for (int i = threadIdx.x; i < 2048; i += 256) {
    float4 v = *(const float4*)(p + (size_t)i * 4);
    s  += v.x + v.y + v.z + v.w;
    ss += v.x*v.x + v.y*v.y + v.z*v.z + v.w*v.w;
  }
  for (int off = 32; off; off >>= 1) { s += __shfl_down(s, off); ss += __shfl_down(ss, off); }
  __shared__ float red[8];
  int w = threadIdx.x >> 6;
  if ((threadIdx.x & 63) == 0) { red[w] = s; red[w + 4] = ss; }
  __syncthreads();
  if (threadIdx.x == 0) {
    part[bid * 2]     = red[0] + red[1] + red[2] + red[3];
    part[bid * 2 + 1] = red[4] + red[5] + red[6] + red[7];
  }
}
__global__ __launch_bounds__(128) void gn_stats2(const float* __restrict__ part,
                                                 float* __restrict__ stats){
  const int g = threadIdx.x;
  float s = 0.f, ss = 0.f;
#pragma unroll
  for (int i = 0; i < 8; i++) { s += part[(g * 8 + i) * 2]; ss += part[(g * 8 + i) * 2 + 1]; }
  float mean = s * (1.f / 65536.f);
  float var  = ss * (1.f / 65536.f) - mean * mean;
  stats[g * 2]     = mean;
  stats[g * 2 + 1] = rsqrtf(var + 1e-6f);
}

// ---------------- GN apply + transpose -> fp8 k-interleaved hn8[b*4096+p][perm(c)] ----------------
__global__ __launch_bounds__(256) void gn_apply(const float* __restrict__ x,
                                                const float* __restrict__ stats,
                                                const float* __restrict__ gamma,
                                                const float* __restrict__ beta,
                                                unsigned char* __restrict__ hn8){
  __shared__ float tile[64][33];
  const int b  = blockIdx.z;
  const int c0 = blockIdx.y * 64;
  const int p0 = blockIdx.x * 32;
  const int t  = threadIdx.x;
  const float* xb = x + (size_t)b * 512 * 4096;
  const int lpx = t & 31, lcc = t >> 5;
#pragma unroll
  for (int i = 0; i < 8; i++)
    tile[lcc + i * 8][lpx] = xb[(size_t)(c0 + lcc + i * 8) * 4096 + p0 + lpx];
  __syncthreads();
  unsigned char* hb = hn8 + (size_t)b * 4096 * 512;
  const int c   = c0 + (t & 31) * 2;      // even channel pair
  const int pxi = t >> 5;
  const int g2  = (b * 32 + (c >> 4)) * 2;
  const float mean = stats[g2], rstd = stats[g2 + 1];
  const float ga0 = gamma[c], be0 = beta[c];
  const float ga1 = gamma[c + 1], be1 = beta[c + 1];
  const int cp = perm64(c);               // pair stays adjacent under perm64
#pragma unroll
  for (int i = 0; i < 4; i++) {
    const int px = pxi + i * 8;
    float v0 = tile[(t & 31) * 2][px];
    float v1 = tile[(t & 31) * 2 + 1][px];
    unsigned int b0 = f2fp8((v0 - mean) * rstd * ga0 + be0);
    unsigned int b1 = f2fp8((v1 - mean) * rstd * ga1 + be1);
    *(unsigned short*)&hb[(size_t)(p0 + px) * 512 + cp] = (unsigned short)(b0 | (b1 << 8));
  }
}

// ---------------- unified scaled-fp8 GEMM: BM=128, BN=128, BK=64, NBUF=2 ----------------
// 8 waves 2Mx4N (wave tile 64x32), 32x32x64 MFMA, C/D layout col=lane&31,
// row=(reg&3)+8*(reg>>2)+4*(lane>>5).
// MODE 1: +bias(qk split) -> fp8 @perm64 col, dst q|k     (auxA=bq auxB=bk)
// MODE 2: +bias[row]      -> fp8 @perm64 col              (auxA=bv)
// MODE 4: *rinv[row]      -> fp8 @perm64 col              (auxA=rinv)
// MODE 5: +resid+bias[col]-> fp32 transposed out          (auxA=resid auxB=bo)
template<int MODE>
__device__ __forceinline__ void gemm8_body(
    const unsigned char* __restrict__ A, const unsigned char* __restrict__ B,
    unsigned char* __restrict__ C8, float* __restrict__ OUTF,
    const float* __restrict__ auxA, const float* __restrict__ auxB,
    int M, int N, int K, int ldA, int ldB,
    size_t sA, size_t sB, size_t sC, int gx, int gy)
{
  __shared__ __align__(16) unsigned char As[2 * 8192];   // 16 KB
  __shared__ __align__(16) unsigned char Bs[2 * 8192];   // 16 KB

  const int lin = blockIdx.x;
  const int nwg = gridDim.x;
  const int wg = ((lin & 7) * (nwg >> 3)) + (lin >> 3);
  const int bx = wg % gx;
  const int t2 = wg / gx;
  const int by = t2 % gy;
  const int bz = t2 / gy;

  const unsigned char* Ab = A + (size_t)bz * sA;
  const unsigned char* Bb = B + (size_t)bz * sB;
  const int brow = bx * 128;
  const int bcol = by * 128;
  const int t = threadIdx.x;
  const int lane = t & 63;
  const int wid = t >> 6;
  const int wr = wid >> 2;        // 0..1 (64 rows)
  const int wc = wid & 3;         // 0..3 (32 cols)
  const int l31 = lane & 31;
  const int lh  = lane >> 5;

  f32x16 acc[2];
#pragma unroll
  for (int m = 0; m < 2; m++)
#pragma unroll
    for (int e = 0; e < 16; e++) acc[m][e] = 0.f;

  const unsigned char* srcA1;
  const unsigned char* srcB1;
  {
    const int r = t >> 2, s = (t & 3) ^ ((r >> 1) & 3);
    srcA1 = Ab + (size_t)(brow + r) * ldA + s * 16;
    srcB1 = Bb + (size_t)(bcol + r) * ldB + s * 16;
  }
  auto STAGE = [&](int kt, int buf) {
    const int ko = kt * 64;
    gl_lds16b(srcA1 + ko, &As[buf * 8192 + t * 16]);
    gl_lds16b(srcB1 + ko, &Bs[buf * 8192 + t * 16]);
  };
  auto LDA32 = [&](int buf, int mb) -> i32x8 {
    const int ru = wr * 64 + mb * 32 + l31;
    const int x = (ru >> 1) & 3;
    const unsigned char* base = &As[buf * 8192 + ru * 64];
    i32x4 lo = *(const i32x4*)&base[((2 * lh) ^ x) * 16];
    i32x4 hi = *(const i32x4*)&base[((2 * lh + 1) ^ x) * 16];
    i32x8 r;
    r[0]=lo[0]; r[1]=lo[1]; r[2]=lo[2]; r[3]=lo[3];
    r[4]=hi[0]; r[5]=hi[1]; r[6]=hi[2]; r[7]=hi[3];
    return r;
  };
  auto LDB32 = [&](int buf) -> i32x8 {
    const int ru = wc * 32 + l31;
    const int x = (ru >> 1) & 3;
    const unsigned char* base = &Bs[buf * 8192 + ru * 64];
    i32x4 lo = *(const i32x4*)&base[((2 * lh) ^ x) * 16];
    i32x4 hi = *(const i32x4*)&base[((2 * lh + 1) ^ x) * 16];
    i32x8 r;
    r[0]=lo[0]; r[1]=lo[1]; r[2]=lo[2]; r[3]=lo[3];
    r[4]=hi[0]; r[5]=hi[1]; r[6]=hi[2]; r[7]=hi[3];
    return r;
  };

  const int nk = K >> 6;
  STAGE(0, 0);
  for (int j = 0; j < nk; ++j) {
    const int bi = j & 1;
    asm volatile("s_waitcnt vmcnt(0)" ::: "memory");
    __builtin_amdgcn_s_barrier();
    __builtin_amdgcn_sched_barrier(0);
    if (j + 1 < nk) STAGE(j + 1, bi ^ 1);
    i32x8 aq[2], bq;
    bq = LDB32(bi);
#pragma unroll
    for (int m = 0; m < 2; m++) aq[m] = LDA32(bi, m);
    asm volatile("s_waitcnt lgkmcnt(0)" ::: "memory");
    __builtin_amdgcn_sched_barrier(0);
    __builtin_amdgcn_s_setprio(1);
#pragma unroll
    for (int m = 0; m < 2; m++)
      acc[m] = mfma8_32x32x64(aq[m], bq, acc[m]);
    __builtin_amdgcn_s_setprio(0);
    __builtin_amdgcn_sched_barrier(0);
  }

  // epilogue
  const int rowbase = brow + wr * 64;
  const int colbase = bcol + wc * 32;
  const int col = colbase + l31;

  if (MODE == 1) {
    unsigned char* dst = C8 + (col < 512 ? 0 : (size_t)8388608);
    const float bcv = (col < 512 ? auxA[col] : auxB[col - 512]);
    const int cp = perm64(col & 511);
#pragma unroll
    for (int mb = 0; mb < 2; mb++)
#pragma unroll
      for (int g = 0; g < 4; g++) {
        const int r0 = rowbase + mb * 32 + g * 8 + 4 * lh;
#pragma unroll
        for (int q = 0; q < 4; q++)
          dst[(size_t)(r0 + q) * 512 + cp] = f2fp8(acc[mb][g * 4 + q] + bcv);
      }
  } else if (MODE == 2) {
    unsigned char* Cb = C8 + (size_t)bz * sC;
    const int cp = perm64(col);
#pragma unroll
    for (int mb = 0; mb < 2; mb++)
#pragma unroll
      for (int g = 0; g < 4; g++) {
        const int r0 = rowbase + mb * 32 + g * 8 + 4 * lh;
#pragma unroll
        for (int q = 0; q < 4; q++)
          Cb[(size_t)(r0 + q) * N + cp] = f2fp8(acc[mb][g * 4 + q] + auxA[r0 + q]);
      }
  } else if (MODE == 4) {
    unsigned char* Cb = C8 + (size_t)bz * sC;
    const float* rb = auxA + (size_t)bz * 4096;
    const int cp = perm64(col);
#pragma unroll
    for (int mb = 0; mb < 2; mb++)
#pragma unroll
      for (int g = 0; g < 4; g++) {
        const int r0 = rowbase + mb * 32 + g * 8 + 4 * lh;
        const float4 ri = *(const float4*)&rb[r0];
        const float riv[4] = {ri.x, ri.y, ri.z, ri.w};
#pragma unroll
        for (int q = 0; q < 4; q++)
          Cb[(size_t)(r0 + q) * N + cp] = f2fp8(acc[mb][g * 4 + q] * riv[q]);
      }
  } else { // MODE 5
    const float bv = auxB[col];
#pragma unroll
    for (int mb = 0; mb < 2; mb++)
#pragma unroll
      for (int g = 0; g < 4; g++) {
        const int r0 = rowbase + mb * 32 + g * 8 + 4 * lh;
        const int bb = r0 >> 12;
        const int p  = r0 & 4095;
        const size_t idx = ((size_t)bb * 512 + col) * 4096 + p;
        const float4 xv = *(const float4*)&auxA[idx];
        float4 ov;
        ov.x = acc[mb][g * 4 + 0] + xv.x + bv;
        ov.y = acc[mb][g * 4 + 1] + xv.y + bv;
        ov.z = acc[mb][g * 4 + 2] + xv.z + bv;
        ov.w = acc[mb][g * 4 + 3] + xv.w + bv;
        *(float4*)&OUTF[idx] = ov;
      }
  }
}

#define G8_ARGS const unsigned char* A, const unsigned char* B, unsigned char* C8, \
                float* OUTF, const float* auxA, const float* auxB, \
                int M, int N, int K, int ldA, int ldB, \
                size_t sA, size_t sB, size_t sC, int gx, int gy
#define G8_PASS A, B, C8, OUTF, auxA, auxB, M, N, K, ldA, ldB, sA, sB, sC, gx, gy

__global__ __launch_bounds__(512, 2) void k_qkproj(G8_ARGS){ gemm8_body<1>(G8_PASS); }
__global__ __launch_bounds__(512, 2) void k_vproj (G8_ARGS){ gemm8_body<2>(G8_PASS); }
__global__ __launch_bounds__(512, 2) void k_pv    (G8_ARGS){ gemm8_body<4>(G8_PASS); }
__global__ __launch_bounds__(512, 2) void k_oproj (G8_ARGS){ gemm8_body<5>(G8_PASS); }

// ---------------- scaled-fp8 scores: BM=BN=256, BK=64, NBUF=2 (R13 body) ----------------
__global__ __launch_bounds__(512, 2)
void k_scores(const unsigned char* __restrict__ A, const unsigned char* __restrict__ B,
              unsigned char* __restrict__ C, const float* __restrict__ mask,
              float* __restrict__ partial,
              int M, int N, int K, int ldA, int ldB, float scale,
              size_t sA, size_t sB, size_t sC, int gx, int gy)
{
  __shared__ __align__(16) unsigned char LDSBUF[65536];
  unsigned char* As = LDSBUF;
  unsigned char* Bs = LDSBUF + 32768;

  const int lin = blockIdx.x;
  const int nwg = gridDim.x;
  const int wg = ((lin & 7) * (nwg >> 3)) + (lin >> 3);
  const int bx = wg % gx;
  const int t2 = wg / gx;
  const int by = t2 % gy;
  const int bz = t2 / gy;

  const unsigned char* Ab = A + (size_t)bz * sA;
  const unsigned char* Bb = B + (size_t)bz * sB;
  const int brow = bx * 256;
  const int bcol = by * 256;
  const int t = threadIdx.x;
  const int lane = t & 63;
  const int wid = t >> 6;
  const int wr = wid >> 2;
  const int wc = wid & 3;
  const int l31 = lane & 31;
  const int lh  = lane >> 5;

  f32x16 acc[4][2];
#pragma unroll
  for (int m = 0; m < 4; m++)
#pragma unroll
    for (int n = 0; n < 2; n++)
#pragma unroll
      for (int e = 0; e < 16; e++) acc[m][n][e] = 0.f;

  const unsigned char* srcA[2];
  const unsigned char* srcB[2];
#pragma unroll
  for (int c = 0; c < 2; ++c) {
    const int q = c * 512 + t, r = q >> 2, s = (q & 3) ^ ((r >> 1) & 3);
    srcA[c] = Ab + (size_t)(brow + r) * ldA + s * 16;
    srcB[c] = Bb + (size_t)(bcol + r) * ldB + s * 16;
  }
  auto STAGE = [&](int kt, int buf) {
    const int ko = kt * 64;
#pragma unroll
    for (int c = 0; c < 2; ++c) {
      gl_lds16b(srcA[c] + ko, &As[buf * 16384 + (c * 512 + t) * 16]);
      gl_lds16b(srcB[c] + ko, &Bs[buf * 16384 + (c * 512 + t) * 16]);
    }
  };
  auto LDA32 = [&](int buf, int mb) -> i32x8 {
    const int ru = wr * 128 + mb * 32 + l31;
    const int x = (ru >> 1) & 3;
    const unsigned char* base = &As[buf * 16384 + ru * 64];
    i32x4 lo = *(const i32x4*)&base[((2 * lh) ^ x) * 16];
    i32x4 hi = *(const i32x4*)&base[((2 * lh + 1) ^ x) * 16];
    i32x8 r;
    r[0]=lo[0]; r[1]=lo[1]; r[2]=lo[2]; r[3]=lo[3];
    r[4]=hi[0]; r[5]=hi[1]; r[6]=hi[2]; r[7]=hi[3];
    return r;
  };
  auto LDB32 = [&](int buf, int nb) -> i32x8 {
    const int ru = wc * 64 + nb * 32 + l31;
    const int x = (ru >> 1) & 3;
    const unsigned char* base = &Bs[buf * 16384 + ru * 64];
    i32x4 lo = *(const i32x4*)&base[((2 * lh) ^ x) * 16];
    i32x4 hi = *(const i32x4*)&base[((2 * lh + 1) ^ x) * 16];
    i32x8 r;
    r[0]=lo[0]; r[1]=lo[1]; r[2]=lo[2]; r[3]=lo[3];
    r[4]=hi[0]; r[5]=hi[1]; r[6]=hi[2]; r[7]=hi[3];
    return r;
  };

  const int nk = K >> 6;    // 8
  STAGE(0, 0);
  for (int j = 0; j < nk; ++j) {
    const int bi = j & 1;
    asm volatile("s_waitcnt vmcnt(0)" ::: "memory");
    __builtin_amdgcn_s_barrier();
    __builtin_amdgcn_sched_barrier(0);
    if (j + 1 < nk) STAGE(j + 1, bi ^ 1);
    i32x8 aq[4], bq[2];
#pragma unroll
    for (int n = 0; n < 2; n++) bq[n] = LDB32(bi, n);
#pragma unroll
    for (int m = 0; m < 4; m++) aq[m] = LDA32(bi, m);
    asm volatile("s_waitcnt lgkmcnt(0)" ::: "memory");
    __builtin_amdgcn_sched_barrier(0);
    __builtin_amdgcn_s_setprio(1);
#pragma unroll
    for (int m = 0; m < 4; m++)
#pragma unroll
      for (int n = 0; n < 2; n++)
        acc[m][n] = mfma8_32x32x64(aq[m], bq[n], acc[m][n]);
    __builtin_amdgcn_s_setprio(0);
    __builtin_amdgcn_sched_barrier(0);
  }

  const int rowbase = brow + wr * 128;
  const int colbase = bcol + wc * 64;
  const float* maskb = mask + (size_t)bz * 4096;
  float* partb = partial + ((size_t)bz * 64 + (size_t)(by * 4 + wc)) * M;
  const float sc2 = scale * 1.4426950408889634f;

  asm volatile("s_waitcnt lgkmcnt(0)" ::: "memory");
  __builtin_amdgcn_s_barrier();

#pragma unroll
  for (int mi = 0; mi < 4; mi++) {
    float rsm[16];
#pragma unroll
    for (int e = 0; e < 16; e++) rsm[e] = 0.f;
#pragma unroll
    for (int ni = 0; ni < 2; ni++) {
      const int col = colbase + ni * 32 + l31;
      const float mk = maskb[col];
      const int ccl = wc * 64 + perm64(ni * 32 + l31);
#pragma unroll
      for (int g = 0; g < 4; g++) {
#pragma unroll
        for (int q = 0; q < 4; q++) {
          const int reg = g * 4 + q;
          const int rl = wr * 128 + mi * 32 + g * 8 + 4 * lh + q;
          float v = mk * fast_exp2(acc[mi][ni][reg] * sc2);
          rsm[reg] += v;
          LDSBUF[rl * 256 + (ccl ^ (((rl >> 2) & 1) << 5))] = f2fp8(v);
        }
      }
    }
#pragma unroll
    for (int off = 1; off < 32; off <<= 1)
#pragma unroll
      for (int e = 0; e < 16; e++) rsm[e] += __shfl_xor(rsm[e], off);
    if (l31 == 0) {
#pragma unroll
      for (int g = 0; g < 4; g++) {
        float4 v = make_float4(rsm[g*4], rsm[g*4+1], rsm[g*4+2], rsm[g*4+3]);
        *(float4*)&partb[rowbase + mi * 32 + g * 8 + 4 * lh] = v;
      }
    }
  }
  __builtin_amdgcn_s_barrier();
  unsigned char* Cb = C + (size_t)bz * sC;
#pragma unroll
  for (int i = 0; i < 8; i++) {
    const int ch = i * 512 + t;
    const int rl = ch >> 4;
    const int c16 = (ch & 15) * 16;
    i32x4 v = *(const i32x4*)&LDSBUF[rl * 256 + (c16 ^ (((rl >> 2) & 1) << 5))];
    *(i32x4*)&Cb[(size_t)(brow + rl) * N + bcol + c16] = v;
  }
}

// ---------------- rowsum reduce ----------------
__global__ __launch_bounds__(256) void rowsum_inv(const float* __restrict__ partial,
                                                  float* __restrict__ rinv){
  const int idx = blockIdx.x * 256 + threadIdx.x;
  const int b = idx >> 12, q = idx & 4095;
  const float* p = partial + ((size_t)b * 64) * 4096 + q;
  float s = 0.f;
#pragma unroll
  for (int i = 0; i < 64; i++) s += p[(size_t)i * 4096];
  rinv[idx] = 1.f / s;
}

extern "C" void kernel_launch(void* const* d_in, const int* in_sizes, int n_in,
                              void* d_out, int out_size, void* d_ws, size_t ws_size,
                              hipStream_t stream) {
  const float* x     = (const float*)d_in[0];
  const float* mask  = (const float*)d_in[1];
  const float* gamma = (const float*)d_in[2];
  const float* beta  = (const float*)d_in[3];
  const float* Wq    = (const float*)d_in[4];
  const float* bq    = (const float*)d_in[5];
  const float* Wk    = (const float*)d_in[6];
  const float* bk    = (const float*)d_in[7];
  const float* Wv    = (const float*)d_in[8];
  const float* bv    = (const float*)d_in[9];
  const float* Wo    = (const float*)d_in[10];
  const float* bo    = (const float*)d_in[11];
  float* out = (float*)d_out;

  size_t off = 0;
  auto nxt = [&](size_t bytes) -> void* {
    void* p = (char*)d_ws + off;
    off += (bytes + 255) & ~(size_t)255;
    return p;
  };
  float* stats          = (float*)nxt(256 * sizeof(float));
  float* spart          = (float*)nxt(2048 * sizeof(float));
  float* partial        = (float*)nxt((size_t)4 * 64 * 4096 * 4);
  float* rinv           = (float*)nxt((size_t)16384 * 4);
  unsigned char* Wqk8   = (unsigned char*)nxt((size_t)1024 * 512);     // q|k weights fp8 k-ilv
  unsigned char* Wv8    = (unsigned char*)nxt((size_t)512 * 512);
  unsigned char* Wo8    = (unsigned char*)nxt((size_t)512 * 512);
  unsigned char* hn8    = (unsigned char*)nxt((size_t)16384 * 512);    // GN out fp8 k-ilv
  unsigned char* qk8    = (unsigned char*)nxt((size_t)2 * 16384 * 512);// q | k fp8 k-ilv
  unsigned char* vcm8   = (unsigned char*)nxt((size_t)4 * 512 * 4096); // [b][c][perm(p)] fp8
  unsigned char* ot8    = (unsigned char*)nxt((size_t)16384 * 512);    // O fp8 k-ilv (normalized)
  unsigned char* P8     = (unsigned char*)nxt((size_t)4 * 4096 * 4096);// fp8 k-ilv cols

  conv4<<<512, 256, 0, stream>>>(Wq, Wk, Wv, Wo, Wqk8, Wv8, Wo8);

  gn_stats1<<<1024, 256, 0, stream>>>(x, spart);
  gn_stats2<<<1, 128, 0, stream>>>(spart, stats);
  gn_apply<<<dim3(128, 8, 4), 256, 0, stream>>>(x, stats, gamma, beta, hn8);

  // fused QK proj -> fp8 qt8/kt8; M=16384 N=1024 K=512; gx=128, gy=8 -> 1024
  k_qkproj<<<1024, 512, 0, stream>>>(hn8, Wqk8, qk8, nullptr, bq, bk,
                                     16384, 1024, 512, 512, 512, 0, 0, 0, 128, 8);
  // V proj -> fp8 vcm8[b][c][perm(p)]; M=512 N=4096 K=512; gx=4, gy=32, gz=4 -> 512
  k_vproj<<<512, 512, 0, stream>>>(Wv8, hn8, vcm8, nullptr, bv, nullptr,
                                   512, 4096, 512, 512, 512,
                                   0, (size_t)4096 * 512, (size_t)512 * 4096, 4, 32);
  // scores (scaled fp8, fp8 P out + f32 partials); gx=16, gy=16, gz=4 -> 1024
  k_scores<<<1024, 512, 0, stream>>>(qk8, qk8 + (size_t)8388608, P8, mask, partial,
                                     4096, 4096, 512, 512, 512, 0.044194173824159216f,
                                     (size_t)4096 * 512, (size_t)4096 * 512,
                                     (size_t)4096 * 4096, 16, 16);
  rowsum_inv<<<64, 256, 0, stream>>>(partial, rinv);
  // PV -> fp8 ot8 (normalized, k-ilv cols); M=4096 N=512 K=4096; gx=32, gy=4, gz=4 -> 512
  k_pv<<<512, 512, 0, stream>>>(P8, vcm8, ot8, nullptr, rinv, nullptr,
                                4096, 512, 4096, 4096, 4096,
                                (size_t)4096 * 4096, (size_t)512 * 4096,
                                (size_t)4096 * 512, 32, 4);
  // O-projection + residual + bias -> fp32 out; M=16384 N=512 K=512; gx=128, gy=4 -> 512
  k_oproj<<<512, 512, 0, stream>>>(ot8, Wo8, nullptr, out, x, bo,
                                   16384, 512, 512, 512, 512, 0, 0, 0, 128, 4);
}

// Round 15
// 189.465 us; speedup vs baseline: 1.2914x; 1.1728x over previous
//
#include <hip/hip_runtime.h>
#include <hip/hip_bf16.h>
#include <stdint.h>

typedef __attribute__((ext_vector_type(4))) float f32x4;
typedef __attribute__((ext_vector_type(16))) float f32x16;
typedef __attribute__((ext_vector_type(4))) int i32x4;
typedef __attribute__((ext_vector_type(8))) int i32x8;
typedef long long ll64;
typedef __attribute__((ext_vector_type(2))) long long ll64x2;

__device__ __forceinline__ float fast_exp2(float x){
#if __has_builtin(__builtin_amdgcn_exp2f)
  return __builtin_amdgcn_exp2f(x);
#else
  return exp2f(x);
#endif
}
__device__ __forceinline__ unsigned char f2fp8(float f){
#if __has_builtin(__builtin_amdgcn_cvt_pk_fp8_f32)
  int r = __builtin_amdgcn_cvt_pk_fp8_f32(f, f, 0, false);
  return (unsigned char)(r & 0xff);
#else
  uint32_t u = __builtin_bit_cast(uint32_t, f);
  uint32_t s = (u >> 24) & 0x80u;
  uint32_t a = u & 0x7fffffffu;
  float af = __builtin_bit_cast(float, a);
  if (af >= 448.f) return (unsigned char)(s | 0x7e);
  a += 0x000fffffu + ((a >> 20) & 1u);
  int e = (int)(a >> 23) - 127;
  if (e < -6) return (unsigned char)s;
  return (unsigned char)(s | (uint32_t)((e + 7) << 3) | ((a >> 20) & 7u));
#endif
}
// k-interleave permutation: lane lk's two 8B chunks (true k lk*8, 32+lk*8) contiguous
__device__ __forceinline__ int perm64(int c){
  return (c & ~63) | (((c >> 3) & 3) << 4) | (((c >> 5) & 1) << 3) | (c & 7);
}
__device__ __forceinline__ void gl_lds16b(const unsigned char* g, unsigned char* l){
  __builtin_amdgcn_global_load_lds(
      (const __attribute__((address_space(1))) uint32_t*)g,
      (__attribute__((address_space(3))) uint32_t*)l, 16, 0, 0);
}

// 32x32 K=64 fp8 MFMA: scaled-MX with unit scales (2.3x rate) or 4x non-scaled fallback
__device__ __forceinline__ f32x16 mfma8_32x32x64(i32x8 a, i32x8 b, f32x16 c){
#if __has_builtin(__builtin_amdgcn_mfma_scale_f32_32x32x64_f8f6f4)
  return __builtin_amdgcn_mfma_scale_f32_32x32x64_f8f6f4(a, b, c, 0, 0,
                                                         0, 0x7f7f7f7f, 0, 0x7f7f7f7f);
#else
  ll64x2 al = __builtin_bit_cast(ll64x2, *(i32x4*)&a);
  ll64x2 ah; ah[0] = ((ll64*)&a)[2]; ah[1] = ((ll64*)&a)[3];
  ll64x2 bl = __builtin_bit_cast(ll64x2, *(i32x4*)&b);
  ll64x2 bh; bh[0] = ((ll64*)&b)[2]; bh[1] = ((ll64*)&b)[3];
  c = __builtin_amdgcn_mfma_f32_32x32x16_fp8_fp8(al[0], bl[0], c, 0, 0, 0);
  c = __builtin_amdgcn_mfma_f32_32x32x16_fp8_fp8(al[1], bl[1], c, 0, 0, 0);
  c = __builtin_amdgcn_mfma_f32_32x32x16_fp8_fp8(ah[0], bh[0], c, 0, 0, 0);
  c = __builtin_amdgcn_mfma_f32_32x32x16_fp8_fp8(ah[1], bh[1], c, 0, 0, 0);
  return c;
#endif
}

// ---------------- fused prep: GN partial stats (blocks 0..1023) + weight fp8 convert (1024..1535) ----
__global__ __launch_bounds__(256) void k_prep(const float* __restrict__ x,
                                              float* __restrict__ part,
                                              const float* __restrict__ Wq, const float* __restrict__ Wk,
                                              const float* __restrict__ Wv, const float* __restrict__ Wo,
                                              unsigned char* __restrict__ oqk,
                                              unsigned char* __restrict__ ov,
                                              unsigned char* __restrict__ oo){
  __shared__ float red[8];
  const int bid = blockIdx.x;
  if (bid < 1024) {
    const float* p = x + (size_t)bid * 8192;
    float s = 0.f, ss = 0.f;
    for (int i = threadIdx.x; i < 2048; i += 256) {
      float4 v = *(const float4*)(p + (size_t)i * 4);
      s  += v.x + v.y + v.z + v.w;
      ss += v.x*v.x + v.y*v.y + v.z*v.z + v.w*v.w;
    }
    for (int off = 32; off; off >>= 1) { s += __shfl_down(s, off); ss += __shfl_down(ss, off); }
    int w = threadIdx.x >> 6;
    if ((threadIdx.x & 63) == 0) { red[w] = s; red[w + 4] = ss; }
    __syncthreads();
    if (threadIdx.x == 0) {
      part[bid * 2]     = red[0] + red[1] + red[2] + red[3];
      part[bid * 2 + 1] = red[4] + red[5] + red[6] + red[7];
    }
  } else {
    const int cb = bid - 1024;
    const int sel = cb >> 7;
    const float* in = sel == 0 ? Wq : sel == 1 ? Wk : sel == 2 ? Wv : Wo;
    unsigned char* out = sel == 0 ? oqk : sel == 1 ? (oqk + 262144) : sel == 2 ? ov : oo;
    const int i = ((cb & 127) * 256 + threadIdx.x) * 8;
    const int row = i >> 9;
    const int c0  = i & 511;
    float4 v0 = *(const float4*)&in[i];
    float4 v1 = *(const float4*)&in[i + 4];
    unsigned char o[8];
    o[0]=f2fp8(v0.x); o[1]=f2fp8(v0.y); o[2]=f2fp8(v0.z); o[3]=f2fp8(v0.w);
    o[4]=f2fp8(v1.x); o[5]=f2fp8(v1.y); o[6]=f2fp8(v1.z); o[7]=f2fp8(v1.w);
    *(ll64*)&out[row * 512 + perm64(c0)] = *(ll64*)o;
  }
}

// ---------------- GN apply + transpose -> fp8 k-interleaved; final stat reduce inline ----------------
__global__ __launch_bounds__(256) void gn_apply(const float* __restrict__ x,
                                                const float* __restrict__ spart,
                                                const float* __restrict__ gamma,
                                                const float* __restrict__ beta,
                                                unsigned char* __restrict__ hn8){
  __shared__ float tile[64][33];
  const int b  = blockIdx.z;
  const int c0 = blockIdx.y * 64;
  const int p0 = blockIdx.x * 32;
  const int t  = threadIdx.x;
  const float* xb = x + (size_t)b * 512 * 4096;
  const int lpx = t & 31, lcc = t >> 5;
#pragma unroll
  for (int i = 0; i < 8; i++)
    tile[lcc + i * 8][lpx] = xb[(size_t)(c0 + lcc + i * 8) * 4096 + p0 + lpx];
  __syncthreads();
  unsigned char* hb = hn8 + (size_t)b * 4096 * 512;
  const int c   = c0 + (t & 31) * 2;      // even channel pair
  const int pxi = t >> 5;
  const int g2  = b * 32 + (c >> 4);      // group index
  float sum = 0.f, ssum = 0.f;
#pragma unroll
  for (int i = 0; i < 8; i++) { sum += spart[(g2 * 8 + i) * 2]; ssum += spart[(g2 * 8 + i) * 2 + 1]; }
  const float mean = sum * (1.f / 65536.f);
  const float rstd = rsqrtf(ssum * (1.f / 65536.f) - mean * mean + 1e-6f);
  const float ga0 = gamma[c], be0 = beta[c];
  const float ga1 = gamma[c + 1], be1 = beta[c + 1];
  const int cp = perm64(c);               // pair stays adjacent under perm64
#pragma unroll
  for (int i = 0; i < 4; i++) {
    const int px = pxi + i * 8;
    float v0 = tile[(t & 31) * 2][px];
    float v1 = tile[(t & 31) * 2 + 1][px];
    unsigned int b0 = f2fp8((v0 - mean) * rstd * ga0 + be0);
    unsigned int b1 = f2fp8((v1 - mean) * rstd * ga1 + be1);
    *(unsigned short*)&hb[(size_t)(p0 + px) * 512 + cp] = (unsigned short)(b0 | (b1 << 8));
  }
}

// ---------------- unified scaled-fp8 GEMM body: BM=128, BN=128, BK=64, NBUF=2 ----------------
// MODE 1: +bias(qk split) -> fp8 @perm64 col  | 2: +bias[row] -> fp8 @perm64 col
// MODE 4: *rinv(row, computed inline from partial) -> fp8 @perm64 col
// MODE 5: +resid+bias[col] -> fp32 transposed out
template<int MODE>
__device__ __forceinline__ void gemm8_body(
    int wg, unsigned char* smem,
    const unsigned char* __restrict__ A, const unsigned char* __restrict__ B,
    unsigned char* __restrict__ C8, float* __restrict__ OUTF,
    const float* __restrict__ auxA, const float* __restrict__ auxB,
    const float* __restrict__ partial,
    int N, int K, int ldA, int ldB,
    size_t sA, size_t sB, size_t sC, int gx, int gy)
{
  unsigned char* As = smem;
  unsigned char* Bs = smem + 16384;

  const int bx = wg % gx;
  const int t2 = wg / gx;
  const int by = t2 % gy;
  const int bz = t2 / gy;

  const unsigned char* Ab = A + (size_t)bz * sA;
  const unsigned char* Bb = B + (size_t)bz * sB;
  const int brow = bx * 128;
  const int bcol = by * 128;
  const int t = threadIdx.x;
  const int lane = t & 63;
  const int wid = t >> 6;
  const int wr = wid >> 2;        // 0..1 (64 rows)
  const int wc = wid & 3;         // 0..3 (32 cols)
  const int l31 = lane & 31;
  const int lh  = lane >> 5;

  f32x16 acc[2];
#pragma unroll
  for (int m = 0; m < 2; m++)
#pragma unroll
    for (int e = 0; e < 16; e++) acc[m][e] = 0.f;

  const unsigned char* srcA1;
  const unsigned char* srcB1;
  {
    const int r = t >> 2, s = (t & 3) ^ ((r >> 1) & 3);
    srcA1 = Ab + (size_t)(brow + r) * ldA + s * 16;
    srcB1 = Bb + (size_t)(bcol + r) * ldB + s * 16;
  }
  auto STAGE = [&](int kt, int buf) {
    const int ko = kt * 64;
    gl_lds16b(srcA1 + ko, &As[buf * 8192 + t * 16]);
    gl_lds16b(srcB1 + ko, &Bs[buf * 8192 + t * 16]);
  };
  auto LDA32 = [&](int buf, int mb) -> i32x8 {
    const int ru = wr * 64 + mb * 32 + l31;
    const int x = (ru >> 1) & 3;
    const unsigned char* base = &As[buf * 8192 + ru * 64];
    i32x4 lo = *(const i32x4*)&base[((2 * lh) ^ x) * 16];
    i32x4 hi = *(const i32x4*)&base[((2 * lh + 1) ^ x) * 16];
    i32x8 r;
    r[0]=lo[0]; r[1]=lo[1]; r[2]=lo[2]; r[3]=lo[3];
    r[4]=hi[0]; r[5]=hi[1]; r[6]=hi[2]; r[7]=hi[3];
    return r;
  };
  auto LDB32 = [&](int buf) -> i32x8 {
    const int ru = wc * 32 + l31;
    const int x = (ru >> 1) & 3;
    const unsigned char* base = &Bs[buf * 8192 + ru * 64];
    i32x4 lo = *(const i32x4*)&base[((2 * lh) ^ x) * 16];
    i32x4 hi = *(const i32x4*)&base[((2 * lh + 1) ^ x) * 16];
    i32x8 r;
    r[0]=lo[0]; r[1]=lo[1]; r[2]=lo[2]; r[3]=lo[3];
    r[4]=hi[0]; r[5]=hi[1]; r[6]=hi[2]; r[7]=hi[3];
    return r;
  };

  const int nk = K >> 6;
  STAGE(0, 0);
  for (int j = 0; j < nk; ++j) {
    const int bi = j & 1;
    asm volatile("s_waitcnt vmcnt(0)" ::: "memory");
    __builtin_amdgcn_s_barrier();
    __builtin_amdgcn_sched_barrier(0);
    if (j + 1 < nk) STAGE(j + 1, bi ^ 1);
    i32x8 aq[2], bq;
    bq = LDB32(bi);
#pragma unroll
    for (int m = 0; m < 2; m++) aq[m] = LDA32(bi, m);
    asm volatile("s_waitcnt lgkmcnt(0)" ::: "memory");
    __builtin_amdgcn_sched_barrier(0);
    __builtin_amdgcn_s_setprio(1);
#pragma unroll
    for (int m = 0; m < 2; m++)
      acc[m] = mfma8_32x32x64(aq[m], bq, acc[m]);
    __builtin_amdgcn_s_setprio(0);
    __builtin_amdgcn_sched_barrier(0);
  }

  // epilogue (32x32 C/D layout: col=lane&31, row=(reg&3)+8*(reg>>2)+4*(lane>>5))
  const int rowbase = brow + wr * 64;
  const int colbase = bcol + wc * 32;
  const int col = colbase + l31;

  if (MODE == 1) {
    unsigned char* dst = C8 + (col < 512 ? 0 : (size_t)8388608);
    const float bcv = (col < 512 ? auxA[col] : auxB[col - 512]);
    const int cp = perm64(col & 511);
#pragma unroll
    for (int mb = 0; mb < 2; mb++)
#pragma unroll
      for (int g = 0; g < 4; g++) {
        const int r0 = rowbase + mb * 32 + g * 8 + 4 * lh;
#pragma unroll
        for (int q = 0; q < 4; q++)
          dst[(size_t)(r0 + q) * 512 + cp] = f2fp8(acc[mb][g * 4 + q] + bcv);
      }
  } else if (MODE == 2) {
    unsigned char* Cb = C8 + (size_t)bz * sC;
    const int cp = perm64(col);
#pragma unroll
    for (int mb = 0; mb < 2; mb++)
#pragma unroll
      for (int g = 0; g < 4; g++) {
        const int r0 = rowbase + mb * 32 + g * 8 + 4 * lh;
#pragma unroll
        for (int q = 0; q < 4; q++)
          Cb[(size_t)(r0 + q) * N + cp] = f2fp8(acc[mb][g * 4 + q] + auxA[r0 + q]);
      }
  } else if (MODE == 4) {
    // inline rinv for this block's 128 rows from the 64 scores partials
    float* rtmp  = (float*)(smem + 32768);          // [128][4]
    float* rinvL = (float*)(smem + 32768 + 2048);   // [128]
    {
      const int row = t >> 2, q4 = t & 3;
      const float* pb = partial + ((size_t)bz * 64 + q4 * 16) * 4096 + (brow + row);
      float s = 0.f;
#pragma unroll
      for (int i = 0; i < 16; i++) s += pb[(size_t)i * 4096];
      rtmp[row * 4 + q4] = s;
    }
    __syncthreads();
    if (t < 128) rinvL[t] = 1.f / (rtmp[t * 4] + rtmp[t * 4 + 1] + rtmp[t * 4 + 2] + rtmp[t * 4 + 3]);
    __syncthreads();
    unsigned char* Cb = C8 + (size_t)bz * sC;
    const int cp = perm64(col);
#pragma unroll
    for (int mb = 0; mb < 2; mb++)
#pragma unroll
      for (int g = 0; g < 4; g++) {
        const int r0 = rowbase + mb * 32 + g * 8 + 4 * lh;
        const int rl = r0 - brow;
#pragma unroll
        for (int q = 0; q < 4; q++)
          Cb[(size_t)(r0 + q) * N + cp] = f2fp8(acc[mb][g * 4 + q] * rinvL[rl + q]);
      }
  } else { // MODE 5
    const float bv = auxB[col];
#pragma unroll
    for (int mb = 0; mb < 2; mb++)
#pragma unroll
      for (int g = 0; g < 4; g++) {
        const int r0 = rowbase + mb * 32 + g * 8 + 4 * lh;
        const int bb = r0 >> 12;
        const int p  = r0 & 4095;
        const size_t idx = ((size_t)bb * 512 + col) * 4096 + p;
        const float4 xv = *(const float4*)&auxA[idx];
        float4 ov;
        ov.x = acc[mb][g * 4 + 0] + xv.x + bv;
        ov.y = acc[mb][g * 4 + 1] + xv.y + bv;
        ov.z = acc[mb][g * 4 + 2] + xv.z + bv;
        ov.w = acc[mb][g * 4 + 3] + xv.w + bv;
        *(float4*)&OUTF[idx] = ov;
      }
  }
}

// ---------------- fused QK+V projections: blocks 0..1023 -> QK, 1024..1535 -> V ----------------
__global__ __launch_bounds__(512, 2)
void k_qkv(const unsigned char* __restrict__ hn8, const unsigned char* __restrict__ Wqk8,
           const unsigned char* __restrict__ Wv8,
           unsigned char* __restrict__ qk8, unsigned char* __restrict__ vcm8,
           const float* __restrict__ bq, const float* __restrict__ bk,
           const float* __restrict__ bv){
  __shared__ __align__(16) unsigned char SMEM[32768];
  const int lin = blockIdx.x;
  const int nwg = gridDim.x;   // 1536
  const int wg = ((lin & 7) * (nwg >> 3)) + (lin >> 3);
  if (wg < 1024)
    gemm8_body<1>(wg, SMEM, hn8, Wqk8, qk8, nullptr, bq, bk, nullptr,
                  1024, 512, 512, 512, 0, 0, 0, 128, 8);
  else
    gemm8_body<2>(wg - 1024, SMEM, Wv8, hn8, vcm8, nullptr, bv, nullptr, nullptr,
                  4096, 512, 512, 512,
                  0, (size_t)4096 * 512, (size_t)512 * 4096, 4, 32);
}

// ---------------- PV (rinv inline) and O-proj wrappers ----------------
__global__ __launch_bounds__(512, 2)
void k_pv(const unsigned char* __restrict__ P8, const unsigned char* __restrict__ vcm8,
          unsigned char* __restrict__ ot8, const float* __restrict__ partial){
  __shared__ __align__(16) unsigned char SMEM[32768 + 2560];
  const int lin = blockIdx.x;
  const int nwg = gridDim.x;   // 512
  const int wg = ((lin & 7) * (nwg >> 3)) + (lin >> 3);
  gemm8_body<4>(wg, SMEM, P8, vcm8, ot8, nullptr, nullptr, nullptr, partial,
                512, 4096, 4096, 4096,
                (size_t)4096 * 4096, (size_t)512 * 4096, (size_t)4096 * 512, 32, 4);
}
__global__ __launch_bounds__(512, 2)
void k_oproj(const unsigned char* __restrict__ ot8, const unsigned char* __restrict__ Wo8,
             float* __restrict__ out, const float* __restrict__ resid,
             const float* __restrict__ bo){
  __shared__ __align__(16) unsigned char SMEM[32768];
  const int lin = blockIdx.x;
  const int nwg = gridDim.x;   // 512
  const int wg = ((lin & 7) * (nwg >> 3)) + (lin >> 3);
  gemm8_body<5>(wg, SMEM, ot8, Wo8, nullptr, out, resid, bo, nullptr,
                512, 512, 512, 512, 0, 0, 0, 128, 4);
}

// ---------------- scaled-fp8 scores: BM=BN=256, BK=64, NBUF=2 (unchanged R13/R14 body) ----------------
__global__ __launch_bounds__(512, 2)
void k_scores(const unsigned char* __restrict__ A, const unsigned char* __restrict__ B,
              unsigned char* __restrict__ C, const float* __restrict__ mask,
              float* __restrict__ partial,
              int M, int N, int K, int ldA, int ldB, float scale,
              size_t sA, size_t sB, size_t sC, int gx, int gy)
{
  __shared__ __align__(16) unsigned char LDSBUF[65536];
  unsigned char* As = LDSBUF;
  unsigned char* Bs = LDSBUF + 32768;

  const int lin = blockIdx.x;
  const int nwg = gridDim.x;
  const int wg = ((lin & 7) * (nwg >> 3)) + (lin >> 3);
  const int bx = wg % gx;
  const int t2 = wg / gx;
  const int by = t2 % gy;
  const int bz = t2 / gy;

  const unsigned char* Ab = A + (size_t)bz * sA;
  const unsigned char* Bb = B + (size_t)bz * sB;
  const int brow = bx * 256;
  const int bcol = by * 256;
  const int t = threadIdx.x;
  const int lane = t & 63;
  const int wid = t >> 6;
  const int wr = wid >> 2;
  const int wc = wid & 3;
  const int l31 = lane & 31;
  const int lh  = lane >> 5;

  f32x16 acc[4][2];
#pragma unroll
  for (int m = 0; m < 4; m++)
#pragma unroll
    for (int n = 0; n < 2; n++)
#pragma unroll
      for (int e = 0; e < 16; e++) acc[m][n][e] = 0.f;

  const unsigned char* srcA[2];
  const unsigned char* srcB[2];
#pragma unroll
  for (int c = 0; c < 2; ++c) {
    const int q = c * 512 + t, r = q >> 2, s = (q & 3) ^ ((r >> 1) & 3);
    srcA[c] = Ab + (size_t)(brow + r) * ldA + s * 16;
    srcB[c] = Bb + (size_t)(bcol + r) * ldB + s * 16;
  }
  auto STAGE = [&](int kt, int buf) {
    const int ko = kt * 64;
#pragma unroll
    for (int c = 0; c < 2; ++c) {
      gl_lds16b(srcA[c] + ko, &As[buf * 16384 + (c * 512 + t) * 16]);
      gl_lds16b(srcB[c] + ko, &Bs[buf * 16384 + (c * 512 + t) * 16]);
    }
  };
  auto LDA32 = [&](int buf, int mb) -> i32x8 {
    const int ru = wr * 128 + mb * 32 + l31;
    const int x = (ru >> 1) & 3;
    const unsigned char* base = &As[buf * 16384 + ru * 64];
    i32x4 lo = *(const i32x4*)&base[((2 * lh) ^ x) * 16];
    i32x4 hi = *(const i32x4*)&base[((2 * lh + 1) ^ x) * 16];
    i32x8 r;
    r[0]=lo[0]; r[1]=lo[1]; r[2]=lo[2]; r[3]=lo[3];
    r[4]=hi[0]; r[5]=hi[1]; r[6]=hi[2]; r[7]=hi[3];
    return r;
  };
  auto LDB32 = [&](int buf, int nb) -> i32x8 {
    const int ru = wc * 64 + nb * 32 + l31;
    const int x = (ru >> 1) & 3;
    const unsigned char* base = &Bs[buf * 16384 + ru * 64];
    i32x4 lo = *(const i32x4*)&base[((2 * lh) ^ x) * 16];
    i32x4 hi = *(const i32x4*)&base[((2 * lh + 1) ^ x) * 16];
    i32x8 r;
    r[0]=lo[0]; r[1]=lo[1]; r[2]=lo[2]; r[3]=lo[3];
    r[4]=hi[0]; r[5]=hi[1]; r[6]=hi[2]; r[7]=hi[3];
    return r;
  };

  const int nk = K >> 6;    // 8
  STAGE(0, 0);
  for (int j = 0; j < nk; ++j) {
    const int bi = j & 1;
    asm volatile("s_waitcnt vmcnt(0)" ::: "memory");
    __builtin_amdgcn_s_barrier();
    __builtin_amdgcn_sched_barrier(0);
    if (j + 1 < nk) STAGE(j + 1, bi ^ 1);
    i32x8 aq[4], bq[2];
#pragma unroll
    for (int n = 0; n < 2; n++) bq[n] = LDB32(bi, n);
#pragma unroll
    for (int m = 0; m < 4; m++) aq[m] = LDA32(bi, m);
    asm volatile("s_waitcnt lgkmcnt(0)" ::: "memory");
    __builtin_amdgcn_sched_barrier(0);
    __builtin_amdgcn_s_setprio(1);
#pragma unroll
    for (int m = 0; m < 4; m++)
#pragma unroll
      for (int n = 0; n < 2; n++)
        acc[m][n] = mfma8_32x32x64(aq[m], bq[n], acc[m][n]);
    __builtin_amdgcn_s_setprio(0);
    __builtin_amdgcn_sched_barrier(0);
  }

  const int rowbase = brow + wr * 128;
  const int colbase = bcol + wc * 64;
  const float* maskb = mask + (size_t)bz * 4096;
  float* partb = partial + ((size_t)bz * 64 + (size_t)(by * 4 + wc)) * M;
  const float sc2 = scale * 1.4426950408889634f;

  asm volatile("s_waitcnt lgkmcnt(0)" ::: "memory");
  __builtin_amdgcn_s_barrier();

#pragma unroll
  for (int mi = 0; mi < 4; mi++) {
    float rsm[16];
#pragma unroll
    for (int e = 0; e < 16; e++) rsm[e] = 0.f;
#pragma unroll
    for (int ni = 0; ni < 2; ni++) {
      const int col = colbase + ni * 32 + l31;
      const float mk = maskb[col];
      const int ccl = wc * 64 + perm64(ni * 32 + l31);
#pragma unroll
      for (int g = 0; g < 4; g++) {
#pragma unroll
        for (int q = 0; q < 4; q++) {
          const int reg = g * 4 + q;
          const int rl = wr * 128 + mi * 32 + g * 8 + 4 * lh + q;
          float v = mk * fast_exp2(acc[mi][ni][reg] * sc2);
          rsm[reg] += v;
          LDSBUF[rl * 256 + (ccl ^ (((rl >> 2) & 1) << 5))] = f2fp8(v);
        }
      }
    }
#pragma unroll
    for (int off = 1; off < 32; off <<= 1)
#pragma unroll
      for (int e = 0; e < 16; e++) rsm[e] += __shfl_xor(rsm[e], off);
    if (l31 == 0) {
#pragma unroll
      for (int g = 0; g < 4; g++) {
        float4 v = make_float4(rsm[g*4], rsm[g*4+1], rsm[g*4+2], rsm[g*4+3]);
        *(float4*)&partb[rowbase + mi * 32 + g * 8 + 4 * lh] = v;
      }
    }
  }
  __builtin_amdgcn_s_barrier();
  unsigned char* Cb = C + (size_t)bz * sC;
#pragma unroll
  for (int i = 0; i < 8; i++) {
    const int ch = i * 512 + t;
    const int rl = ch >> 4;
    const int c16 = (ch & 15) * 16;
    i32x4 v = *(const i32x4*)&LDSBUF[rl * 256 + (c16 ^ (((rl >> 2) & 1) << 5))];
    *(i32x4*)&Cb[(size_t)(brow + rl) * N + bcol + c16] = v;
  }
}

extern "C" void kernel_launch(void* const* d_in, const int* in_sizes, int n_in,
                              void* d_out, int out_size, void* d_ws, size_t ws_size,
                              hipStream_t stream) {
  const float* x     = (const float*)d_in[0];
  const float* mask  = (const float*)d_in[1];
  const float* gamma = (const float*)d_in[2];
  const float* beta  = (const float*)d_in[3];
  const float* Wq    = (const float*)d_in[4];
  const float* bq    = (const float*)d_in[5];
  const float* Wk    = (const float*)d_in[6];
  const float* bk    = (const float*)d_in[7];
  const float* Wv    = (const float*)d_in[8];
  const float* bv    = (const float*)d_in[9];
  const float* Wo    = (const float*)d_in[10];
  const float* bo    = (const float*)d_in[11];
  float* out = (float*)d_out;

  size_t off = 0;
  auto nxt = [&](size_t bytes) -> void* {
    void* p = (char*)d_ws + off;
    off += (bytes + 255) & ~(size_t)255;
    return p;
  };
  float* spart          = (float*)nxt(2048 * sizeof(float));
  float* partial        = (float*)nxt((size_t)4 * 64 * 4096 * 4);
  unsigned char* Wqk8   = (unsigned char*)nxt((size_t)1024 * 512);     // q|k weights fp8 k-ilv
  unsigned char* Wv8    = (unsigned char*)nxt((size_t)512 * 512);
  unsigned char* Wo8    = (unsigned char*)nxt((size_t)512 * 512);
  unsigned char* hn8    = (unsigned char*)nxt((size_t)16384 * 512);    // GN out fp8 k-ilv
  unsigned char* qk8    = (unsigned char*)nxt((size_t)2 * 16384 * 512);// q | k fp8 k-ilv
  unsigned char* vcm8   = (unsigned char*)nxt((size_t)4 * 512 * 4096); // [b][c][perm(p)] fp8
  unsigned char* ot8    = (unsigned char*)nxt((size_t)16384 * 512);    // O fp8 k-ilv (normalized)
  unsigned char* P8     = (unsigned char*)nxt((size_t)4 * 4096 * 4096);// fp8 k-ilv cols

  // GN partial stats + weight converts (fused, independent work)
  k_prep<<<1536, 256, 0, stream>>>(x, spart, Wq, Wk, Wv, Wo, Wqk8, Wv8, Wo8);
  // GN apply (final stat reduction inline) -> fp8 hn
  gn_apply<<<dim3(128, 8, 4), 256, 0, stream>>>(x, spart, gamma, beta, hn8);
  // fused QK + V projections -> fp8 (k-interleaved)
  k_qkv<<<1536, 512, 0, stream>>>(hn8, Wqk8, Wv8, qk8, vcm8, bq, bk, bv);
  // scores: P = mask*exp(s*scale) fp8 + f32 row partials
  k_scores<<<1024, 512, 0, stream>>>(qk8, qk8 + (size_t)8388608, P8, mask, partial,
                                     4096, 4096, 512, 512, 512, 0.044194173824159216f,
                                     (size_t)4096 * 512, (size_t)4096 * 512,
                                     (size_t)4096 * 4096, 16, 16);
  // PV (rinv computed inline from partials) -> normalized fp8 ot
  k_pv<<<512, 512, 0, stream>>>(P8, vcm8, ot8, partial);
  // O-projection + residual + bias -> fp32 out
  k_oproj<<<512, 512, 0, stream>>>(ot8, Wo8, out, x, bo);
}

// Round 16
// 166.566 us; speedup vs baseline: 1.4689x; 1.1375x over previous
//
#include <hip/hip_runtime.h>
#include <hip/hip_bf16.h>
#include <stdint.h>

typedef __attribute__((ext_vector_type(4))) float f32x4;
typedef __attribute__((ext_vector_type(16))) float f32x16;
typedef __attribute__((ext_vector_type(4))) int i32x4;
typedef __attribute__((ext_vector_type(8))) int i32x8;
typedef long long ll64;
typedef __attribute__((ext_vector_type(2))) long long ll64x2;

__device__ __forceinline__ float fast_exp2(float x){
#if __has_builtin(__builtin_amdgcn_exp2f)
  return __builtin_amdgcn_exp2f(x);
#else
  return exp2f(x);
#endif
}
__device__ __forceinline__ unsigned char f2fp8(float f){
#if __has_builtin(__builtin_amdgcn_cvt_pk_fp8_f32)
  int r = __builtin_amdgcn_cvt_pk_fp8_f32(f, f, 0, false);
  return (unsigned char)(r & 0xff);
#else
  uint32_t u = __builtin_bit_cast(uint32_t, f);
  uint32_t s = (u >> 24) & 0x80u;
  uint32_t a = u & 0x7fffffffu;
  float af = __builtin_bit_cast(float, a);
  if (af >= 448.f) return (unsigned char)(s | 0x7e);
  a += 0x000fffffu + ((a >> 20) & 1u);
  int e = (int)(a >> 23) - 127;
  if (e < -6) return (unsigned char)s;
  return (unsigned char)(s | (uint32_t)((e + 7) << 3) | ((a >> 20) & 7u));
#endif
}
__device__ __forceinline__ uint32_t pack4(float a, float b, float c, float d){
#if __has_builtin(__builtin_amdgcn_cvt_pk_fp8_f32)
  int lo = __builtin_amdgcn_cvt_pk_fp8_f32(a, b, 0, false);
  int r  = __builtin_amdgcn_cvt_pk_fp8_f32(c, d, lo, true);
  return (uint32_t)r;
#else
  return (uint32_t)f2fp8(a) | ((uint32_t)f2fp8(b) << 8) |
         ((uint32_t)f2fp8(c) << 16) | ((uint32_t)f2fp8(d) << 24);
#endif
}
// k-interleave permutation: lane lk's two 8B chunks (true k lk*8, 32+lk*8) contiguous.
// For 4-aligned c: perm64(c+q) = perm64(c)+q, q<4.
__device__ __forceinline__ int perm64(int c){
  return (c & ~63) | (((c >> 3) & 3) << 4) | (((c >> 5) & 1) << 3) | (c & 7);
}
__device__ __forceinline__ void gl_lds16b(const unsigned char* g, unsigned char* l){
  __builtin_amdgcn_global_load_lds(
      (const __attribute__((address_space(1))) uint32_t*)g,
      (__attribute__((address_space(3))) uint32_t*)l, 16, 0, 0);
}

// 32x32 K=64 fp8 MFMA: scaled-MX with unit scales (2.3x rate) or 4x non-scaled fallback
__device__ __forceinline__ f32x16 mfma8_32x32x64(i32x8 a, i32x8 b, f32x16 c){
#if __has_builtin(__builtin_amdgcn_mfma_scale_f32_32x32x64_f8f6f4)
  return __builtin_amdgcn_mfma_scale_f32_32x32x64_f8f6f4(a, b, c, 0, 0,
                                                         0, 0x7f7f7f7f, 0, 0x7f7f7f7f);
#else
  ll64x2 al = __builtin_bit_cast(ll64x2, *(i32x4*)&a);
  ll64x2 ah; ah[0] = ((ll64*)&a)[2]; ah[1] = ((ll64*)&a)[3];
  ll64x2 bl = __builtin_bit_cast(ll64x2, *(i32x4*)&b);
  ll64x2 bh; bh[0] = ((ll64*)&b)[2]; bh[1] = ((ll64*)&b)[3];
  c = __builtin_amdgcn_mfma_f32_32x32x16_fp8_fp8(al[0], bl[0], c, 0, 0, 0);
  c = __builtin_amdgcn_mfma_f32_32x32x16_fp8_fp8(al[1], bl[1], c, 0, 0, 0);
  c = __builtin_amdgcn_mfma_f32_32x32x16_fp8_fp8(ah[0], bh[0], c, 0, 0, 0);
  c = __builtin_amdgcn_mfma_f32_32x32x16_fp8_fp8(ah[1], bh[1], c, 0, 0, 0);
  return c;
#endif
}

// ---------------- fused prep: GN partial stats (0..1023) + weight fp8 convert (1024..1535) ----
__global__ __launch_bounds__(256) void k_prep(const float* __restrict__ x,
                                              float* __restrict__ part,
                                              const float* __restrict__ Wq, const float* __restrict__ Wk,
                                              const float* __restrict__ Wv, const float* __restrict__ Wo,
                                              unsigned char* __restrict__ oqk,
                                              unsigned char* __restrict__ ov,
                                              unsigned char* __restrict__ oo){
  __shared__ float red[8];
  const int bid = blockIdx.x;
  if (bid < 1024) {
    const float* p = x + (size_t)bid * 8192;
    float s = 0.f, ss = 0.f;
    for (int i = threadIdx.x; i < 2048; i += 256) {
      float4 v = *(const float4*)(p + (size_t)i * 4);
      s  += v.x + v.y + v.z + v.w;
      ss += v.x*v.x + v.y*v.y + v.z*v.z + v.w*v.w;
    }
    for (int off = 32; off; off >>= 1) { s += __shfl_down(s, off); ss += __shfl_down(ss, off); }
    int w = threadIdx.x >> 6;
    if ((threadIdx.x & 63) == 0) { red[w] = s; red[w + 4] = ss; }
    __syncthreads();
    if (threadIdx.x == 0) {
      part[bid * 2]     = red[0] + red[1] + red[2] + red[3];
      part[bid * 2 + 1] = red[4] + red[5] + red[6] + red[7];
    }
  } else {
    const int cb = bid - 1024;
    const int sel = cb >> 7;
    const float* in = sel == 0 ? Wq : sel == 1 ? Wk : sel == 2 ? Wv : Wo;
    unsigned char* out = sel == 0 ? oqk : sel == 1 ? (oqk + 262144) : sel == 2 ? ov : oo;
    const int i = ((cb & 127) * 256 + threadIdx.x) * 8;
    const int row = i >> 9;
    const int c0  = i & 511;
    float4 v0 = *(const float4*)&in[i];
    float4 v1 = *(const float4*)&in[i + 4];
    unsigned char o[8];
    o[0]=f2fp8(v0.x); o[1]=f2fp8(v0.y); o[2]=f2fp8(v0.z); o[3]=f2fp8(v0.w);
    o[4]=f2fp8(v1.x); o[5]=f2fp8(v1.y); o[6]=f2fp8(v1.z); o[7]=f2fp8(v1.w);
    *(ll64*)&out[row * 512 + perm64(c0)] = *(ll64*)o;
  }
}

// ---------------- GN apply + transpose -> fp8 k-interleaved; final stat reduce inline ----------------
__global__ __launch_bounds__(256) void gn_apply(const float* __restrict__ x,
                                                const float* __restrict__ spart,
                                                const float* __restrict__ gamma,
                                                const float* __restrict__ beta,
                                                unsigned char* __restrict__ hn8){
  __shared__ float tile[64][33];
  const int b  = blockIdx.z;
  const int c0 = blockIdx.y * 64;
  const int p0 = blockIdx.x * 32;
  const int t  = threadIdx.x;
  const float* xb = x + (size_t)b * 512 * 4096;
  const int lpx = t & 31, lcc = t >> 5;
#pragma unroll
  for (int i = 0; i < 8; i++)
    tile[lcc + i * 8][lpx] = xb[(size_t)(c0 + lcc + i * 8) * 4096 + p0 + lpx];
  __syncthreads();
  unsigned char* hb = hn8 + (size_t)b * 4096 * 512;
  const int c   = c0 + (t & 31) * 2;
  const int pxi = t >> 5;
  const int g2  = b * 32 + (c >> 4);
  float sum = 0.f, ssum = 0.f;
#pragma unroll
  for (int i = 0; i < 8; i++) { sum += spart[(g2 * 8 + i) * 2]; ssum += spart[(g2 * 8 + i) * 2 + 1]; }
  const float mean = sum * (1.f / 65536.f);
  const float rstd = rsqrtf(ssum * (1.f / 65536.f) - mean * mean + 1e-6f);
  const float ga0 = gamma[c], be0 = beta[c];
  const float ga1 = gamma[c + 1], be1 = beta[c + 1];
  const int cp = perm64(c);
#pragma unroll
  for (int i = 0; i < 4; i++) {
    const int px = pxi + i * 8;
    float v0 = tile[(t & 31) * 2][px];
    float v1 = tile[(t & 31) * 2 + 1][px];
    unsigned int b0 = f2fp8((v0 - mean) * rstd * ga0 + be0);
    unsigned int b1 = f2fp8((v1 - mean) * rstd * ga1 + be1);
    *(unsigned short*)&hb[(size_t)(p0 + px) * 512 + cp] = (unsigned short)(b0 | (b1 << 8));
  }
}

// ---------------- unified scaled-fp8 GEMM body (swapped-operand epilogues) ----------------
// BM=128 (rows = pack dim), BN=128 (cols = lane dim), BK=64, NBUF=2.
// MODE 1 qkproj: A=Wqk[ch][k], B=hn[tok][k]; C^T[ch][tok] -> pack 4 ch -> qk8[tok][perm(ch)]
// MODE 2 vproj : A=hn[tok][k], B=Wv[ch][k]; C[tok][ch]   -> pack 4 tok -> vcm8[b][ch][perm(p)]
// MODE 4 pv    : A=vcm8[c][key], B=P8[q][key]; O^T[c][q]  -> *rinv(q) -> pack 4 c -> ot8[tok][perm(c)]
// MODE 5 oproj : A=ot8[tok][k], B=Wo[ch][k]; +resid+bias -> fp32 transposed out
template<int MODE>
__device__ __forceinline__ void gemm8_body(
    int wg, unsigned char* smem,
    const unsigned char* __restrict__ A, const unsigned char* __restrict__ B,
    unsigned char* __restrict__ C8, float* __restrict__ OUTF,
    const float* __restrict__ auxA, const float* __restrict__ auxB,
    const float* __restrict__ partial,
    int K, int ldA, int ldB,
    size_t sA, size_t sB, int gx, int gy)
{
  unsigned char* As = smem;
  unsigned char* Bs = smem + 16384;

  const int bx = wg % gx;
  const int t2 = wg / gx;
  const int by = t2 % gy;
  const int bz = t2 / gy;

  const unsigned char* Ab = A + (size_t)bz * sA;
  const unsigned char* Bb = B + (size_t)bz * sB;
  const int brow = bx * 128;
  const int bcol = by * 128;
  const int t = threadIdx.x;
  const int lane = t & 63;
  const int wid = t >> 6;
  const int wr = wid >> 2;        // 0..1 (64 rows)
  const int wc = wid & 3;         // 0..3 (32 cols)
  const int l31 = lane & 31;
  const int lh  = lane >> 5;

  f32x16 acc[2];
#pragma unroll
  for (int m = 0; m < 2; m++)
#pragma unroll
    for (int e = 0; e < 16; e++) acc[m][e] = 0.f;

  const unsigned char* srcA1;
  const unsigned char* srcB1;
  {
    const int r = t >> 2, s = (t & 3) ^ ((r >> 1) & 3);
    srcA1 = Ab + (size_t)(brow + r) * ldA + s * 16;
    srcB1 = Bb + (size_t)(bcol + r) * ldB + s * 16;
  }
  auto STAGE = [&](int kt, int buf) {
    const int ko = kt * 64;
    gl_lds16b(srcA1 + ko, &As[buf * 8192 + t * 16]);
    gl_lds16b(srcB1 + ko, &Bs[buf * 8192 + t * 16]);
  };
  auto LDA32 = [&](int buf, int mb) -> i32x8 {
    const int ru = wr * 64 + mb * 32 + l31;
    const int x = (ru >> 1) & 3;
    const unsigned char* base = &As[buf * 8192 + ru * 64];
    i32x4 lo = *(const i32x4*)&base[((2 * lh) ^ x) * 16];
    i32x4 hi = *(const i32x4*)&base[((2 * lh + 1) ^ x) * 16];
    i32x8 r;
    r[0]=lo[0]; r[1]=lo[1]; r[2]=lo[2]; r[3]=lo[3];
    r[4]=hi[0]; r[5]=hi[1]; r[6]=hi[2]; r[7]=hi[3];
    return r;
  };
  auto LDB32 = [&](int buf) -> i32x8 {
    const int ru = wc * 32 + l31;
    const int x = (ru >> 1) & 3;
    const unsigned char* base = &Bs[buf * 8192 + ru * 64];
    i32x4 lo = *(const i32x4*)&base[((2 * lh) ^ x) * 16];
    i32x4 hi = *(const i32x4*)&base[((2 * lh + 1) ^ x) * 16];
    i32x8 r;
    r[0]=lo[0]; r[1]=lo[1]; r[2]=lo[2]; r[3]=lo[3];
    r[4]=hi[0]; r[5]=hi[1]; r[6]=hi[2]; r[7]=hi[3];
    return r;
  };

  const int nk = K >> 6;
  STAGE(0, 0);
  for (int j = 0; j < nk; ++j) {
    const int bi = j & 1;
    asm volatile("s_waitcnt vmcnt(0)" ::: "memory");
    __builtin_amdgcn_s_barrier();
    __builtin_amdgcn_sched_barrier(0);
    if (j + 1 < nk) STAGE(j + 1, bi ^ 1);
    i32x8 aq[2], bq;
    bq = LDB32(bi);
#pragma unroll
    for (int m = 0; m < 2; m++) aq[m] = LDA32(bi, m);
    asm volatile("s_waitcnt lgkmcnt(0)" ::: "memory");
    __builtin_amdgcn_sched_barrier(0);
    __builtin_amdgcn_s_setprio(1);
#pragma unroll
    for (int m = 0; m < 2; m++)
      acc[m] = mfma8_32x32x64(aq[m], bq, acc[m]);
    __builtin_amdgcn_s_setprio(0);
    __builtin_amdgcn_sched_barrier(0);
  }

  // epilogue (32x32 C/D: col=lane&31, row=(reg&3)+8*(reg>>2)+4*(lane>>5))
  const int rowbase = brow + wr * 64;
  const int colbase = bcol + wc * 32;
  const int col = colbase + l31;

  if (MODE == 1) {
    const int tok = col;
#pragma unroll
    for (int mb = 0; mb < 2; mb++)
#pragma unroll
      for (int g = 0; g < 4; g++) {
        const int ch0 = rowbase + mb * 32 + g * 8 + 4 * lh;
        const float* bp = (ch0 < 512) ? (auxA + ch0) : (auxB + ch0 - 512);
        const float4 b4 = *(const float4*)bp;
        unsigned char* dst = C8 + (ch0 < 512 ? 0 : (size_t)8388608);
        const int cp = perm64(ch0 & 511);
        uint32_t w = pack4(acc[mb][g*4+0] + b4.x, acc[mb][g*4+1] + b4.y,
                           acc[mb][g*4+2] + b4.z, acc[mb][g*4+3] + b4.w);
        *(uint32_t*)&dst[(size_t)tok * 512 + cp] = w;
      }
  } else if (MODE == 2) {
    const float bcv = auxA[col];
#pragma unroll
    for (int mb = 0; mb < 2; mb++)
#pragma unroll
      for (int g = 0; g < 4; g++) {
        const int t0 = rowbase + mb * 32 + g * 8 + 4 * lh;   // token
        const int bb = t0 >> 12, p0 = t0 & 4095;
        uint32_t w = pack4(acc[mb][g*4+0] + bcv, acc[mb][g*4+1] + bcv,
                           acc[mb][g*4+2] + bcv, acc[mb][g*4+3] + bcv);
        *(uint32_t*)&C8[((size_t)bb * 512 + col) * 4096 + perm64(p0)] = w;
      }
  } else if (MODE == 4) {
    // inline rinv for q in [bcol, bcol+128) from partial[bz][32][4096]
    float* rtmp  = (float*)(smem + 32768);
    float* rinvL = (float*)(smem + 32768 + 2048);
    {
      const int row = t >> 2, q4 = t & 3;
      const float* pb = partial + ((size_t)bz * 32 + q4 * 8) * 4096 + (bcol + row);
      float s = 0.f;
#pragma unroll
      for (int i = 0; i < 8; i++) s += pb[(size_t)i * 4096];
      rtmp[row * 4 + q4] = s;
    }
    __syncthreads();
    if (t < 128) rinvL[t] = 1.f / (rtmp[t * 4] + rtmp[t * 4 + 1] + rtmp[t * 4 + 2] + rtmp[t * 4 + 3]);
    __syncthreads();
    const int ql = wc * 32 + l31;
    const float ri = rinvL[ql];
    const size_t tok = (size_t)bz * 4096 + bcol + ql;
#pragma unroll
    for (int mb = 0; mb < 2; mb++)
#pragma unroll
      for (int g = 0; g < 4; g++) {
        const int c0 = rowbase + mb * 32 + g * 8 + 4 * lh;   // channel
        uint32_t w = pack4(acc[mb][g*4+0] * ri, acc[mb][g*4+1] * ri,
                           acc[mb][g*4+2] * ri, acc[mb][g*4+3] * ri);
        *(uint32_t*)&C8[tok * 512 + perm64(c0)] = w;
      }
  } else { // MODE 5
    const float bv = auxB[col];
#pragma unroll
    for (int mb = 0; mb < 2; mb++)
#pragma unroll
      for (int g = 0; g < 4; g++) {
        const int r0 = rowbase + mb * 32 + g * 8 + 4 * lh;
        const int bb = r0 >> 12;
        const int p  = r0 & 4095;
        const size_t idx = ((size_t)bb * 512 + col) * 4096 + p;
        const float4 xv = *(const float4*)&auxA[idx];
        float4 ov;
        ov.x = acc[mb][g * 4 + 0] + xv.x + bv;
        ov.y = acc[mb][g * 4 + 1] + xv.y + bv;
        ov.z = acc[mb][g * 4 + 2] + xv.z + bv;
        ov.w = acc[mb][g * 4 + 3] + xv.w + bv;
        *(float4*)&OUTF[idx] = ov;
      }
  }
}

// ---------------- fused QK+V projections ----------------
__global__ __launch_bounds__(512, 2)
void k_qkv(const unsigned char* __restrict__ hn8, const unsigned char* __restrict__ Wqk8,
           const unsigned char* __restrict__ Wv8,
           unsigned char* __restrict__ qk8, unsigned char* __restrict__ vcm8,
           const float* __restrict__ bq, const float* __restrict__ bk,
           const float* __restrict__ bv){
  __shared__ __align__(16) unsigned char SMEM[32768];
  const int lin = blockIdx.x;
  const int nwg = gridDim.x;   // 1536
  const int wg = ((lin & 7) * (nwg >> 3)) + (lin >> 3);
  if (wg < 1024)
    // A=Wqk (1024 ch), B=hn (16384 tok): gx=8, gy=128
    gemm8_body<1>(wg, SMEM, Wqk8, hn8, qk8, nullptr, bq, bk, nullptr,
                  512, 512, 512, 0, 0, 8, 128);
  else
    // A=hn (16384 tok), B=Wv (512 ch): gx=128, gy=4
    gemm8_body<2>(wg - 1024, SMEM, hn8, Wv8, vcm8, nullptr, bv, nullptr, nullptr,
                  512, 512, 512, 0, 0, 128, 4);
}

// ---------------- PV (swapped: A=V, B=P; rinv inline) and O-proj ----------------
__global__ __launch_bounds__(512, 2)
void k_pv(const unsigned char* __restrict__ vcm8, const unsigned char* __restrict__ P8,
          unsigned char* __restrict__ ot8, const float* __restrict__ partial){
  __shared__ __align__(16) unsigned char SMEM[32768 + 2560];
  const int lin = blockIdx.x;
  const int nwg = gridDim.x;   // 512
  const int wg = ((lin & 7) * (nwg >> 3)) + (lin >> 3);
  // A=vcm8[b] (512 c x 4096 keys), B=P8[b] (4096 q x 4096 keys): gx=4, gy=32, bz=b
  gemm8_body<4>(wg, SMEM, vcm8, P8, ot8, nullptr, nullptr, nullptr, partial,
                4096, 4096, 4096,
                (size_t)512 * 4096, (size_t)4096 * 4096, 4, 32);
}
__global__ __launch_bounds__(512, 2)
void k_oproj(const unsigned char* __restrict__ ot8, const unsigned char* __restrict__ Wo8,
             float* __restrict__ out, const float* __restrict__ resid,
             const float* __restrict__ bo){
  __shared__ __align__(16) unsigned char SMEM[32768];
  const int lin = blockIdx.x;
  const int nwg = gridDim.x;   // 512
  const int wg = ((lin & 7) * (nwg >> 3)) + (lin >> 3);
  gemm8_body<5>(wg, SMEM, ot8, Wo8, nullptr, out, resid, bo, nullptr,
                512, 512, 512, 0, 0, 128, 4);
}

// ---------------- scaled-fp8 scores, SWAPPED: S^T = K x Q^T ----------------
// BM=BN=256, BK=64, NBUF=2. rows=keys, cols=queries. P packed 4-keys/u32 into
// swizzled LDS tile [256 q][256 perm-key], then coalesced b128 copy-out.
__global__ __launch_bounds__(512, 2)
void k_scores(const unsigned char* __restrict__ Kt, const unsigned char* __restrict__ Qt,
              unsigned char* __restrict__ C, const float* __restrict__ mask,
              float* __restrict__ partial, float scale,
              size_t sA, size_t sB, size_t sC, int gx, int gy)
{
  __shared__ __align__(16) unsigned char LDSBUF[65536];
  unsigned char* As = LDSBUF;
  unsigned char* Bs = LDSBUF + 32768;

  const int lin = blockIdx.x;
  const int nwg = gridDim.x;
  const int wg = ((lin & 7) * (nwg >> 3)) + (lin >> 3);
  const int bx = wg % gx;          // key block
  const int t2 = wg / gx;
  const int by = t2 % gy;          // query block
  const int bz = t2 / gy;

  const unsigned char* Ab = Kt + (size_t)bz * sA;
  const unsigned char* Bb = Qt + (size_t)bz * sB;
  const int brow = bx * 256;       // keys
  const int bcol = by * 256;       // queries
  const int t = threadIdx.x;
  const int lane = t & 63;
  const int wid = t >> 6;
  const int wr = wid >> 2;         // key half (128)
  const int wc = wid & 3;          // query quarter (64)
  const int l31 = lane & 31;
  const int lh  = lane >> 5;

  f32x16 acc[4][2];
#pragma unroll
  for (int m = 0; m < 4; m++)
#pragma unroll
    for (int n = 0; n < 2; n++)
#pragma unroll
      for (int e = 0; e < 16; e++) acc[m][n][e] = 0.f;

  const unsigned char* srcA[2];
  const unsigned char* srcB[2];
#pragma unroll
  for (int c = 0; c < 2; ++c) {
    const int q = c * 512 + t, r = q >> 2, s = (q & 3) ^ ((r >> 1) & 3);
    srcA[c] = Ab + (size_t)(brow + r) * 512 + s * 16;
    srcB[c] = Bb + (size_t)(bcol + r) * 512 + s * 16;
  }
  auto STAGE = [&](int kt, int buf) {
    const int ko = kt * 64;
#pragma unroll
    for (int c = 0; c < 2; ++c) {
      gl_lds16b(srcA[c] + ko, &As[buf * 16384 + (c * 512 + t) * 16]);
      gl_lds16b(srcB[c] + ko, &Bs[buf * 16384 + (c * 512 + t) * 16]);
    }
  };
  auto LDA32 = [&](int buf, int mb) -> i32x8 {
    const int ru = wr * 128 + mb * 32 + l31;
    const int x = (ru >> 1) & 3;
    const unsigned char* base = &As[buf * 16384 + ru * 64];
    i32x4 lo = *(const i32x4*)&base[((2 * lh) ^ x) * 16];
    i32x4 hi = *(const i32x4*)&base[((2 * lh + 1) ^ x) * 16];
    i32x8 r;
    r[0]=lo[0]; r[1]=lo[1]; r[2]=lo[2]; r[3]=lo[3];
    r[4]=hi[0]; r[5]=hi[1]; r[6]=hi[2]; r[7]=hi[3];
    return r;
  };
  auto LDB32 = [&](int buf, int nb) -> i32x8 {
    const int ru = wc * 64 + nb * 32 + l31;
    const int x = (ru >> 1) & 3;
    const unsigned char* base = &Bs[buf * 16384 + ru * 64];
    i32x4 lo = *(const i32x4*)&base[((2 * lh) ^ x) * 16];
    i32x4 hi = *(const i32x4*)&base[((2 * lh + 1) ^ x) * 16];
    i32x8 r;
    r[0]=lo[0]; r[1]=lo[1]; r[2]=lo[2]; r[3]=lo[3];
    r[4]=hi[0]; r[5]=hi[1]; r[6]=hi[2]; r[7]=hi[3];
    return r;
  };

  const int nk = 8;    // K=512
  STAGE(0, 0);
  for (int j = 0; j < nk; ++j) {
    const int bi = j & 1;
    asm volatile("s_waitcnt vmcnt(0)" ::: "memory");
    __builtin_amdgcn_s_barrier();
    __builtin_amdgcn_sched_barrier(0);
    if (j + 1 < nk) STAGE(j + 1, bi ^ 1);
    i32x8 aq[4], bq[2];
#pragma unroll
    for (int n = 0; n < 2; n++) bq[n] = LDB32(bi, n);
#pragma unroll
    for (int m = 0; m < 4; m++) aq[m] = LDA32(bi, m);
    asm volatile("s_waitcnt lgkmcnt(0)" ::: "memory");
    __builtin_amdgcn_sched_barrier(0);
    __builtin_amdgcn_s_setprio(1);
#pragma unroll
    for (int m = 0; m < 4; m++)
#pragma unroll
      for (int n = 0; n < 2; n++)
        acc[m][n] = mfma8_32x32x64(aq[m], bq[n], acc[m][n]);
    __builtin_amdgcn_s_setprio(0);
    __builtin_amdgcn_sched_barrier(0);
  }

  // epilogue: rows = keys, cols = queries
  const float* maskb = mask + (size_t)bz * 4096;
  const float sc2 = scale * 1.4426950408889634f;

  asm volatile("s_waitcnt lgkmcnt(0)" ::: "memory");
  __builtin_amdgcn_s_barrier();

  float rs0 = 0.f, rs1 = 0.f;   // per-(lane,ni) query rowsums over this lane's keys
#pragma unroll
  for (int mi = 0; mi < 4; mi++) {
#pragma unroll
    for (int g = 0; g < 4; g++) {
      const int kl0 = wr * 128 + mi * 32 + g * 8 + 4 * lh;   // block-local key (4-aligned)
      const float4 m4 = *(const float4*)&maskb[brow + kl0];
      const int kp = perm64(kl0);
#pragma unroll
      for (int ni = 0; ni < 2; ni++) {
        const int reg = g * 4;
        float v0 = m4.x * fast_exp2(acc[mi][ni][reg + 0] * sc2);
        float v1 = m4.y * fast_exp2(acc[mi][ni][reg + 1] * sc2);
        float v2 = m4.z * fast_exp2(acc[mi][ni][reg + 2] * sc2);
        float v3 = m4.w * fast_exp2(acc[mi][ni][reg + 3] * sc2);
        if (ni == 0) rs0 += v0 + v1 + v2 + v3; else rs1 += v0 + v1 + v2 + v3;
        const int ql = wc * 64 + ni * 32 + l31;
        *(uint32_t*)&LDSBUF[ql * 256 + (kp ^ ((ql & 15) << 4))] = pack4(v0, v1, v2, v3);
      }
    }
  }
  // combine lh halves (lane ^ 32 has the other half of this wr's keys, same query)
  rs0 += __shfl_xor(rs0, 32);
  rs1 += __shfl_xor(rs1, 32);
  if (lh == 0) {
    float* pslot = partial + ((size_t)bz * 32 + (size_t)(bx * 2 + wr)) * 4096;
    pslot[bcol + wc * 64 + l31]      = rs0;
    pslot[bcol + wc * 64 + 32 + l31] = rs1;
  }
  __builtin_amdgcn_s_barrier();
  // coalesced copy-out: P8[q][perm-key], rows q stride 4096
  unsigned char* Cb = C + (size_t)bz * sC;
#pragma unroll
  for (int i = 0; i < 8; i++) {
    const int ch = i * 512 + t;
    const int rl = ch >> 4;              // local q
    const int c16 = (ch & 15) * 16;      // perm-key chunk
    i32x4 v = *(const i32x4*)&LDSBUF[rl * 256 + (c16 ^ ((rl & 15) << 4))];
    *(i32x4*)&Cb[(size_t)(bcol + rl) * 4096 + brow + c16] = v;
  }
}

extern "C" void kernel_launch(void* const* d_in, const int* in_sizes, int n_in,
                              void* d_out, int out_size, void* d_ws, size_t ws_size,
                              hipStream_t stream) {
  const float* x     = (const float*)d_in[0];
  const float* mask  = (const float*)d_in[1];
  const float* gamma = (const float*)d_in[2];
  const float* beta  = (const float*)d_in[3];
  const float* Wq    = (const float*)d_in[4];
  const float* bq    = (const float*)d_in[5];
  const float* Wk    = (const float*)d_in[6];
  const float* bk    = (const float*)d_in[7];
  const float* Wv    = (const float*)d_in[8];
  const float* bv    = (const float*)d_in[9];
  const float* Wo    = (const float*)d_in[10];
  const float* bo    = (const float*)d_in[11];
  float* out = (float*)d_out;

  size_t off = 0;
  auto nxt = [&](size_t bytes) -> void* {
    void* p = (char*)d_ws + off;
    off += (bytes + 255) & ~(size_t)255;
    return p;
  };
  float* spart          = (float*)nxt(2048 * sizeof(float));
  float* partial        = (float*)nxt((size_t)4 * 32 * 4096 * 4);
  unsigned char* Wqk8   = (unsigned char*)nxt((size_t)1024 * 512);
  unsigned char* Wv8    = (unsigned char*)nxt((size_t)512 * 512);
  unsigned char* Wo8    = (unsigned char*)nxt((size_t)512 * 512);
  unsigned char* hn8    = (unsigned char*)nxt((size_t)16384 * 512);
  unsigned char* qk8    = (unsigned char*)nxt((size_t)2 * 16384 * 512);
  unsigned char* vcm8   = (unsigned char*)nxt((size_t)4 * 512 * 4096);
  unsigned char* ot8    = (unsigned char*)nxt((size_t)16384 * 512);
  unsigned char* P8     = (unsigned char*)nxt((size_t)4 * 4096 * 4096);

  k_prep<<<1536, 256, 0, stream>>>(x, spart, Wq, Wk, Wv, Wo, Wqk8, Wv8, Wo8);
  gn_apply<<<dim3(128, 8, 4), 256, 0, stream>>>(x, spart, gamma, beta, hn8);
  k_qkv<<<1536, 512, 0, stream>>>(hn8, Wqk8, Wv8, qk8, vcm8, bq, bk, bv);
  // scores swapped: A=K, B=Q; gx=16 key-blocks, gy=16 q-blocks, gz=4
  k_scores<<<1024, 512, 0, stream>>>(qk8 + (size_t)8388608, qk8, P8, mask, partial,
                                     0.044194173824159216f,
                                     (size_t)4096 * 512, (size_t)4096 * 512,
                                     (size_t)4096 * 4096, 16, 16);
  k_pv<<<512, 512, 0, stream>>>(vcm8, P8, ot8, partial);
  k_oproj<<<512, 512, 0, stream>>>(ot8, Wo8, out, x, bo);
}

// Round 17
// 149.029 us; speedup vs baseline: 1.6418x; 1.1177x over previous
//
#include <hip/hip_runtime.h>
#include <hip/hip_bf16.h>
#include <stdint.h>

typedef __attribute__((ext_vector_type(4))) float f32x4;
typedef __attribute__((ext_vector_type(16))) float f32x16;
typedef __attribute__((ext_vector_type(4))) int i32x4;
typedef __attribute__((ext_vector_type(8))) int i32x8;
typedef long long ll64;
typedef __attribute__((ext_vector_type(2))) long long ll64x2;

__device__ __forceinline__ float fast_exp2(float x){
#if __has_builtin(__builtin_amdgcn_exp2f)
  return __builtin_amdgcn_exp2f(x);
#else
  return exp2f(x);
#endif
}
__device__ __forceinline__ unsigned char f2fp8(float f){
#if __has_builtin(__builtin_amdgcn_cvt_pk_fp8_f32)
  int r = __builtin_amdgcn_cvt_pk_fp8_f32(f, f, 0, false);
  return (unsigned char)(r & 0xff);
#else
  uint32_t u = __builtin_bit_cast(uint32_t, f);
  uint32_t s = (u >> 24) & 0x80u;
  uint32_t a = u & 0x7fffffffu;
  float af = __builtin_bit_cast(float, a);
  if (af >= 448.f) return (unsigned char)(s | 0x7e);
  a += 0x000fffffu + ((a >> 20) & 1u);
  int e = (int)(a >> 23) - 127;
  if (e < -6) return (unsigned char)s;
  return (unsigned char)(s | (uint32_t)((e + 7) << 3) | ((a >> 20) & 7u));
#endif
}
__device__ __forceinline__ uint32_t pack4(float a, float b, float c, float d){
#if __has_builtin(__builtin_amdgcn_cvt_pk_fp8_f32)
  int lo = __builtin_amdgcn_cvt_pk_fp8_f32(a, b, 0, false);
  int r  = __builtin_amdgcn_cvt_pk_fp8_f32(c, d, lo, true);
  return (uint32_t)r;
#else
  return (uint32_t)f2fp8(a) | ((uint32_t)f2fp8(b) << 8) |
         ((uint32_t)f2fp8(c) << 16) | ((uint32_t)f2fp8(d) << 24);
#endif
}
// k-interleave permutation; for 4-aligned c: perm64(c+q)=perm64(c)+q, q<4.
// Also perm64(base+l) = base + perm64(l) when base is a multiple of 64.
__device__ __forceinline__ int perm64(int c){
  return (c & ~63) | (((c >> 3) & 3) << 4) | (((c >> 5) & 1) << 3) | (c & 7);
}
__device__ __forceinline__ void gl_lds16b(const unsigned char* g, unsigned char* l){
  __builtin_amdgcn_global_load_lds(
      (const __attribute__((address_space(1))) uint32_t*)g,
      (__attribute__((address_space(3))) uint32_t*)l, 16, 0, 0);
}

// 32x32 K=64 fp8 MFMA: scaled-MX with unit scales (2.3x rate) or 4x non-scaled fallback
__device__ __forceinline__ f32x16 mfma8_32x32x64(i32x8 a, i32x8 b, f32x16 c){
#if __has_builtin(__builtin_amdgcn_mfma_scale_f32_32x32x64_f8f6f4)
  return __builtin_amdgcn_mfma_scale_f32_32x32x64_f8f6f4(a, b, c, 0, 0,
                                                         0, 0x7f7f7f7f, 0, 0x7f7f7f7f);
#else
  ll64x2 al = __builtin_bit_cast(ll64x2, *(i32x4*)&a);
  ll64x2 ah; ah[0] = ((ll64*)&a)[2]; ah[1] = ((ll64*)&a)[3];
  ll64x2 bl = __builtin_bit_cast(ll64x2, *(i32x4*)&b);
  ll64x2 bh; bh[0] = ((ll64*)&b)[2]; bh[1] = ((ll64*)&b)[3];
  c = __builtin_amdgcn_mfma_f32_32x32x16_fp8_fp8(al[0], bl[0], c, 0, 0, 0);
  c = __builtin_amdgcn_mfma_f32_32x32x16_fp8_fp8(al[1], bl[1], c, 0, 0, 0);
  c = __builtin_amdgcn_mfma_f32_32x32x16_fp8_fp8(ah[0], bh[0], c, 0, 0, 0);
  c = __builtin_amdgcn_mfma_f32_32x32x16_fp8_fp8(ah[1], bh[1], c, 0, 0, 0);
  return c;
#endif
}

// ---------------- fused prep: GN partial stats (0..1023) + weight fp8 convert (1024..1535) ----
__global__ __launch_bounds__(256) void k_prep(const float* __restrict__ x,
                                              float* __restrict__ part,
                                              const float* __restrict__ Wq, const float* __restrict__ Wk,
                                              const float* __restrict__ Wv, const float* __restrict__ Wo,
                                              unsigned char* __restrict__ oqk,
                                              unsigned char* __restrict__ ov,
                                              unsigned char* __restrict__ oo){
  __shared__ float red[8];
  const int bid = blockIdx.x;
  if (bid < 1024) {
    const float* p = x + (size_t)bid * 8192;
    float s = 0.f, ss = 0.f;
    for (int i = threadIdx.x; i < 2048; i += 256) {
      float4 v = *(const float4*)(p + (size_t)i * 4);
      s  += v.x + v.y + v.z + v.w;
      ss += v.x*v.x + v.y*v.y + v.z*v.z + v.w*v.w;
    }
    for (int off = 32; off; off >>= 1) { s += __shfl_down(s, off); ss += __shfl_down(ss, off); }
    int w = threadIdx.x >> 6;
    if ((threadIdx.x & 63) == 0) { red[w] = s; red[w + 4] = ss; }
    __syncthreads();
    if (threadIdx.x == 0) {
      part[bid * 2]     = red[0] + red[1] + red[2] + red[3];
      part[bid * 2 + 1] = red[4] + red[5] + red[6] + red[7];
    }
  } else {
    const int cb = bid - 1024;
    const int sel = cb >> 7;
    const float* in = sel == 0 ? Wq : sel == 1 ? Wk : sel == 2 ? Wv : Wo;
    unsigned char* out = sel == 0 ? oqk : sel == 1 ? (oqk + 262144) : sel == 2 ? ov : oo;
    const int i = ((cb & 127) * 256 + threadIdx.x) * 8;
    const int row = i >> 9;
    const int c0  = i & 511;
    float4 v0 = *(const float4*)&in[i];
    float4 v1 = *(const float4*)&in[i + 4];
    unsigned char o[8];
    o[0]=f2fp8(v0.x); o[1]=f2fp8(v0.y); o[2]=f2fp8(v0.z); o[3]=f2fp8(v0.w);
    o[4]=f2fp8(v1.x); o[5]=f2fp8(v1.y); o[6]=f2fp8(v1.z); o[7]=f2fp8(v1.w);
    *(ll64*)&out[row * 512 + perm64(c0)] = *(ll64*)o;
  }
}

// ---------------- GN apply + transpose -> fp8 k-interleaved; final stat reduce inline ----------------
__global__ __launch_bounds__(256) void gn_apply(const float* __restrict__ x,
                                                const float* __restrict__ spart,
                                                const float* __restrict__ gamma,
                                                const float* __restrict__ beta,
                                                unsigned char* __restrict__ hn8){
  __shared__ float tile[64][33];
  const int b  = blockIdx.z;
  const int c0 = blockIdx.y * 64;
  const int p0 = blockIdx.x * 32;
  const int t  = threadIdx.x;
  const float* xb = x + (size_t)b * 512 * 4096;
  const int lpx = t & 31, lcc = t >> 5;
#pragma unroll
  for (int i = 0; i < 8; i++)
    tile[lcc + i * 8][lpx] = xb[(size_t)(c0 + lcc + i * 8) * 4096 + p0 + lpx];
  __syncthreads();
  unsigned char* hb = hn8 + (size_t)b * 4096 * 512;
  const int c   = c0 + (t & 31) * 2;
  const int pxi = t >> 5;
  const int g2  = b * 32 + (c >> 4);
  float sum = 0.f, ssum = 0.f;
#pragma unroll
  for (int i = 0; i < 8; i++) { sum += spart[(g2 * 8 + i) * 2]; ssum += spart[(g2 * 8 + i) * 2 + 1]; }
  const float mean = sum * (1.f / 65536.f);
  const float rstd = rsqrtf(ssum * (1.f / 65536.f) - mean * mean + 1e-6f);
  const float ga0 = gamma[c], be0 = beta[c];
  const float ga1 = gamma[c + 1], be1 = beta[c + 1];
  const int cp = perm64(c);
#pragma unroll
  for (int i = 0; i < 4; i++) {
    const int px = pxi + i * 8;
    float v0 = tile[(t & 31) * 2][px];
    float v1 = tile[(t & 31) * 2 + 1][px];
    unsigned int b0 = f2fp8((v0 - mean) * rstd * ga0 + be0);
    unsigned int b1 = f2fp8((v1 - mean) * rstd * ga1 + be1);
    *(unsigned short*)&hb[(size_t)(p0 + px) * 512 + cp] = (unsigned short)(b0 | (b1 << 8));
  }
}

// ---------------- unified scaled-fp8 GEMM body; LDS-transpose coalesced epilogues ----------------
// BM=128 (rows = pack dim), BN=128 (cols = lane dim), BK=64, NBUF=2.
// MODE 1 qkproj: A=Wqk[ch][k], B=hn[tok][k]; tile[ch][tok] -> qk8[tok][perm(ch)] via LDS
// MODE 2 vproj : A=hn[tok][k], B=Wv[ch][k]; tile[tok][ch] -> vcm8[b][ch][perm(p)] via LDS
// MODE 4 pv    : A=vcm8[c][key], B=P8[q][key]; *rinv(q)   -> ot8[tok][perm(c)] via LDS
// MODE 5 oproj : A=Wo[ch][k], B=ot8[tok][k]; +resid+bias  -> fp32 out (lane-coalesced in p)
template<int MODE>
__device__ __forceinline__ void gemm8_body(
    int wg, unsigned char* smem,
    const unsigned char* __restrict__ A, const unsigned char* __restrict__ B,
    unsigned char* __restrict__ C8, float* __restrict__ OUTF,
    const float* __restrict__ auxA, const float* __restrict__ auxB,
    const float* __restrict__ partial,
    int K, int ldA, int ldB,
    size_t sA, size_t sB, int gx, int gy)
{
  unsigned char* As = smem;
  unsigned char* Bs = smem + 16384;

  const int bx = wg % gx;
  const int t2 = wg / gx;
  const int by = t2 % gy;
  const int bz = t2 / gy;

  const unsigned char* Ab = A + (size_t)bz * sA;
  const unsigned char* Bb = B + (size_t)bz * sB;
  const int brow = bx * 128;
  const int bcol = by * 128;
  const int t = threadIdx.x;
  const int lane = t & 63;
  const int wid = t >> 6;
  const int wr = wid >> 2;        // 0..1 (64 rows)
  const int wc = wid & 3;         // 0..3 (32 cols)
  const int l31 = lane & 31;
  const int lh  = lane >> 5;

  f32x16 acc[2];
#pragma unroll
  for (int m = 0; m < 2; m++)
#pragma unroll
    for (int e = 0; e < 16; e++) acc[m][e] = 0.f;

  const unsigned char* srcA1;
  const unsigned char* srcB1;
  {
    const int r = t >> 2, s = (t & 3) ^ ((r >> 1) & 3);
    srcA1 = Ab + (size_t)(brow + r) * ldA + s * 16;
    srcB1 = Bb + (size_t)(bcol + r) * ldB + s * 16;
  }
  auto STAGE = [&](int kt, int buf) {
    const int ko = kt * 64;
    gl_lds16b(srcA1 + ko, &As[buf * 8192 + t * 16]);
    gl_lds16b(srcB1 + ko, &Bs[buf * 8192 + t * 16]);
  };
  auto LDA32 = [&](int buf, int mb) -> i32x8 {
    const int ru = wr * 64 + mb * 32 + l31;
    const int x = (ru >> 1) & 3;
    const unsigned char* base = &As[buf * 8192 + ru * 64];
    i32x4 lo = *(const i32x4*)&base[((2 * lh) ^ x) * 16];
    i32x4 hi = *(const i32x4*)&base[((2 * lh + 1) ^ x) * 16];
    i32x8 r;
    r[0]=lo[0]; r[1]=lo[1]; r[2]=lo[2]; r[3]=lo[3];
    r[4]=hi[0]; r[5]=hi[1]; r[6]=hi[2]; r[7]=hi[3];
    return r;
  };
  auto LDB32 = [&](int buf) -> i32x8 {
    const int ru = wc * 32 + l31;
    const int x = (ru >> 1) & 3;
    const unsigned char* base = &Bs[buf * 8192 + ru * 64];
    i32x4 lo = *(const i32x4*)&base[((2 * lh) ^ x) * 16];
    i32x4 hi = *(const i32x4*)&base[((2 * lh + 1) ^ x) * 16];
    i32x8 r;
    r[0]=lo[0]; r[1]=lo[1]; r[2]=lo[2]; r[3]=lo[3];
    r[4]=hi[0]; r[5]=hi[1]; r[6]=hi[2]; r[7]=hi[3];
    return r;
  };

  const int nk = K >> 6;
  STAGE(0, 0);
  for (int j = 0; j < nk; ++j) {
    const int bi = j & 1;
    asm volatile("s_waitcnt vmcnt(0)" ::: "memory");
    __builtin_amdgcn_s_barrier();
    __builtin_amdgcn_sched_barrier(0);
    if (j + 1 < nk) STAGE(j + 1, bi ^ 1);
    i32x8 aq[2], bq;
    bq = LDB32(bi);
#pragma unroll
    for (int m = 0; m < 2; m++) aq[m] = LDA32(bi, m);
    asm volatile("s_waitcnt lgkmcnt(0)" ::: "memory");
    __builtin_amdgcn_sched_barrier(0);
    __builtin_amdgcn_s_setprio(1);
#pragma unroll
    for (int m = 0; m < 2; m++)
      acc[m] = mfma8_32x32x64(aq[m], bq, acc[m]);
    __builtin_amdgcn_s_setprio(0);
    __builtin_amdgcn_sched_barrier(0);
  }

  // epilogues (32x32 C/D: col=lane&31, row=(reg&3)+8*(reg>>2)+4*(lane>>5))
  const int lcol = wc * 32 + l31;          // block-local col (lane dim)

  if (MODE == 1) {
    // tile[ch rows][tok cols]; out qk8[tok][perm(ch)]
    asm volatile("s_waitcnt lgkmcnt(0)" ::: "memory");
    __builtin_amdgcn_s_barrier();
#pragma unroll
    for (int mb = 0; mb < 2; mb++)
#pragma unroll
      for (int g = 0; g < 4; g++) {
        const int lch0 = wr * 64 + mb * 32 + g * 8 + 4 * lh;
        const int ch0 = brow + lch0;
        const float4 b4 = *(const float4*)((ch0 < 512) ? (auxA + ch0) : (auxB + ch0 - 512));
        const int cpL = perm64(lch0 & 127) | (lch0 & 64);   // local perm within 128
        uint32_t w = pack4(acc[mb][g*4+0] + b4.x, acc[mb][g*4+1] + b4.y,
                           acc[mb][g*4+2] + b4.z, acc[mb][g*4+3] + b4.w);
        *(uint32_t*)&smem[lcol * 128 + ((cpL & 127) ^ ((lcol & 7) << 4))] = w;
      }
    __builtin_amdgcn_s_barrier();
    unsigned char* dst = C8 + (brow < 512 ? 0 : (size_t)8388608);
    const int chb = brow & 511;
#pragma unroll
    for (int i = 0; i < 2; i++) {
      const int ch = i * 512 + t;
      const int rl = ch >> 3, c16 = (ch & 7) * 16;
      i32x4 v = *(const i32x4*)&smem[rl * 128 + (c16 ^ ((rl & 7) << 4))];
      *(i32x4*)&dst[(size_t)(bcol + rl) * 512 + chb + c16] = v;
    }
  } else if (MODE == 2) {
    // tile[tok rows][ch cols]; out vcm8[b][ch][perm(p)]
    const float bcv = auxA[bcol + lcol];
    asm volatile("s_waitcnt lgkmcnt(0)" ::: "memory");
    __builtin_amdgcn_s_barrier();
#pragma unroll
    for (int mb = 0; mb < 2; mb++)
#pragma unroll
      for (int g = 0; g < 4; g++) {
        const int lt0 = wr * 64 + mb * 32 + g * 8 + 4 * lh;    // local tok
        const int ppL = perm64(lt0 & 63) | (lt0 & 64);
        uint32_t w = pack4(acc[mb][g*4+0] + bcv, acc[mb][g*4+1] + bcv,
                           acc[mb][g*4+2] + bcv, acc[mb][g*4+3] + bcv);
        *(uint32_t*)&smem[lcol * 128 + (ppL ^ ((lcol & 7) << 4))] = w;
      }
    __builtin_amdgcn_s_barrier();
    const int bb = brow >> 12;
    const int pb = brow & 4095;
#pragma unroll
    for (int i = 0; i < 2; i++) {
      const int ch = i * 512 + t;
      const int rl = ch >> 3, c16 = (ch & 7) * 16;
      i32x4 v = *(const i32x4*)&smem[rl * 128 + (c16 ^ ((rl & 7) << 4))];
      *(i32x4*)&C8[((size_t)bb * 512 + bcol + rl) * 4096 + pb + c16] = v;
    }
  } else if (MODE == 4) {
    // rinv for q in [bcol,bcol+128) from partial[bz][32][4096]
    float* rtmp  = (float*)(smem + 32768);
    float* rinvL = (float*)(smem + 32768 + 2048);
    {
      const int row = t >> 2, q4 = t & 3;
      const float* pb = partial + ((size_t)bz * 32 + q4 * 8) * 4096 + (bcol + row);
      float s = 0.f;
#pragma unroll
      for (int i = 0; i < 8; i++) s += pb[(size_t)i * 4096];
      rtmp[row * 4 + q4] = s;
    }
    __syncthreads();
    if (t < 128) rinvL[t] = 1.f / (rtmp[t * 4] + rtmp[t * 4 + 1] + rtmp[t * 4 + 2] + rtmp[t * 4 + 3]);
    __syncthreads();
    const float ri = rinvL[lcol];
#pragma unroll
    for (int mb = 0; mb < 2; mb++)
#pragma unroll
      for (int g = 0; g < 4; g++) {
        const int lch0 = wr * 64 + mb * 32 + g * 8 + 4 * lh;
        const int cpL = perm64(lch0 & 63) | (lch0 & 64);
        uint32_t w = pack4(acc[mb][g*4+0] * ri, acc[mb][g*4+1] * ri,
                           acc[mb][g*4+2] * ri, acc[mb][g*4+3] * ri);
        *(uint32_t*)&smem[lcol * 128 + (cpL ^ ((lcol & 7) << 4))] = w;
      }
    __builtin_amdgcn_s_barrier();
#pragma unroll
    for (int i = 0; i < 2; i++) {
      const int ch = i * 512 + t;
      const int rl = ch >> 3, c16 = (ch & 7) * 16;
      i32x4 v = *(const i32x4*)&smem[rl * 128 + (c16 ^ ((rl & 7) << 4))];
      *(i32x4*)&C8[((size_t)bz * 4096 + bcol + rl) * 512 + brow + c16] = v;
    }
  } else { // MODE 5: rows=ch (Wo), cols=tok; coalesced-in-p resid/out
    const int tok = bcol + lcol;
    const int bb = tok >> 12;
    const int p  = tok & 4095;
#pragma unroll
    for (int mb = 0; mb < 2; mb++)
#pragma unroll
      for (int g = 0; g < 4; g++) {
        const int ch0 = brow + wr * 64 + mb * 32 + g * 8 + 4 * lh;
        const float4 b4 = *(const float4*)&auxB[ch0];
#pragma unroll
        for (int q = 0; q < 4; q++) {
          const size_t idx = ((size_t)bb * 512 + ch0 + q) * 4096 + p;
          OUTF[idx] = acc[mb][g * 4 + q] + auxA[idx] +
                      (q == 0 ? b4.x : q == 1 ? b4.y : q == 2 ? b4.z : b4.w);
        }
      }
  }
}

// ---------------- fused QK+V projections ----------------
__global__ __launch_bounds__(512, 2)
void k_qkv(const unsigned char* __restrict__ hn8, const unsigned char* __restrict__ Wqk8,
           const unsigned char* __restrict__ Wv8,
           unsigned char* __restrict__ qk8, unsigned char* __restrict__ vcm8,
           const float* __restrict__ bq, const float* __restrict__ bk,
           const float* __restrict__ bv){
  __shared__ __align__(16) unsigned char SMEM[32768];
  const int lin = blockIdx.x;
  const int nwg = gridDim.x;   // 1536
  const int wg = ((lin & 7) * (nwg >> 3)) + (lin >> 3);
  if (wg < 1024)
    gemm8_body<1>(wg, SMEM, Wqk8, hn8, qk8, nullptr, bq, bk, nullptr,
                  512, 512, 512, 0, 0, 8, 128);
  else
    gemm8_body<2>(wg - 1024, SMEM, hn8, Wv8, vcm8, nullptr, bv, nullptr, nullptr,
                  512, 512, 512, 0, 0, 128, 4);
}

// ---------------- PV (swapped, rinv inline) and O-proj (swapped, coalesced) ----------------
__global__ __launch_bounds__(512, 2)
void k_pv(const unsigned char* __restrict__ vcm8, const unsigned char* __restrict__ P8,
          unsigned char* __restrict__ ot8, const float* __restrict__ partial){
  __shared__ __align__(16) unsigned char SMEM[32768 + 2560];
  const int lin = blockIdx.x;
  const int nwg = gridDim.x;   // 512
  const int wg = ((lin & 7) * (nwg >> 3)) + (lin >> 3);
  gemm8_body<4>(wg, SMEM, vcm8, P8, ot8, nullptr, nullptr, nullptr, partial,
                4096, 4096, 4096,
                (size_t)512 * 4096, (size_t)4096 * 4096, 4, 32);
}
__global__ __launch_bounds__(512, 2)
void k_oproj(const unsigned char* __restrict__ Wo8, const unsigned char* __restrict__ ot8,
             float* __restrict__ out, const float* __restrict__ resid,
             const float* __restrict__ bo){
  __shared__ __align__(16) unsigned char SMEM[32768];
  const int lin = blockIdx.x;
  const int nwg = gridDim.x;   // 512
  const int wg = ((lin & 7) * (nwg >> 3)) + (lin >> 3);
  // A=Wo (512 ch, gx=4), B=ot8 (16384 tok, gy=128)
  gemm8_body<5>(wg, SMEM, Wo8, ot8, nullptr, out, resid, bo, nullptr,
                512, 512, 512, 0, 0, 4, 128);
}

// ---------------- scaled-fp8 scores, SWAPPED: S^T = K x Q^T (R16 body, unchanged) ----------------
__global__ __launch_bounds__(512, 2)
void k_scores(const unsigned char* __restrict__ Kt, const unsigned char* __restrict__ Qt,
              unsigned char* __restrict__ C, const float* __restrict__ mask,
              float* __restrict__ partial, float scale,
              size_t sA, size_t sB, size_t sC, int gx, int gy)
{
  __shared__ __align__(16) unsigned char LDSBUF[65536];
  unsigned char* As = LDSBUF;
  unsigned char* Bs = LDSBUF + 32768;

  const int lin = blockIdx.x;
  const int nwg = gridDim.x;
  const int wg = ((lin & 7) * (nwg >> 3)) + (lin >> 3);
  const int bx = wg % gx;          // key block
  const int t2 = wg / gx;
  const int by = t2 % gy;          // query block
  const int bz = t2 / gy;

  const unsigned char* Ab = Kt + (size_t)bz * sA;
  const unsigned char* Bb = Qt + (size_t)bz * sB;
  const int brow = bx * 256;       // keys
  const int bcol = by * 256;       // queries
  const int t = threadIdx.x;
  const int lane = t & 63;
  const int wid = t >> 6;
  const int wr = wid >> 2;
  const int wc = wid & 3;
  const int l31 = lane & 31;
  const int lh  = lane >> 5;

  f32x16 acc[4][2];
#pragma unroll
  for (int m = 0; m < 4; m++)
#pragma unroll
    for (int n = 0; n < 2; n++)
#pragma unroll
      for (int e = 0; e < 16; e++) acc[m][n][e] = 0.f;

  const unsigned char* srcA[2];
  const unsigned char* srcB[2];
#pragma unroll
  for (int c = 0; c < 2; ++c) {
    const int q = c * 512 + t, r = q >> 2, s = (q & 3) ^ ((r >> 1) & 3);
    srcA[c] = Ab + (size_t)(brow + r) * 512 + s * 16;
    srcB[c] = Bb + (size_t)(bcol + r) * 512 + s * 16;
  }
  auto STAGE = [&](int kt, int buf) {
    const int ko = kt * 64;
#pragma unroll
    for (int c = 0; c < 2; ++c) {
      gl_lds16b(srcA[c] + ko, &As[buf * 16384 + (c * 512 + t) * 16]);
      gl_lds16b(srcB[c] + ko, &Bs[buf * 16384 + (c * 512 + t) * 16]);
    }
  };
  auto LDA32 = [&](int buf, int mb) -> i32x8 {
    const int ru = wr * 128 + mb * 32 + l31;
    const int x = (ru >> 1) & 3;
    const unsigned char* base = &As[buf * 16384 + ru * 64];
    i32x4 lo = *(const i32x4*)&base[((2 * lh) ^ x) * 16];
    i32x4 hi = *(const i32x4*)&base[((2 * lh + 1) ^ x) * 16];
    i32x8 r;
    r[0]=lo[0]; r[1]=lo[1]; r[2]=lo[2]; r[3]=lo[3];
    r[4]=hi[0]; r[5]=hi[1]; r[6]=hi[2]; r[7]=hi[3];
    return r;
  };
  auto LDB32 = [&](int buf, int nb) -> i32x8 {
    const int ru = wc * 64 + nb * 32 + l31;
    const int x = (ru >> 1) & 3;
    const unsigned char* base = &Bs[buf * 16384 + ru * 64];
    i32x4 lo = *(const i32x4*)&base[((2 * lh) ^ x) * 16];
    i32x4 hi = *(const i32x4*)&base[((2 * lh + 1) ^ x) * 16];
    i32x8 r;
    r[0]=lo[0]; r[1]=lo[1]; r[2]=lo[2]; r[3]=lo[3];
    r[4]=hi[0]; r[5]=hi[1]; r[6]=hi[2]; r[7]=hi[3];
    return r;
  };

  const int nk = 8;    // K=512
  STAGE(0, 0);
  for (int j = 0; j < nk; ++j) {
    const int bi = j & 1;
    asm volatile("s_waitcnt vmcnt(0)" ::: "memory");
    __builtin_amdgcn_s_barrier();
    __builtin_amdgcn_sched_barrier(0);
    if (j + 1 < nk) STAGE(j + 1, bi ^ 1);
    i32x8 aq[4], bq[2];
#pragma unroll
    for (int n = 0; n < 2; n++) bq[n] = LDB32(bi, n);
#pragma unroll
    for (int m = 0; m < 4; m++) aq[m] = LDA32(bi, m);
    asm volatile("s_waitcnt lgkmcnt(0)" ::: "memory");
    __builtin_amdgcn_sched_barrier(0);
    __builtin_amdgcn_s_setprio(1);
#pragma unroll
    for (int m = 0; m < 4; m++)
#pragma unroll
      for (int n = 0; n < 2; n++)
        acc[m][n] = mfma8_32x32x64(aq[m], bq[n], acc[m][n]);
    __builtin_amdgcn_s_setprio(0);
    __builtin_amdgcn_sched_barrier(0);
  }

  const float* maskb = mask + (size_t)bz * 4096;
  const float sc2 = scale * 1.4426950408889634f;

  asm volatile("s_waitcnt lgkmcnt(0)" ::: "memory");
  __builtin_amdgcn_s_barrier();

  float rs0 = 0.f, rs1 = 0.f;
#pragma unroll
  for (int mi = 0; mi < 4; mi++) {
#pragma unroll
    for (int g = 0; g < 4; g++) {
      const int kl0 = wr * 128 + mi * 32 + g * 8 + 4 * lh;
      const float4 m4 = *(const float4*)&maskb[brow + kl0];
      const int kp = perm64(kl0);
#pragma unroll
      for (int ni = 0; ni < 2; ni++) {
        const int reg = g * 4;
        float v0 = m4.x * fast_exp2(acc[mi][ni][reg + 0] * sc2);
        float v1 = m4.y * fast_exp2(acc[mi][ni][reg + 1] * sc2);
        float v2 = m4.z * fast_exp2(acc[mi][ni][reg + 2] * sc2);
        float v3 = m4.w * fast_exp2(acc[mi][ni][reg + 3] * sc2);
        if (ni == 0) rs0 += v0 + v1 + v2 + v3; else rs1 += v0 + v1 + v2 + v3;
        const int ql = wc * 64 + ni * 32 + l31;
        *(uint32_t*)&LDSBUF[ql * 256 + (kp ^ ((ql & 15) << 4))] = pack4(v0, v1, v2, v3);
      }
    }
  }
  rs0 += __shfl_xor(rs0, 32);
  rs1 += __shfl_xor(rs1, 32);
  if (lh == 0) {
    float* pslot = partial + ((size_t)bz * 32 + (size_t)(bx * 2 + wr)) * 4096;
    pslot[bcol + wc * 64 + l31]      = rs0;
    pslot[bcol + wc * 64 + 32 + l31] = rs1;
  }
  __builtin_amdgcn_s_barrier();
  unsigned char* Cb = C + (size_t)bz * sC;
#pragma unroll
  for (int i = 0; i < 8; i++) {
    const int ch = i * 512 + t;
    const int rl = ch >> 4;
    const int c16 = (ch & 15) * 16;
    i32x4 v = *(const i32x4*)&LDSBUF[rl * 256 + (c16 ^ ((rl & 15) << 4))];
    *(i32x4*)&Cb[(size_t)(bcol + rl) * 4096 + brow + c16] = v;
  }
}

extern "C" void kernel_launch(void* const* d_in, const int* in_sizes, int n_in,
                              void* d_out, int out_size, void* d_ws, size_t ws_size,
                              hipStream_t stream) {
  const float* x     = (const float*)d_in[0];
  const float* mask  = (const float*)d_in[1];
  const float* gamma = (const float*)d_in[2];
  const float* beta  = (const float*)d_in[3];
  const float* Wq    = (const float*)d_in[4];
  const float* bq    = (const float*)d_in[5];
  const float* Wk    = (const float*)d_in[6];
  const float* bk    = (const float*)d_in[7];
  const float* Wv    = (const float*)d_in[8];
  const float* bv    = (const float*)d_in[9];
  const float* Wo    = (const float*)d_in[10];
  const float* bo    = (const float*)d_in[11];
  float* out = (float*)d_out;

  size_t off = 0;
  auto nxt = [&](size_t bytes) -> void* {
    void* p = (char*)d_ws + off;
    off += (bytes + 255) & ~(size_t)255;
    return p;
  };
  float* spart          = (float*)nxt(2048 * sizeof(float));
  float* partial        = (float*)nxt((size_t)4 * 32 * 4096 * 4);
  unsigned char* Wqk8   = (unsigned char*)nxt((size_t)1024 * 512);
  unsigned char* Wv8    = (unsigned char*)nxt((size_t)512 * 512);
  unsigned char* Wo8    = (unsigned char*)nxt((size_t)512 * 512);
  unsigned char* hn8    = (unsigned char*)nxt((size_t)16384 * 512);
  unsigned char* qk8    = (unsigned char*)nxt((size_t)2 * 16384 * 512);
  unsigned char* vcm8   = (unsigned char*)nxt((size_t)4 * 512 * 4096);
  unsigned char* ot8    = (unsigned char*)nxt((size_t)16384 * 512);
  unsigned char* P8     = (unsigned char*)nxt((size_t)4 * 4096 * 4096);

  k_prep<<<1536, 256, 0, stream>>>(x, spart, Wq, Wk, Wv, Wo, Wqk8, Wv8, Wo8);
  gn_apply<<<dim3(128, 8, 4), 256, 0, stream>>>(x, spart, gamma, beta, hn8);
  k_qkv<<<1536, 512, 0, stream>>>(hn8, Wqk8, Wv8, qk8, vcm8, bq, bk, bv);
  k_scores<<<1024, 512, 0, stream>>>(qk8 + (size_t)8388608, qk8, P8, mask, partial,
                                     0.044194173824159216f,
                                     (size_t)4096 * 512, (size_t)4096 * 512,
                                     (size_t)4096 * 4096, 16, 16);
  k_pv<<<512, 512, 0, stream>>>(vcm8, P8, ot8, partial);
  k_oproj<<<512, 512, 0, stream>>>(Wo8, ot8, out, x, bo);
}